// Round 7
// baseline (1059.785 us; speedup 1.0000x reference)
//
#include <hip/hip_runtime.h>

// RelativeAxialAttention on MI355X (gfx950). Single-attention-pass design.
// K=48, G=8, DK=8, DV=16, CIN=64, B = 2304.
//
// Math shortcuts:
//  * kv/q BatchNorm folded into GEMM weights via x-gram.
//  * sim BN: softmax-invariant mean/beta; scales from CLOSED-FORM moments
//    (grams + Toeplitz windowed outer-products, k_mtab) -- no logits pass.
//  * k_stage1 GEMM on MFMA bf16 (stage1m) with X pre-transposed (k_xpose).
//  * k_attn2 round-7: diagnosis was VGPR starvation (VGPR_Count=56 => compiler
//    serialized the 16 table loads per chunk; ~47us wall/block vs ~4us issue).
//    Fix: c-interleaved tables qe2/keT2[i][j][c] (1 uint4 = 8 channels per (i,j),
//    halves load count, coalesces), break-free unrolled logits loop, and
//    explicitly staged sv/sve loads (12 in flight). Structure otherwise round-5.
// Tiers: ws>=129.5MB full path; >=113.6MB VALU stage1; else recompute fallback.

typedef unsigned short u16;
typedef __attribute__((ext_vector_type(8))) short short8v;
typedef __attribute__((ext_vector_type(4))) float float4v;

#define N_S 110592
#define N_B 2304

__device__ __forceinline__ float b2f(u16 v) {
    return __builtin_bit_cast(float, ((unsigned)v) << 16);
}
__device__ __forceinline__ u16 f2b(float f) {
    unsigned u = __builtin_bit_cast(unsigned, f);
    u = (u + 0x7FFFu + ((u >> 16) & 1u)) >> 16;
    return (u16)u;
}
__device__ __forceinline__ float ldf(const void* p, int idx, int f32) {
    return f32 ? ((const float*)p)[idx] : b2f(((const u16*)p)[idx]);
}
// unpack 8 bf16 (packed in uint4) -> 8 floats; 1 VALU op per element
__device__ __forceinline__ void unpk8(uint4 p, float* v) {
    v[0] = __builtin_bit_cast(float, p.x << 16);
    v[1] = __builtin_bit_cast(float, p.x & 0xFFFF0000u);
    v[2] = __builtin_bit_cast(float, p.y << 16);
    v[3] = __builtin_bit_cast(float, p.y & 0xFFFF0000u);
    v[4] = __builtin_bit_cast(float, p.z << 16);
    v[5] = __builtin_bit_cast(float, p.z & 0xFFFF0000u);
    v[6] = __builtin_bit_cast(float, p.w << 16);
    v[7] = __builtin_bit_cast(float, p.w & 0xFFFF0000u);
}

// ---------------- dtype detection ----------------
__global__ void k_detect(const u16* X, int* flag) {
    __shared__ int tot;
    if (threadIdx.x == 0) tot = 0;
    __syncthreads();
    int cnt = 0;
#pragma unroll
    for (int k = 0; k < 8; k++) {
        u16 v = X[(threadIdx.x * 8 + k) * 2];
        int e = (v >> 7) & 0xFF;
        cnt += (e >= 0x70 && e <= 0x8F) ? 1 : 0;
    }
    atomicAdd(&tot, cnt);
    __syncthreads();
    if (threadIdx.x == 0) flag[0] = (tot < 1024) ? 1 : 0;   // 1 = f32
}

// ---------------- zero stats region ----------------
__global__ void k_zero(float* w) {
    for (int i = blockIdx.x * blockDim.x + threadIdx.x; i < 4720; i += gridDim.x * blockDim.x)
        w[i] = 0.0f;
}

// ---------------- build emb tables ----------------
// old c-major qe/keT/ve (fallback + sv/sve) AND c-interleaved qe2/keT2 (fast logits)
__global__ void k_emb(const void* rel, const int* fidx, const int* flag,
                      u16* qe, u16* keT, u16* ve, u16* qe2, u16* keT2) {
    int f32 = flag[0];
    int t = blockIdx.x * 256 + threadIdx.x;
    if (t >= 2304) return;
    int i = t / 48, j = t % 48;
    int fij = fidx[i * 48 + j];
    int fji = fidx[j * 48 + i];
#pragma unroll
    for (int c = 0; c < 8; c++) {
        u16 qv_ = f2b(ldf(rel, c * 95 + fij, f32));
        u16 kv_ = f2b(ldf(rel, (8 + c) * 95 + fji, f32));
        qe[c * 2304 + t]  = qv_;
        keT[c * 2304 + t] = kv_;
        qe2[t * 8 + c]  = qv_;
        keT2[t * 8 + c] = kv_;
    }
#pragma unroll
    for (int c = 0; c < 16; c++)
        ve[c * 2304 + t] = f2b(ldf(rel, (16 + c) * 95 + fij, f32));
}

// ---------------- Toeplitz moment tables ----------------
__global__ void k_mtab(const void* rel, const int* flag,
                       float* mq, float* mk, float* e1q, float* e1k) {
    __shared__ float rl[1520];
    int f32 = flag[0];
    int tid = threadIdx.x;
    for (int idx = tid; idx < 1520; idx += 128) rl[idx] = ldf(rel, idx, f32);
    __syncthreads();
    if (tid >= 96) return;
    int tbl = tid / 48, i = tid % 48;
    const float* R = rl + tbl * 760;
    float* M = (tbl ? mk : mq) + i * 40;
    float* E = (tbl ? e1k : e1q) + i * 8;
    float acc[36], e[8];
#pragma unroll
    for (int x = 0; x < 36; x++) acc[x] = 0.0f;
#pragma unroll
    for (int c = 0; c < 8; c++) e[c] = 0.0f;
    for (int d = i; d < i + 48; d++) {
        float v[8];
#pragma unroll
        for (int c = 0; c < 8; c++) { v[c] = R[c * 95 + d]; e[c] += v[c]; }
        int idx = 0;
#pragma unroll
        for (int c = 0; c < 8; c++)
#pragma unroll
            for (int c2 = c; c2 < 8; c2++) { acc[idx] += v[c] * v[c2]; idx++; }
    }
    int idx = 0;
#pragma unroll
    for (int c = 0; c < 8; c++) {
        E[c] = e[c];
#pragma unroll
        for (int c2 = c; c2 < 8; c2++) {
            M[idx] = (c2 == c ? 1.0f : 2.0f) * acc[idx];
            idx++;
        }
    }
}

// ---------------- x gram ----------------
__global__ __launch_bounds__(256) void k_gram(const void* Xv, const int* flag,
                                              float* musum, float* gram) {
    __shared__ float xs[64 * 65];
    int f32 = flag[0];
    int tid = threadIdx.x;
    int cb1 = tid >> 4, cb2 = tid & 15;
    float acc[4][4];
#pragma unroll
    for (int a = 0; a < 4; a++)
#pragma unroll
        for (int b = 0; b < 4; b++) acc[a][b] = 0.0f;
    float mur = 0.0f;
    for (int tile = blockIdx.x; tile < 1728; tile += gridDim.x) {
        int s0 = tile * 64;
        __syncthreads();
#pragma unroll
        for (int r = 0; r < 4; r++) {
            int idx4 = tid + 256 * r;
            int c = idx4 >> 4, sl = (idx4 & 15) * 4;
            if (f32) {
                float4 u = *(const float4*)((const float*)Xv + c * N_S + s0 + sl);
                xs[c * 65 + sl + 0] = u.x; xs[c * 65 + sl + 1] = u.y;
                xs[c * 65 + sl + 2] = u.z; xs[c * 65 + sl + 3] = u.w;
            } else {
                ushort4 u = *(const ushort4*)((const u16*)Xv + c * N_S + s0 + sl);
                xs[c * 65 + sl + 0] = b2f(u.x); xs[c * 65 + sl + 1] = b2f(u.y);
                xs[c * 65 + sl + 2] = b2f(u.z); xs[c * 65 + sl + 3] = b2f(u.w);
            }
        }
        __syncthreads();
        for (int s = 0; s < 64; s++) {
            float av[4], bv[4];
#pragma unroll
            for (int a = 0; a < 4; a++) av[a] = xs[(cb1 + 16 * a) * 65 + s];
#pragma unroll
            for (int b = 0; b < 4; b++) bv[b] = xs[(cb2 + 16 * b) * 65 + s];
#pragma unroll
            for (int a = 0; a < 4; a++)
#pragma unroll
                for (int b = 0; b < 4; b++) acc[a][b] += av[a] * bv[b];
        }
        if (tid < 64) {
            for (int s = 0; s < 64; s++) mur += xs[tid * 65 + s];
        }
    }
#pragma unroll
    for (int a = 0; a < 4; a++)
#pragma unroll
        for (int b = 0; b < 4; b++)
            atomicAdd(&gram[(cb1 + 16 * a) * 64 + (cb2 + 16 * b)], acc[a][b]);
    if (tid < 64) atomicAdd(&musum[tid], mur);
}

// ---------------- fold BN into weights (f32 + bf16 copies) ----------------
__global__ __launch_bounds__(256) void k_fold(const void* Wkv, const void* Wq,
        const void* gkv, const void* bkv, const void* gq, const void* bq,
        const int* flag, const float* musum, const float* gram,
        float* weff, u16* weffh, float* beff) {
    int f32 = flag[0];
    int o = threadIdx.x;
    float gam, bet;
    float w[64];
    if (o < 192) {
#pragma unroll
        for (int c = 0; c < 64; c++) w[c] = ldf(Wkv, o * 64 + c, f32);
        gam = ldf(gkv, o, f32); bet = ldf(bkv, o, f32);
    } else {
        int oq = o - 192;
#pragma unroll
        for (int c = 0; c < 64; c++) w[c] = ldf(Wq, oq * 64 + c, f32);
        gam = ldf(gq, oq, f32); bet = ldf(bq, oq, f32);
    }
    const float inv = 1.0f / (float)N_S;
    float mean = 0.0f;
#pragma unroll
    for (int c = 0; c < 64; c++) mean += w[c] * musum[c];
    mean *= inv;
    float e2 = 0.0f;
    for (int c = 0; c < 64; c++) {
        float t = 0.0f;
#pragma unroll
        for (int c2 = 0; c2 < 64; c2++) t += w[c2] * gram[c * 64 + c2];
        e2 += w[c] * t;
    }
    e2 *= inv;
    float var = e2 - mean * mean;
    if (var < 0.0f) var = 0.0f;
    float sc = gam * rsqrtf(var + 1e-5f);
#pragma unroll
    for (int c = 0; c < 64; c++) {
        float wv = sc * w[c];
        weff[o * 64 + c] = wv;
        weffh[o * 64 + c] = f2b(wv);
    }
    beff[o] = bet - sc * mean;
}

// ---------------- transpose X -> Xt[b][h][c] bf16, h-stride 72 ----------------
__global__ __launch_bounds__(256) void k_xpose(const void* Xv, const int* flag, u16* Xt) {
    __shared__ float tile[64][65];
    int f32 = flag[0];
    int h = blockIdx.x, b0 = blockIdx.y * 64, tid = threadIdx.x;
#pragma unroll
    for (int r = 0; r < 4; r++) {
        int idx = tid + 256 * r;
        int c = idx >> 4, bq = (idx & 15) * 4;
        if (f32) {
            float4 u = *(const float4*)((const float*)Xv + (size_t)c * N_S + h * 2304 + b0 + bq);
            tile[c][bq + 0] = u.x; tile[c][bq + 1] = u.y;
            tile[c][bq + 2] = u.z; tile[c][bq + 3] = u.w;
        } else {
            ushort4 u = *(const ushort4*)((const u16*)Xv + (size_t)c * N_S + h * 2304 + b0 + bq);
            tile[c][bq + 0] = b2f(u.x); tile[c][bq + 1] = b2f(u.y);
            tile[c][bq + 2] = b2f(u.z); tile[c][bq + 3] = b2f(u.w);
        }
    }
    __syncthreads();
#pragma unroll
    for (int r = 0; r < 4; r++) {
        int idx = tid + 256 * r;
        int bb = idx >> 4, cq = (idx & 15) * 4;
        ushort4 o4 = make_ushort4(f2b(tile[cq + 0][bb]), f2b(tile[cq + 1][bb]),
                                  f2b(tile[cq + 2][bb]), f2b(tile[cq + 3][bb]));
        *(ushort4*)(Xt + (size_t)(b0 + bb) * 3456 + h * 72 + cq) = o4;
    }
}

// ================= FAST PATH (tier 2) =================
// stage1m: MFMA qkv GEMM + closed-form sim-BN moments.
__global__ __launch_bounds__(256) void k_stage1m(const u16* Xt, const u16* weffh, const float* beff,
        const float* mq, const float* mk, const float* e1q, const float* e1k,
        float* sstat, u16* qkv) {
    __shared__ __align__(16) u16 xs[3456];      // [h][72] bf16
    __shared__ __align__(16) u16 qkbf[6144];    // q at [(g*8+c)*48+i], k at +3072
    __shared__ float sbias[256];
    __shared__ float red[48];
    int b = blockIdx.x, tid = threadIdx.x;
    {
        const uint4* src = (const uint4*)(Xt + (size_t)b * 3456);
        uint4* dst = (uint4*)xs;
        for (int idx = tid; idx < 432; idx += 256) dst[idx] = src[idx];
    }
    sbias[tid] = beff[tid];
    if (tid < 48) red[tid] = 0.0f;
    __syncthreads();
    {
        int wv = tid >> 6, l = tid & 63;
        int lm = l & 15, lk8 = (l >> 4) * 8;
        short8v Bf[3][2];
#pragma unroll
        for (int ct = 0; ct < 3; ct++)
#pragma unroll
            for (int ks = 0; ks < 2; ks++)
                Bf[ct][ks] = *(const short8v*)(xs + (ct * 16 + lm) * 72 + ks * 32 + lk8);
        float4v acc[4][3];
#pragma unroll
        for (int a = 0; a < 4; a++)
#pragma unroll
            for (int c = 0; c < 3; c++)
#pragma unroll
                for (int e = 0; e < 4; e++) acc[a][c][e] = 0.0f;
#pragma unroll
        for (int rt = 0; rt < 4; rt++) {
            int orow = wv * 64 + rt * 16 + lm;
#pragma unroll
            for (int ks = 0; ks < 2; ks++) {
                short8v Af = *(const short8v*)(weffh + orow * 64 + ks * 32 + lk8);
#pragma unroll
                for (int ct = 0; ct < 3; ct++)
                    acc[rt][ct] = __builtin_amdgcn_mfma_f32_16x16x32_bf16(Af, Bf[ct][ks], acc[rt][ct], 0, 0, 0);
            }
        }
        int rbase = (l >> 4) * 4;
        u16* qdst = qkv + (size_t)b * 12288;
#pragma unroll
        for (int rt = 0; rt < 4; rt++) {
#pragma unroll
            for (int ct = 0; ct < 3; ct++) {
                int h = ct * 16 + lm;
#pragma unroll
                for (int rg = 0; rg < 4; rg++) {
                    int o = wv * 64 + rt * 16 + rbase + rg;
                    u16 vb = f2b(acc[rt][ct][rg] + sbias[o]);
                    int row, lq = -1;
                    if (o >= 192) {
                        int g = (o - 192) >> 3, c = (o - 192) & 7;
                        row = g * 32 + c;
                        lq = (g * 8 + c) * 48;
                    } else {
                        int g = o / 24, t = o % 24;
                        if (t < 8) { row = g * 32 + 8 + t; lq = 3072 + (g * 8 + t) * 48; }
                        else       { row = g * 32 + 16 + (t - 8); }
                    }
                    qdst[row * 48 + h] = vb;
                    if (lq >= 0) qkbf[lq + h] = vb;
                }
            }
        }
    }
    __syncthreads();
    {
        int g = tid >> 5, t = tid & 31;
        float gq[36], gk[36], sq[8], sk[8];
        float s1qr = 0, s1kr = 0, s2qr = 0, s2kr = 0;
#pragma unroll
        for (int x = 0; x < 36; x++) { gq[x] = 0.0f; gk[x] = 0.0f; }
#pragma unroll
        for (int c = 0; c < 8; c++) { sq[c] = 0.0f; sk[c] = 0.0f; }
#pragma unroll
        for (int pass = 0; pass < 2; pass++) {
            int i = t + pass * 32;
            if (i >= 48) break;
            float qv[8], kvv[8];
#pragma unroll
            for (int c = 0; c < 8; c++) {
                qv[c]  = b2f(qkbf[(g * 8 + c) * 48 + i]);
                kvv[c] = b2f(qkbf[3072 + (g * 8 + c) * 48 + i]);
            }
            const float* mqr = mq + i * 40;
            const float* mkr = mk + i * 40;
            const float* eqr = e1q + i * 8;
            const float* ekr = e1k + i * 8;
            int idx = 0;
#pragma unroll
            for (int c = 0; c < 8; c++) {
                sq[c] += qv[c]; sk[c] += kvv[c];
                s1qr += qv[c] * eqr[c];
                s1kr += kvv[c] * ekr[c];
#pragma unroll
                for (int c2 = c; c2 < 8; c2++) {
                    float oq = qv[c] * qv[c2], ok = kvv[c] * kvv[c2];
                    gq[idx] += oq; gk[idx] += ok;
                    s2qr += mqr[idx] * oq;
                    s2kr += mkr[idx] * ok;
                    idx++;
                }
            }
        }
#pragma unroll
        for (int off = 1; off <= 16; off <<= 1) {
#pragma unroll
            for (int x = 0; x < 36; x++) { gq[x] += __shfl_xor(gq[x], off); gk[x] += __shfl_xor(gk[x], off); }
#pragma unroll
            for (int c = 0; c < 8; c++) { sq[c] += __shfl_xor(sq[c], off); sk[c] += __shfl_xor(sk[c], off); }
            s1qr += __shfl_xor(s1qr, off); s1kr += __shfl_xor(s1kr, off);
            s2qr += __shfl_xor(s2qr, off); s2kr += __shfl_xor(s2kr, off);
        }
        if (t == 0) {
            float s1qk = 0.0f, s2qk = 0.0f;
            int idx = 0;
#pragma unroll
            for (int c = 0; c < 8; c++) {
                s1qk += sq[c] * sk[c];
#pragma unroll
                for (int c2 = c; c2 < 8; c2++) {
                    float w = (c2 == c) ? 1.0f : 2.0f;
                    s2qk += w * gq[idx] * gk[idx];
                    idx++;
                }
            }
            red[0 * 8 + g] = s1qk;  red[1 * 8 + g] = s1qr;  red[2 * 8 + g] = s1kr;
            red[3 * 8 + g] = s2qk;  red[4 * 8 + g] = s2qr;  red[5 * 8 + g] = s2kr;
        }
    }
    __syncthreads();
    if (tid < 48) atomicAdd(&sstat[tid], red[tid]);
}

// ================= tier-1 stage1 (VALU, reads X directly) =================
__global__ __launch_bounds__(256) void k_stage1(const void* Xv, const float* weff, const float* beff,
        const float* mq, const float* mk, const float* e1q, const float* e1k,
        const int* flag, float* sstat, u16* qkv) {
    __shared__ __align__(16) float xs[3072];
    __shared__ __align__(16) float qk[6144];
    __shared__ float red[48];
    int f32 = flag[0];
    int b = blockIdx.x, tid = threadIdx.x;
    for (int idx = tid; idx < 3072; idx += 256) {
        int c = idx / 48, h = idx % 48;
        xs[idx] = ldf(Xv, c * N_S + h * 2304 + b, f32);
    }
    __syncthreads();
    {
        int g = tid >> 5, r = tid & 31;
        int o;
        if (r < 8)       o = 192 + g * 8 + r;
        else if (r < 16) o = g * 24 + (r - 8);
        else             o = g * 24 + 8 + (r - 16);
        float wr[64];
        const float4* wrow = (const float4*)(weff + o * 64);
#pragma unroll
        for (int c4 = 0; c4 < 16; c4++) {
            float4 t4 = wrow[c4];
            wr[c4 * 4 + 0] = t4.x; wr[c4 * 4 + 1] = t4.y; wr[c4 * 4 + 2] = t4.z; wr[c4 * 4 + 3] = t4.w;
        }
        float bias = beff[o];
        u16* gdst = qkv + (b * 256 + tid) * 48;
        float* ldst = (r < 8) ? (qk + g * 768 + r * 48)
                    : (r < 16 ? (qk + g * 768 + 384 + (r - 8) * 48) : nullptr);
#pragma unroll
        for (int hb = 0; hb < 6; hb++) {
            float acc[8];
#pragma unroll
            for (int u = 0; u < 8; u++) acc[u] = bias;
#pragma unroll
            for (int c = 0; c < 64; c++) {
                float wv = wr[c];
                const float4* xp = (const float4*)(xs + c * 48 + hb * 8);
                float4 x0 = xp[0], x1 = xp[1];
                acc[0] += wv * x0.x; acc[1] += wv * x0.y; acc[2] += wv * x0.z; acc[3] += wv * x0.w;
                acc[4] += wv * x1.x; acc[5] += wv * x1.y; acc[6] += wv * x1.z; acc[7] += wv * x1.w;
            }
            ushort4 p0 = make_ushort4(f2b(acc[0]), f2b(acc[1]), f2b(acc[2]), f2b(acc[3]));
            ushort4 p1 = make_ushort4(f2b(acc[4]), f2b(acc[5]), f2b(acc[6]), f2b(acc[7]));
            *(ushort4*)(gdst + hb * 8)     = p0;
            *(ushort4*)(gdst + hb * 8 + 4) = p1;
            if (ldst) {
                *(float4*)(ldst + hb * 8)     = make_float4(acc[0], acc[1], acc[2], acc[3]);
                *(float4*)(ldst + hb * 8 + 4) = make_float4(acc[4], acc[5], acc[6], acc[7]);
            }
        }
    }
    __syncthreads();
    {
        int g = tid >> 5, t = tid & 31;
        float gq[36], gk[36], sq[8], sk[8];
        float s1qr = 0, s1kr = 0, s2qr = 0, s2kr = 0;
#pragma unroll
        for (int x = 0; x < 36; x++) { gq[x] = 0.0f; gk[x] = 0.0f; }
#pragma unroll
        for (int c = 0; c < 8; c++) { sq[c] = 0.0f; sk[c] = 0.0f; }
#pragma unroll
        for (int pass = 0; pass < 2; pass++) {
            int i = t + pass * 32;
            if (i >= 48) break;
            float qv[8], kvv[8];
#pragma unroll
            for (int c = 0; c < 8; c++) {
                qv[c]  = qk[g * 768 + c * 48 + i];
                kvv[c] = qk[g * 768 + 384 + c * 48 + i];
            }
            const float* mqr = mq + i * 40;
            const float* mkr = mk + i * 40;
            const float* eqr = e1q + i * 8;
            const float* ekr = e1k + i * 8;
            int idx = 0;
#pragma unroll
            for (int c = 0; c < 8; c++) {
                sq[c] += qv[c]; sk[c] += kvv[c];
                s1qr += qv[c] * eqr[c];
                s1kr += kvv[c] * ekr[c];
#pragma unroll
                for (int c2 = c; c2 < 8; c2++) {
                    float oq = qv[c] * qv[c2], ok = kvv[c] * kvv[c2];
                    gq[idx] += oq; gk[idx] += ok;
                    s2qr += mqr[idx] * oq;
                    s2kr += mkr[idx] * ok;
                    idx++;
                }
            }
        }
#pragma unroll
        for (int off = 1; off <= 16; off <<= 1) {
#pragma unroll
            for (int x = 0; x < 36; x++) { gq[x] += __shfl_xor(gq[x], off); gk[x] += __shfl_xor(gk[x], off); }
#pragma unroll
            for (int c = 0; c < 8; c++) { sq[c] += __shfl_xor(sq[c], off); sk[c] += __shfl_xor(sk[c], off); }
            s1qr += __shfl_xor(s1qr, off); s1kr += __shfl_xor(s1kr, off);
            s2qr += __shfl_xor(s2qr, off); s2kr += __shfl_xor(s2kr, off);
        }
        if (t == 0) {
            float s1qk = 0.0f, s2qk = 0.0f;
            int idx = 0;
#pragma unroll
            for (int c = 0; c < 8; c++) {
                s1qk += sq[c] * sk[c];
#pragma unroll
                for (int c2 = c; c2 < 8; c2++) {
                    float w = (c2 == c) ? 1.0f : 2.0f;
                    s2qk += w * gq[idx] * gk[idx];
                    idx++;
                }
            }
            red[0 * 8 + g] = s1qk;  red[1 * 8 + g] = s1qr;  red[2 * 8 + g] = s1kr;
            red[3 * 8 + g] = s2qk;  red[4 * 8 + g] = s2qr;  red[5 * 8 + g] = s2kr;
        }
    }
    __syncthreads();
    if (tid < 48) atomicAdd(&sstat[tid], red[tid]);
}

// scaled=1: sstat already includes fqr/fkr (fallback). scaled=0: apply here.
__global__ void k_simcoef(const float* sstat, const void* gsim, const void* fqrp, const void* fkrp,
                          const int* flag, int scaled, float* scoef) {
    int ch = threadIdx.x;
    if (ch >= 24) return;
    int f32 = flag[0];
    float f = 1.0f;
    if (!scaled) {
        if (ch >= 16)     f = ldf(fkrp, 0, f32);
        else if (ch >= 8) f = ldf(fqrp, 0, f32);
    }
    const float n = 2304.0f * 2304.0f;
    float mean = f * sstat[ch] / n;
    float var = f * f * sstat[24 + ch] / n - mean * mean;
    if (var < 0.0f) var = 0.0f;
    scoef[ch] = ldf(gsim, ch, f32) * rsqrtf(var + 1e-5f);
}

// attn2: one block per (b, g). 128 threads. c-interleaved tables + break-free
// unrolled logits + staged sv/sve loads (register-pressure-for-latency trade).
__global__ __launch_bounds__(128) void k_attn2(const u16* qkv,
        const u16* qe2, const u16* keT2, const u16* ve,
        const float* scoef, const void* fqrp, const void* fkrp,
        const void* fsvp, const void* fsvep, const int* flag,
        float* ostat, u16* pre2) {
    __shared__ __align__(16) u16 qls[384];      // [i][c] stride 8, bf16
    __shared__ __align__(16) u16 kls[384];      // [c][j] bf16
    __shared__ __align__(16) u16 vls[768];      // [c][j] bf16
    __shared__ __align__(16) float z[2496];     // [48][52]
    int f32 = flag[0];
    int b = blockIdx.x, g = blockIdx.y, tid = threadIdx.x;
    {   // load qkv: 1536 u16 = 384 ushort4; q transposed to [i][c]
        const u16* src = qkv + (b * 256 + g * 32) * 48;
#pragma unroll
        for (int rr = 0; rr < 3; rr++) {
            int idx = tid + 128 * rr;
            int r = idx / 12, hq = (idx % 12) * 4;
            ushort4 u = *(const ushort4*)(src + r * 48 + hq);
            if (r < 8) {
                u16* d = qls + hq * 8 + r;
                d[0] = u.x; d[8] = u.y; d[16] = u.z; d[24] = u.w;
            } else if (r < 16) {
                *(ushort4*)(kls + (r - 8) * 48 + hq) = u;
            } else {
                *(ushort4*)(vls + (r - 16) * 48 + hq) = u;
            }
        }
    }
    __syncthreads();
    float fqr = ldf(fqrp, 0, f32), fkr = ldf(fkrp, 0, f32);
    float fsv = ldf(fsvp, 0, f32), fsve = ldf(fsvep, 0, f32);
    float c0 = scoef[g], c1 = scoef[8 + g], c2 = scoef[16 + g];
    // logits: 576 chunks; 4 unrolled + 64-thread tail (no break => pipelinable)
    auto chunk_body = [&](int chunk) {
        int i = chunk / 12, j0 = (chunk % 12) * 4;
        const uint4* qp = (const uint4*)qe2 + (i * 48 + j0);
        const uint4* kp = (const uint4*)keT2 + (i * 48 + j0);
        uint4 pq[4], pk[4];
#pragma unroll
        for (int jj = 0; jj < 4; jj++) { pq[jj] = qp[jj]; pk[jj] = kp[jj]; }
        float qv[4][8], kv[4][8];
#pragma unroll
        for (int jj = 0; jj < 4; jj++) { unpk8(pq[jj], qv[jj]); unpk8(pk[jj], kv[jj]); }
        float qi_[8];
        {
            ushort4 q0 = *(const ushort4*)(qls + i * 8);
            ushort4 q1 = *(const ushort4*)(qls + i * 8 + 4);
            qi_[0] = b2f(q0.x); qi_[1] = b2f(q0.y); qi_[2] = b2f(q0.z); qi_[3] = b2f(q0.w);
            qi_[4] = b2f(q1.x); qi_[5] = b2f(q1.y); qi_[6] = b2f(q1.z); qi_[7] = b2f(q1.w);
        }
        float zq[4] = {0,0,0,0}, zr[4] = {0,0,0,0}, zk[4] = {0,0,0,0};
#pragma unroll
        for (int c = 0; c < 8; c++) {
            float qi = qi_[c];
            ushort4 ku = *(const ushort4*)(kls + c * 48 + j0);
            float k0 = b2f(ku.x), k1 = b2f(ku.y), k2 = b2f(ku.z), k3 = b2f(ku.w);
            zq[0] += qi * k0; zq[1] += qi * k1; zq[2] += qi * k2; zq[3] += qi * k3;
            zr[0] += qi * qv[0][c]; zr[1] += qi * qv[1][c]; zr[2] += qi * qv[2][c]; zr[3] += qi * qv[3][c];
            zk[0] += k0 * kv[0][c]; zk[1] += k1 * kv[1][c]; zk[2] += k2 * kv[2][c]; zk[3] += k3 * kv[3][c];
        }
        float4 o4;
        o4.x = c0 * zq[0] + c1 * (fqr * zr[0]) + c2 * (fkr * zk[0]);
        o4.y = c0 * zq[1] + c1 * (fqr * zr[1]) + c2 * (fkr * zk[1]);
        o4.z = c0 * zq[2] + c1 * (fqr * zr[2]) + c2 * (fkr * zk[2]);
        o4.w = c0 * zq[3] + c1 * (fqr * zr[3]) + c2 * (fkr * zk[3]);
        *(float4*)(z + i * 52 + j0) = o4;
    };
#pragma unroll
    for (int r = 0; r < 4; r++) chunk_body(tid + 128 * r);
    if (tid < 64) chunk_body(512 + tid);
    __syncthreads();
    // softmax: 48 rows, 2 lanes/row, register tree + 1 shuffle
    if (tid < 96) {
        int i = tid >> 1, h = tid & 1;
        float* row = z + i * 52 + h * 24;
        float vv[24];
#pragma unroll
        for (int k = 0; k < 6; k++) *(float4*)&vv[k * 4] = *(const float4*)(row + k * 4);
        float t[12];
#pragma unroll
        for (int k = 0; k < 12; k++) t[k] = fmaxf(vv[k], vv[k + 12]);
#pragma unroll
        for (int k = 0; k < 6; k++) t[k] = fmaxf(t[k], t[k + 6]);
        t[0] = fmaxf(t[0], t[3]); t[1] = fmaxf(t[1], t[4]); t[2] = fmaxf(t[2], t[5]);
        float m = fmaxf(fmaxf(t[0], t[1]), t[2]);
        m = fmaxf(m, __shfl_xor(m, 1));
#pragma unroll
        for (int k = 0; k < 24; k++) vv[k] = __expf(vv[k] - m);
#pragma unroll
        for (int k = 0; k < 12; k++) t[k] = vv[k] + vv[k + 12];
#pragma unroll
        for (int k = 0; k < 6; k++) t[k] = t[k] + t[k + 6];
        t[0] += t[3]; t[1] += t[4]; t[2] += t[5];
        float s = t[0] + t[1] + t[2];
        s += __shfl_xor(s, 1);
        float inv = 1.0f / s;
#pragma unroll
        for (int k = 0; k < 24; k++) vv[k] *= inv;
#pragma unroll
        for (int k = 0; k < 6; k++) *(float4*)(row + k * 4) = *(float4*)&vv[k * 4];
    }
    __syncthreads();
    {   // sv / sve: thread -> (c, u); staged loads (12 in flight per rep)
        int c = tid >> 3, u = tid & 7;
        ushort4 vreg[12];
#pragma unroll
        for (int j4 = 0; j4 < 12; j4++)
            vreg[j4] = *(const ushort4*)(vls + c * 48 + j4 * 4);
        const u16* vebase = ve + c * 2304;
        float sumA = 0, sqA = 0, sumB = 0, sqB = 0;
#pragma unroll
        for (int rep = 0; rep < 6; rep++) {
            int i = u + 8 * rep;
            const float* zrow = z + i * 52;
            ushort4 eu[12];
#pragma unroll
            for (int j4 = 0; j4 < 12; j4++)
                eu[j4] = *(const ushort4*)(vebase + i * 48 + j4 * 4);
            float4 sm[12];
#pragma unroll
            for (int j4 = 0; j4 < 12; j4++)
                sm[j4] = *(const float4*)(zrow + j4 * 4);
            float sv = 0.0f, se = 0.0f;
#pragma unroll
            for (int j4 = 0; j4 < 12; j4++) {
                ushort4 vu = vreg[j4];
                sv += sm[j4].x * b2f(vu.x) + sm[j4].y * b2f(vu.y) + sm[j4].z * b2f(vu.z) + sm[j4].w * b2f(vu.w);
                se += sm[j4].x * b2f(eu[j4].x) + sm[j4].y * b2f(eu[j4].y) + sm[j4].z * b2f(eu[j4].z) + sm[j4].w * b2f(eu[j4].w);
            }
            float a = sv * fsv, bb = se * fsve;
            *(ushort2*)(pre2 + ((b * 128 + g * 16 + c) * 48 + i) * 2) = make_ushort2(f2b(a), f2b(bb));
            sumA += a; sqA += a * a; sumB += bb; sqB += bb * bb;
        }
#pragma unroll
        for (int off = 1; off <= 4; off <<= 1) {
            sumA += __shfl_xor(sumA, off); sqA += __shfl_xor(sqA, off);
            sumB += __shfl_xor(sumB, off); sqB += __shfl_xor(sqB, off);
        }
        if (u == 0) {
            int ch2 = g * 32 + c * 2;
            atomicAdd(&ostat[ch2 * 2 + 0], sumA);
            atomicAdd(&ostat[ch2 * 2 + 1], sqA);
            atomicAdd(&ostat[ch2 * 2 + 2], sumB);
            atomicAdd(&ostat[ch2 * 2 + 3], sqB);
        }
    }
}

__global__ void k_outcoef(const float* ostat, const void* gout, const void* bout,
                          const int* flag, float* ocoef) {
    int f32 = flag[0];
    int o = threadIdx.x;
    const float n = 110592.0f;
    float mean = ostat[o * 2] / n;
    float var = ostat[o * 2 + 1] / n - mean * mean;
    if (var < 0.0f) var = 0.0f;
    float sc = ldf(gout, o, f32) * rsqrtf(var + 1e-5f);
    ocoef[o * 2] = sc;
    ocoef[o * 2 + 1] = ldf(bout, o, f32) - mean * sc;
}

// final: BN + pair-sum + transpose.
__global__ __launch_bounds__(256) void k_final(const u16* pre2, const float* ocoef,
                                               const int* flag, void* outp) {
    __shared__ float tile[48 * 49];
    int f32 = flag[0];
    int ch = blockIdx.x, w = blockIdx.y, tid = threadIdx.x;
    float sc0 = ocoef[(ch * 2) * 2],     sh0 = ocoef[(ch * 2) * 2 + 1];
    float sc1 = ocoef[(ch * 2 + 1) * 2], sh1 = ocoef[(ch * 2 + 1) * 2 + 1];
    float shs = sh0 + sh1;
#pragma unroll
    for (int r = 0; r < 9; r++) {
        int idx = tid + 256 * r;
        int d = idx / 48, i = idx % 48;
        ushort2 p = ((const ushort2*)pre2)[((w * 48 + d) * 128 + ch) * 48 + i];
        tile[d * 49 + i] = b2f(p.x) * sc0 + b2f(p.y) * sc1 + shs;
    }
    __syncthreads();
#pragma unroll
    for (int r = 0; r < 9; r++) {
        int idx = tid + 256 * r;
        int i = idx / 48, d = idx % 48;
        float v = tile[d * 49 + i];
        int oidx = ch * N_S + i * 2304 + w * 48 + d;
        if (f32) ((float*)outp)[oidx] = v;
        else     ((u16*)outp)[oidx] = f2b(v);
    }
}

// ================= FALLBACK PATH =================
__global__ __launch_bounds__(256) void k_qkstat(const void* Xv, const float* weff, const float* beff,
        const u16* qe, const u16* keT, const void* fqrp, const void* fkrp,
        const int* flag, float* sstat) {
    __shared__ __align__(16) float xs[3072];
    __shared__ __align__(16) float qsh[3072];
    __shared__ __align__(16) float ksh[3072];
    __shared__ float red[48];
    int f32 = flag[0];
    int b = blockIdx.x, tid = threadIdx.x;
    for (int idx = tid; idx < 3072; idx += 256) {
        int c = idx / 48, h = idx % 48;
        xs[idx] = ldf(Xv, c * N_S + h * 2304 + b, f32);
    }
    if (tid < 48) red[tid] = 0.0f;
    __syncthreads();
    {
        int r = tid >> 1, half = tid & 1;
        int o; float* dst;
        if (r < 64) { o = 192 + r; dst = qsh + r * 48; }
        else { int rk = r - 64; o = (rk >> 3) * 24 + (rk & 7); dst = ksh + rk * 48; }
        float wr[64];
        const float4* wrow = (const float4*)(weff + o * 64);
#pragma unroll
        for (int c4 = 0; c4 < 16; c4++) {
            float4 t4 = wrow[c4];
            wr[c4 * 4 + 0] = t4.x; wr[c4 * 4 + 1] = t4.y; wr[c4 * 4 + 2] = t4.z; wr[c4 * 4 + 3] = t4.w;
        }
        float bias = beff[o];
        int h0 = half * 24;
#pragma unroll
        for (int hb = 0; hb < 3; hb++) {
            float acc[8];
#pragma unroll
            for (int u = 0; u < 8; u++) acc[u] = bias;
#pragma unroll
            for (int c = 0; c < 64; c++) {
                float wv = wr[c];
                const float4* xp = (const float4*)(xs + c * 48 + h0 + hb * 8);
                float4 x0 = xp[0], x1 = xp[1];
                acc[0] += wv * x0.x; acc[1] += wv * x0.y; acc[2] += wv * x0.z; acc[3] += wv * x0.w;
                acc[4] += wv * x1.x; acc[5] += wv * x1.y; acc[6] += wv * x1.z; acc[7] += wv * x1.w;
            }
            *(float4*)(dst + h0 + hb * 8)     = make_float4(acc[0], acc[1], acc[2], acc[3]);
            *(float4*)(dst + h0 + hb * 8 + 4) = make_float4(acc[4], acc[5], acc[6], acc[7]);
        }
    }
    __syncthreads();
    float fqr = ldf(fqrp, 0, f32), fkr = ldf(fkrp, 0, f32);
    float sum[24], sq[24];
#pragma unroll
    for (int k = 0; k < 24; k++) { sum[k] = 0.0f; sq[k] = 0.0f; }
    for (int r = 0; r < 3; r++) {
        int chunk = tid + 256 * r;
        if (chunk >= 576) break;
        int i = chunk / 12, j0 = (chunk % 12) * 4;
        float qv[8][4], kv[8][4];
#pragma unroll
        for (int c = 0; c < 8; c++) {
            ushort4 uq = *(const ushort4*)(qe + c * 2304 + i * 48 + j0);
            ushort4 uk = *(const ushort4*)(keT + c * 2304 + i * 48 + j0);
            qv[c][0] = b2f(uq.x); qv[c][1] = b2f(uq.y); qv[c][2] = b2f(uq.z); qv[c][3] = b2f(uq.w);
            kv[c][0] = b2f(uk.x); kv[c][1] = b2f(uk.y); kv[c][2] = b2f(uk.z); kv[c][3] = b2f(uk.w);
        }
#pragma unroll
        for (int g = 0; g < 8; g++) {
            float zq[4] = {0,0,0,0}, zr[4] = {0,0,0,0}, zk[4] = {0,0,0,0};
#pragma unroll
            for (int c = 0; c < 8; c++) {
                float qi = qsh[(g * 8 + c) * 48 + i];
                float4 kk = *(const float4*)(ksh + (g * 8 + c) * 48 + j0);
                zq[0] += qi * kk.x; zq[1] += qi * kk.y; zq[2] += qi * kk.z; zq[3] += qi * kk.w;
                zr[0] += qi * qv[c][0]; zr[1] += qi * qv[c][1]; zr[2] += qi * qv[c][2]; zr[3] += qi * qv[c][3];
                zk[0] += kk.x * kv[c][0]; zk[1] += kk.y * kv[c][1]; zk[2] += kk.z * kv[c][2]; zk[3] += kk.w * kv[c][3];
            }
#pragma unroll
            for (int u = 0; u < 4; u++) {
                float a = zq[u];        sum[g] += a;       sq[g] += a * a;
                float r1 = zr[u] * fqr; sum[8 + g] += r1;  sq[8 + g] += r1 * r1;
                float r2 = zk[u] * fkr; sum[16 + g] += r2; sq[16 + g] += r2 * r2;
            }
        }
    }
#pragma unroll
    for (int k = 0; k < 24; k++) {
        float s = sum[k], q = sq[k];
        for (int off = 32; off >= 1; off >>= 1) { s += __shfl_xor(s, off); q += __shfl_xor(q, off); }
        if ((tid & 63) == 0) { atomicAdd(&red[k], s); atomicAdd(&red[24 + k], q); }
    }
    __syncthreads();
    if (tid < 48) atomicAdd(&sstat[tid], red[tid]);
}

__global__ __launch_bounds__(256) void k_attn(const void* Xv, const float* weff, const float* beff,
        const u16* qe, const u16* keT, const u16* ve,
        const float* scoef, const float* ocoef,
        const void* fqrp, const void* fkrp, const void* fsvp, const void* fsvep,
        const int* flag, float* ostat, void* outp, int mode) {
    __shared__ __align__(16) float zx[3072];
    __shared__ __align__(16) float qsh[3072];
    __shared__ __align__(16) float ksh[3072];
    __shared__ __align__(16) float vsh[6144];
    __shared__ float osl[512];
    int f32 = flag[0];
    int b = blockIdx.x, tid = threadIdx.x;
    for (int idx = tid; idx < 3072; idx += 256) {
        int c = idx / 48, h = idx % 48;
        zx[idx] = ldf(Xv, c * N_S + h * 2304 + b, f32);
    }
    __syncthreads();
    {
        int o; float* dst;
        if (tid < 64)       { o = 192 + tid; dst = qsh + tid * 48; }
        else if (tid < 128) { int rk = tid - 64; o = (rk >> 3) * 24 + (rk & 7); dst = ksh + rk * 48; }
        else                { int rv = tid - 128; o = (rv >> 4) * 24 + 8 + (rv & 15); dst = vsh + rv * 48; }
        float wr[64];
        const float4* wrow = (const float4*)(weff + o * 64);
#pragma unroll
        for (int c4 = 0; c4 < 16; c4++) {
            float4 t4 = wrow[c4];
            wr[c4 * 4 + 0] = t4.x; wr[c4 * 4 + 1] = t4.y; wr[c4 * 4 + 2] = t4.z; wr[c4 * 4 + 3] = t4.w;
        }
        float bias = beff[o];
#pragma unroll
        for (int hb = 0; hb < 6; hb++) {
            float acc[8];
#pragma unroll
            for (int u = 0; u < 8; u++) acc[u] = bias;
#pragma unroll
            for (int c = 0; c < 64; c++) {
                float wv = wr[c];
                const float4* xp = (const float4*)(zx + c * 48 + hb * 8);
                float4 x0 = xp[0], x1 = xp[1];
                acc[0] += wv * x0.x; acc[1] += wv * x0.y; acc[2] += wv * x0.z; acc[3] += wv * x0.w;
                acc[4] += wv * x1.x; acc[5] += wv * x1.y; acc[6] += wv * x1.z; acc[7] += wv * x1.w;
            }
            *(float4*)(dst + hb * 8)     = make_float4(acc[0], acc[1], acc[2], acc[3]);
            *(float4*)(dst + hb * 8 + 4) = make_float4(acc[4], acc[5], acc[6], acc[7]);
        }
    }
    __syncthreads();
    float fqr = ldf(fqrp, 0, f32), fkr = ldf(fkrp, 0, f32);
    float fsv = ldf(fsvp, 0, f32), fsve = ldf(fsvep, 0, f32);
    float* z = zx;
    for (int g = 0; g < 8; g++) {
        float c0 = scoef[g], c1 = scoef[8 + g], c2 = scoef[16 + g];
        for (int r = 0; r < 3; r++) {
            int chunk = tid + 256 * r;
            if (chunk >= 576) break;
            int i = chunk / 12, j0 = (chunk % 12) * 4;
            float zq[4] = {0,0,0,0}, zr[4] = {0,0,0,0}, zk[4] = {0,0,0,0};
#pragma unroll
            for (int c = 0; c < 8; c++) {
                ushort4 uq = *(const ushort4*)(qe + c * 2304 + i * 48 + j0);
                ushort4 uk = *(const ushort4*)(keT + c * 2304 + i * 48 + j0);
                float qi = qsh[(g * 8 + c) * 48 + i];
                float4 kk = *(const float4*)(ksh + (g * 8 + c) * 48 + j0);
                zq[0] += qi * kk.x; zq[1] += qi * kk.y; zq[2] += qi * kk.z; zq[3] += qi * kk.w;
                zr[0] += qi * b2f(uq.x); zr[1] += qi * b2f(uq.y); zr[2] += qi * b2f(uq.z); zr[3] += qi * b2f(uq.w);
                zk[0] += kk.x * b2f(uk.x); zk[1] += kk.y * b2f(uk.y); zk[2] += kk.z * b2f(uk.z); zk[3] += kk.w * b2f(uk.w);
            }
            float4 o4;
            o4.x = c0 * zq[0] + c1 * (fqr * zr[0]) + c2 * (fkr * zk[0]);
            o4.y = c0 * zq[1] + c1 * (fqr * zr[1]) + c2 * (fkr * zk[1]);
            o4.z = c0 * zq[2] + c1 * (fqr * zr[2]) + c2 * (fkr * zk[2]);
            o4.w = c0 * zq[3] + c1 * (fqr * zr[3]) + c2 * (fkr * zk[3]);
            *(float4*)(z + i * 52 + j0) = o4;
        }
        __syncthreads();
        {
            int wv = tid >> 6, lane = tid & 63;
            for (int rr = 0; rr < 12; rr++) {
                int i = wv * 12 + rr;
                float val = (lane < 48) ? z[i * 52 + lane] : -1e30f;
                float m = val;
                for (int off = 32; off >= 1; off >>= 1) m = fmaxf(m, __shfl_xor(m, off));
                float e = (lane < 48) ? __expf(val - m) : 0.0f;
                float s = e;
                for (int off = 32; off >= 1; off >>= 1) s += __shfl_xor(s, off);
                if (lane < 48) z[i * 52 + lane] = e / s;
            }
        }
        __syncthreads();
        {
            int c = tid >> 4, u = tid & 15;
            int ch2 = g * 32 + c * 2;
            float oc0 = 0, oc1 = 0, osh = 0;
            if (mode != 0) {
                oc0 = ocoef[ch2 * 2]; oc1 = ocoef[(ch2 + 1) * 2];
                osh = ocoef[ch2 * 2 + 1] + ocoef[(ch2 + 1) * 2 + 1];
            }
            float sumA = 0, sqA = 0, sumB = 0, sqB = 0;
#pragma unroll
            for (int r = 0; r < 3; r++) {
                int i = u + 16 * r;
                float sv = 0.0f, se = 0.0f;
#pragma unroll
                for (int j4 = 0; j4 < 12; j4++) {
                    float4 sm = *(const float4*)(z + i * 52 + j4 * 4);
                    float4 vv = *(const float4*)(vsh + (g * 16 + c) * 48 + j4 * 4);
                    ushort4 veu = *(const ushort4*)(ve + c * 2304 + i * 48 + j4 * 4);
                    sv += sm.x * vv.x + sm.y * vv.y + sm.z * vv.z + sm.w * vv.w;
                    se += sm.x * b2f(veu.x) + sm.y * b2f(veu.y) + sm.z * b2f(veu.z) + sm.w * b2f(veu.w);
                }
                float a = sv * fsv, bb = se * fsve;
                if (mode == 0) {
                    sumA += a; sqA += a * a; sumB += bb; sqB += bb * bb;
                } else {
                    float outv = a * oc0 + bb * oc1 + osh;
                    int oidx = (g * 16 + c) * N_S + i * 2304 + b;
                    if (f32) ((float*)outp)[oidx] = outv;
                    else     ((u16*)outp)[oidx] = f2b(outv);
                }
            }
            if (mode == 0) {
                for (int off = 1; off <= 8; off <<= 1) {
                    sumA += __shfl_xor(sumA, off); sqA += __shfl_xor(sqA, off);
                    sumB += __shfl_xor(sumB, off); sqB += __shfl_xor(sqB, off);
                }
                if (u == 0) {
                    int base = ch2 * 2;
                    osl[base + 0] = sumA; osl[base + 1] = sqA;
                    osl[base + 2] = sumB; osl[base + 3] = sqB;
                }
            }
        }
        __syncthreads();
    }
    if (mode == 0) {
        atomicAdd(&ostat[tid], osl[tid]);
        atomicAdd(&ostat[tid + 256], osl[tid + 256]);
    }
}

extern "C" void kernel_launch(void* const* d_in, const int* in_sizes, int n_in,
                              void* d_out, int out_size, void* d_ws, size_t ws_size,
                              hipStream_t stream) {
    const void* X    = d_in[0];
    const void* Wkv  = d_in[1];
    const void* Wq   = d_in[2];
    const void* gkv  = d_in[3];
    const void* bkv  = d_in[4];
    const void* gq   = d_in[5];
    const void* bq   = d_in[6];
    const void* gsim = d_in[7];
    const void* gout = d_in[9];
    const void* bout = d_in[10];
    const void* rel  = d_in[11];
    const void* fqrp = d_in[12];
    const void* fkrp = d_in[13];
    const void* fsvp = d_in[14];
    const void* fsvep= d_in[15];
    const int* fidx  = (const int*)d_in[16];

    float* W      = (float*)d_ws;
    float* musum  = W;            // 64
    float* gram   = W + 64;       // 4096
    float* sstat  = W + 4160;     // 48
    float* ostat  = W + 4208;     // 512  (zeroed region ends at 4720)
    float* weff   = W + 4720;     // 16384
    float* beff   = W + 21104;    // 256
    float* scoef  = W + 21360;    // 24
    float* ocoef  = W + 21384;    // 512
    int*   flag   = (int*)(W + 21896);    // 1 (+3 pad)
    float* mq     = W + 21900;    // 48*40
    float* mk     = W + 23820;    // 48*40
    float* e1q    = W + 25740;    // 48*8
    float* e1k    = W + 26124;    // 48*8  -> ends 26508
    u16*   qe     = (u16*)(W + 26508);    // 8*2304 u16 (c-major, fallback)
    u16*   keT    = (u16*)(W + 35724);
    u16*   ve     = (u16*)(W + 44940);    // 16*2304 u16 -> ends float 63372
    u16*   weffh  = (u16*)(W + 63372);    // 256*64 u16 -> ends 71564
    u16*   qe2    = (u16*)(W + 71564);    // 2304*8 u16 (c-interleaved) -> ends 80780
    u16*   keT2   = (u16*)(W + 80780);    // -> ends 89996
    u16*   qkv    = (u16*)(W + 89996);    // 2304*256*48 bf16 -> ends 14245772
    u16*   pre2   = qkv + 28311552;       // -> ends 28401548
    u16*   Xt     = (u16*)(W + 28401548); // 2304*3456 bf16 -> ends 32382860

    const size_t need1 = (size_t)28401548 * 4;   // ~113.6 MB (tier 1)
    const size_t need2 = (size_t)32382860 * 4;   // ~129.5 MB (tier 2, +Xt)
    const int tier = (ws_size >= need2) ? 2 : ((ws_size >= need1) ? 1 : 0);

    k_detect<<<1, 256, 0, stream>>>((const u16*)X, flag);
    k_zero<<<8, 256, 0, stream>>>(W);
    k_emb<<<9, 256, 0, stream>>>(rel, fidx, flag, qe, keT, ve, qe2, keT2);
    k_gram<<<256, 256, 0, stream>>>(X, flag, musum, gram);
    k_fold<<<1, 256, 0, stream>>>(Wkv, Wq, gkv, bkv, gq, bq, flag, musum, gram, weff, weffh, beff);
    if (tier > 0) {
        k_mtab<<<1, 128, 0, stream>>>(rel, flag, mq, mk, e1q, e1k);
        if (tier == 2) {
            k_xpose<<<dim3(48, 36), 256, 0, stream>>>(X, flag, Xt);
            k_stage1m<<<2304, 256, 0, stream>>>(Xt, weffh, beff, mq, mk, e1q, e1k, sstat, qkv);
        } else {
            k_stage1<<<2304, 256, 0, stream>>>(X, weff, beff, mq, mk, e1q, e1k, flag, sstat, qkv);
        }
        k_simcoef<<<1, 32, 0, stream>>>(sstat, gsim, fqrp, fkrp, flag, 0, scoef);
        k_attn2<<<dim3(2304, 8), 128, 0, stream>>>(qkv, qe2, keT2, ve, scoef,
                                                   fqrp, fkrp, fsvp, fsvep, flag, ostat, pre2);
        k_outcoef<<<1, 256, 0, stream>>>(ostat, gout, bout, flag, ocoef);
        k_final<<<dim3(128, 48), 256, 0, stream>>>(pre2, ocoef, flag, d_out);
    } else {
        k_qkstat<<<2304, 256, 0, stream>>>(X, weff, beff, qe, keT, fqrp, fkrp, flag, sstat);
        k_simcoef<<<1, 32, 0, stream>>>(sstat, gsim, fqrp, fkrp, flag, 1, scoef);
        k_attn<<<2304, 256, 0, stream>>>(X, weff, beff, qe, keT, ve, scoef, ocoef,
                                         fqrp, fkrp, fsvp, fsvep, flag, ostat, d_out, 0);
        k_outcoef<<<1, 256, 0, stream>>>(ostat, gout, bout, flag, ocoef);
        k_attn<<<2304, 256, 0, stream>>>(X, weff, beff, qe, keT, ve, scoef, ocoef,
                                         fqrp, fkrp, fsvp, fsvep, flag, ostat, d_out, 2);
    }
}

// Round 8
// 1012.251 us; speedup vs baseline: 1.0470x; 1.0470x over previous
//
#include <hip/hip_runtime.h>

// RelativeAxialAttention on MI355X (gfx950). Single-attention-pass design.
// K=48, G=8, DK=8, DV=16, CIN=64, B = 2304.
//
// Math shortcuts:
//  * kv/q BatchNorm folded into GEMM weights via x-gram.
//  * sim BN: softmax-invariant mean/beta; scales from CLOSED-FORM moments
//    (grams + Toeplitz windowed outer-products, k_mtab) -- no logits pass.
//  * k_stage1 GEMM on MFMA bf16 (stage1m) with X pre-transposed (k_xpose).
//  * k_attn3 (round 8): six VALU variants of attention were time-invariant at
//    ~550-650us (VALUBusy 22-35%, HBM 2%, occupancy/conflicts/table-placement
//    all ruled out) => the serial per-thread FMA+gather model is the binder.
//    Rewrite per (b,g) as ONE WAVE of MFMAs using stage1m's verified frag maps:
//      QK   = q^T k                 [48x8]x[8x48]  (K pad 32, lanes>=16 zero)
//      QR   = q^T rel_q             [48x8]x[8x96]; zr[i][j]=QR[i][i-j+47]
//      KR   = k^T rel_k             (banded store qrB/krB[i][47-j])
//      SV   = P(bf16) v^T           [48x64]x[64x16]
//      SVE  = Zd rel_v^T            [48x96]x[96x16], Zd[i][i+47-j]=P[i][j]
//    Softmax 48 rows fully in-register. Single-wave => barriers are trivial.
// Tiers: ws>=129.5MB full path; >=113.5MB VALU stage1; else recompute fallback.

typedef unsigned short u16;
typedef __attribute__((ext_vector_type(8))) short short8v;
typedef __attribute__((ext_vector_type(4))) float float4v;

#define N_S 110592
#define N_B 2304

__device__ __forceinline__ float b2f(u16 v) {
    return __builtin_bit_cast(float, ((unsigned)v) << 16);
}
__device__ __forceinline__ u16 f2b(float f) {
    unsigned u = __builtin_bit_cast(unsigned, f);
    u = (u + 0x7FFFu + ((u >> 16) & 1u)) >> 16;
    return (u16)u;
}
__device__ __forceinline__ float ldf(const void* p, int idx, int f32) {
    return f32 ? ((const float*)p)[idx] : b2f(((const u16*)p)[idx]);
}

// ---------------- dtype detection ----------------
__global__ void k_detect(const u16* X, int* flag) {
    __shared__ int tot;
    if (threadIdx.x == 0) tot = 0;
    __syncthreads();
    int cnt = 0;
#pragma unroll
    for (int k = 0; k < 8; k++) {
        u16 v = X[(threadIdx.x * 8 + k) * 2];
        int e = (v >> 7) & 0xFF;
        cnt += (e >= 0x70 && e <= 0x8F) ? 1 : 0;
    }
    atomicAdd(&tot, cnt);
    __syncthreads();
    if (threadIdx.x == 0) flag[0] = (tot < 1024) ? 1 : 0;   // 1 = f32
}

// ---------------- zero stats region ----------------
__global__ void k_zero(float* w) {
    for (int i = blockIdx.x * blockDim.x + threadIdx.x; i < 4720; i += gridDim.x * blockDim.x)
        w[i] = 0.0f;
}

// ---------------- build emb tables ----------------
// qe/keT/ve (c-major, fallback) + raw Toeplitz rel tables for k_attn3:
//   rq2[d*8+c], rk2[d*8+c] (d<96, row 95 zero), rv2[c*96+d] (col 95 zero)
__global__ void k_emb(const void* rel, const int* fidx, const int* flag,
                      u16* qe, u16* keT, u16* ve, u16* rq2, u16* rk2, u16* rv2) {
    int f32 = flag[0];
    if (blockIdx.x == 0 && threadIdx.x < 96) {
        int d = threadIdx.x;
#pragma unroll
        for (int c = 0; c < 8; c++) {
            rq2[d * 8 + c] = (d < 95) ? f2b(ldf(rel, c * 95 + d, f32)) : (u16)0;
            rk2[d * 8 + c] = (d < 95) ? f2b(ldf(rel, (8 + c) * 95 + d, f32)) : (u16)0;
        }
#pragma unroll
        for (int c = 0; c < 16; c++)
            rv2[c * 96 + d] = (d < 95) ? f2b(ldf(rel, (16 + c) * 95 + d, f32)) : (u16)0;
    }
    int t = blockIdx.x * 256 + threadIdx.x;
    if (t >= 2304) return;
    int i = t / 48, j = t % 48;
    int fij = fidx[i * 48 + j];
    int fji = fidx[j * 48 + i];
#pragma unroll
    for (int c = 0; c < 8; c++) {
        qe[c * 2304 + t]  = f2b(ldf(rel, c * 95 + fij, f32));
        keT[c * 2304 + t] = f2b(ldf(rel, (8 + c) * 95 + fji, f32));
    }
#pragma unroll
    for (int c = 0; c < 16; c++)
        ve[c * 2304 + t] = f2b(ldf(rel, (16 + c) * 95 + fij, f32));
}

// ---------------- Toeplitz moment tables ----------------
__global__ void k_mtab(const void* rel, const int* flag,
                       float* mq, float* mk, float* e1q, float* e1k) {
    __shared__ float rl[1520];
    int f32 = flag[0];
    int tid = threadIdx.x;
    for (int idx = tid; idx < 1520; idx += 128) rl[idx] = ldf(rel, idx, f32);
    __syncthreads();
    if (tid >= 96) return;
    int tbl = tid / 48, i = tid % 48;
    const float* R = rl + tbl * 760;
    float* M = (tbl ? mk : mq) + i * 40;
    float* E = (tbl ? e1k : e1q) + i * 8;
    float acc[36], e[8];
#pragma unroll
    for (int x = 0; x < 36; x++) acc[x] = 0.0f;
#pragma unroll
    for (int c = 0; c < 8; c++) e[c] = 0.0f;
    for (int d = i; d < i + 48; d++) {
        float v[8];
#pragma unroll
        for (int c = 0; c < 8; c++) { v[c] = R[c * 95 + d]; e[c] += v[c]; }
        int idx = 0;
#pragma unroll
        for (int c = 0; c < 8; c++)
#pragma unroll
            for (int c2 = c; c2 < 8; c2++) { acc[idx] += v[c] * v[c2]; idx++; }
    }
    int idx = 0;
#pragma unroll
    for (int c = 0; c < 8; c++) {
        E[c] = e[c];
#pragma unroll
        for (int c2 = c; c2 < 8; c2++) {
            M[idx] = (c2 == c ? 1.0f : 2.0f) * acc[idx];
            idx++;
        }
    }
}

// ---------------- x gram ----------------
__global__ __launch_bounds__(256) void k_gram(const void* Xv, const int* flag,
                                              float* musum, float* gram) {
    __shared__ float xs[64 * 65];
    int f32 = flag[0];
    int tid = threadIdx.x;
    int cb1 = tid >> 4, cb2 = tid & 15;
    float acc[4][4];
#pragma unroll
    for (int a = 0; a < 4; a++)
#pragma unroll
        for (int b = 0; b < 4; b++) acc[a][b] = 0.0f;
    float mur = 0.0f;
    for (int tile = blockIdx.x; tile < 1728; tile += gridDim.x) {
        int s0 = tile * 64;
        __syncthreads();
#pragma unroll
        for (int r = 0; r < 4; r++) {
            int idx4 = tid + 256 * r;
            int c = idx4 >> 4, sl = (idx4 & 15) * 4;
            if (f32) {
                float4 u = *(const float4*)((const float*)Xv + c * N_S + s0 + sl);
                xs[c * 65 + sl + 0] = u.x; xs[c * 65 + sl + 1] = u.y;
                xs[c * 65 + sl + 2] = u.z; xs[c * 65 + sl + 3] = u.w;
            } else {
                ushort4 u = *(const ushort4*)((const u16*)Xv + c * N_S + s0 + sl);
                xs[c * 65 + sl + 0] = b2f(u.x); xs[c * 65 + sl + 1] = b2f(u.y);
                xs[c * 65 + sl + 2] = b2f(u.z); xs[c * 65 + sl + 3] = b2f(u.w);
            }
        }
        __syncthreads();
        for (int s = 0; s < 64; s++) {
            float av[4], bv[4];
#pragma unroll
            for (int a = 0; a < 4; a++) av[a] = xs[(cb1 + 16 * a) * 65 + s];
#pragma unroll
            for (int b = 0; b < 4; b++) bv[b] = xs[(cb2 + 16 * b) * 65 + s];
#pragma unroll
            for (int a = 0; a < 4; a++)
#pragma unroll
                for (int b = 0; b < 4; b++) acc[a][b] += av[a] * bv[b];
        }
        if (tid < 64) {
            for (int s = 0; s < 64; s++) mur += xs[tid * 65 + s];
        }
    }
#pragma unroll
    for (int a = 0; a < 4; a++)
#pragma unroll
        for (int b = 0; b < 4; b++)
            atomicAdd(&gram[(cb1 + 16 * a) * 64 + (cb2 + 16 * b)], acc[a][b]);
    if (tid < 64) atomicAdd(&musum[tid], mur);
}

// ---------------- fold BN into weights (f32 + bf16 copies) ----------------
__global__ __launch_bounds__(256) void k_fold(const void* Wkv, const void* Wq,
        const void* gkv, const void* bkv, const void* gq, const void* bq,
        const int* flag, const float* musum, const float* gram,
        float* weff, u16* weffh, float* beff) {
    int f32 = flag[0];
    int o = threadIdx.x;
    float gam, bet;
    float w[64];
    if (o < 192) {
#pragma unroll
        for (int c = 0; c < 64; c++) w[c] = ldf(Wkv, o * 64 + c, f32);
        gam = ldf(gkv, o, f32); bet = ldf(bkv, o, f32);
    } else {
        int oq = o - 192;
#pragma unroll
        for (int c = 0; c < 64; c++) w[c] = ldf(Wq, oq * 64 + c, f32);
        gam = ldf(gq, oq, f32); bet = ldf(bq, oq, f32);
    }
    const float inv = 1.0f / (float)N_S;
    float mean = 0.0f;
#pragma unroll
    for (int c = 0; c < 64; c++) mean += w[c] * musum[c];
    mean *= inv;
    float e2 = 0.0f;
    for (int c = 0; c < 64; c++) {
        float t = 0.0f;
#pragma unroll
        for (int c2 = 0; c2 < 64; c2++) t += w[c2] * gram[c * 64 + c2];
        e2 += w[c] * t;
    }
    e2 *= inv;
    float var = e2 - mean * mean;
    if (var < 0.0f) var = 0.0f;
    float sc = gam * rsqrtf(var + 1e-5f);
#pragma unroll
    for (int c = 0; c < 64; c++) {
        float wv = sc * w[c];
        weff[o * 64 + c] = wv;
        weffh[o * 64 + c] = f2b(wv);
    }
    beff[o] = bet - sc * mean;
}

// ---------------- transpose X -> Xt[b][h][c] bf16, h-stride 72 ----------------
__global__ __launch_bounds__(256) void k_xpose(const void* Xv, const int* flag, u16* Xt) {
    __shared__ float tile[64][65];
    int f32 = flag[0];
    int h = blockIdx.x, b0 = blockIdx.y * 64, tid = threadIdx.x;
#pragma unroll
    for (int r = 0; r < 4; r++) {
        int idx = tid + 256 * r;
        int c = idx >> 4, bq = (idx & 15) * 4;
        if (f32) {
            float4 u = *(const float4*)((const float*)Xv + (size_t)c * N_S + h * 2304 + b0 + bq);
            tile[c][bq + 0] = u.x; tile[c][bq + 1] = u.y;
            tile[c][bq + 2] = u.z; tile[c][bq + 3] = u.w;
        } else {
            ushort4 u = *(const ushort4*)((const u16*)Xv + (size_t)c * N_S + h * 2304 + b0 + bq);
            tile[c][bq + 0] = b2f(u.x); tile[c][bq + 1] = b2f(u.y);
            tile[c][bq + 2] = b2f(u.z); tile[c][bq + 3] = b2f(u.w);
        }
    }
    __syncthreads();
#pragma unroll
    for (int r = 0; r < 4; r++) {
        int idx = tid + 256 * r;
        int bb = idx >> 4, cq = (idx & 15) * 4;
        ushort4 o4 = make_ushort4(f2b(tile[cq + 0][bb]), f2b(tile[cq + 1][bb]),
                                  f2b(tile[cq + 2][bb]), f2b(tile[cq + 3][bb]));
        *(ushort4*)(Xt + (size_t)(b0 + bb) * 3456 + h * 72 + cq) = o4;
    }
}

// ================= FAST PATH (tier 2) =================
// stage1m: MFMA qkv GEMM + closed-form sim-BN moments.
__global__ __launch_bounds__(256) void k_stage1m(const u16* Xt, const u16* weffh, const float* beff,
        const float* mq, const float* mk, const float* e1q, const float* e1k,
        float* sstat, u16* qkv) {
    __shared__ __align__(16) u16 xs[3456];      // [h][72] bf16
    __shared__ __align__(16) u16 qkbf[6144];    // q at [(g*8+c)*48+i], k at +3072
    __shared__ float sbias[256];
    __shared__ float red[48];
    int b = blockIdx.x, tid = threadIdx.x;
    {
        const uint4* src = (const uint4*)(Xt + (size_t)b * 3456);
        uint4* dst = (uint4*)xs;
        for (int idx = tid; idx < 432; idx += 256) dst[idx] = src[idx];
    }
    sbias[tid] = beff[tid];
    if (tid < 48) red[tid] = 0.0f;
    __syncthreads();
    {
        int wv = tid >> 6, l = tid & 63;
        int lm = l & 15, lk8 = (l >> 4) * 8;
        short8v Bf[3][2];
#pragma unroll
        for (int ct = 0; ct < 3; ct++)
#pragma unroll
            for (int ks = 0; ks < 2; ks++)
                Bf[ct][ks] = *(const short8v*)(xs + (ct * 16 + lm) * 72 + ks * 32 + lk8);
        float4v acc[4][3];
#pragma unroll
        for (int a = 0; a < 4; a++)
#pragma unroll
            for (int c = 0; c < 3; c++)
#pragma unroll
                for (int e = 0; e < 4; e++) acc[a][c][e] = 0.0f;
#pragma unroll
        for (int rt = 0; rt < 4; rt++) {
            int orow = wv * 64 + rt * 16 + lm;
#pragma unroll
            for (int ks = 0; ks < 2; ks++) {
                short8v Af = *(const short8v*)(weffh + orow * 64 + ks * 32 + lk8);
#pragma unroll
                for (int ct = 0; ct < 3; ct++)
                    acc[rt][ct] = __builtin_amdgcn_mfma_f32_16x16x32_bf16(Af, Bf[ct][ks], acc[rt][ct], 0, 0, 0);
            }
        }
        int rbase = (l >> 4) * 4;
        u16* qdst = qkv + (size_t)b * 12288;
#pragma unroll
        for (int rt = 0; rt < 4; rt++) {
#pragma unroll
            for (int ct = 0; ct < 3; ct++) {
                int h = ct * 16 + lm;
#pragma unroll
                for (int rg = 0; rg < 4; rg++) {
                    int o = wv * 64 + rt * 16 + rbase + rg;
                    u16 vb = f2b(acc[rt][ct][rg] + sbias[o]);
                    int row, lq = -1;
                    if (o >= 192) {
                        int g = (o - 192) >> 3, c = (o - 192) & 7;
                        row = g * 32 + c;
                        lq = (g * 8 + c) * 48;
                    } else {
                        int g = o / 24, t = o % 24;
                        if (t < 8) { row = g * 32 + 8 + t; lq = 3072 + (g * 8 + t) * 48; }
                        else       { row = g * 32 + 16 + (t - 8); }
                    }
                    qdst[row * 48 + h] = vb;
                    if (lq >= 0) qkbf[lq + h] = vb;
                }
            }
        }
    }
    __syncthreads();
    {
        int g = tid >> 5, t = tid & 31;
        float gq[36], gk[36], sq[8], sk[8];
        float s1qr = 0, s1kr = 0, s2qr = 0, s2kr = 0;
#pragma unroll
        for (int x = 0; x < 36; x++) { gq[x] = 0.0f; gk[x] = 0.0f; }
#pragma unroll
        for (int c = 0; c < 8; c++) { sq[c] = 0.0f; sk[c] = 0.0f; }
#pragma unroll
        for (int pass = 0; pass < 2; pass++) {
            int i = t + pass * 32;
            if (i >= 48) break;
            float qv[8], kvv[8];
#pragma unroll
            for (int c = 0; c < 8; c++) {
                qv[c]  = b2f(qkbf[(g * 8 + c) * 48 + i]);
                kvv[c] = b2f(qkbf[3072 + (g * 8 + c) * 48 + i]);
            }
            const float* mqr = mq + i * 40;
            const float* mkr = mk + i * 40;
            const float* eqr = e1q + i * 8;
            const float* ekr = e1k + i * 8;
            int idx = 0;
#pragma unroll
            for (int c = 0; c < 8; c++) {
                sq[c] += qv[c]; sk[c] += kvv[c];
                s1qr += qv[c] * eqr[c];
                s1kr += kvv[c] * ekr[c];
#pragma unroll
                for (int c2 = c; c2 < 8; c2++) {
                    float oq = qv[c] * qv[c2], ok = kvv[c] * kvv[c2];
                    gq[idx] += oq; gk[idx] += ok;
                    s2qr += mqr[idx] * oq;
                    s2kr += mkr[idx] * ok;
                    idx++;
                }
            }
        }
#pragma unroll
        for (int off = 1; off <= 16; off <<= 1) {
#pragma unroll
            for (int x = 0; x < 36; x++) { gq[x] += __shfl_xor(gq[x], off); gk[x] += __shfl_xor(gk[x], off); }
#pragma unroll
            for (int c = 0; c < 8; c++) { sq[c] += __shfl_xor(sq[c], off); sk[c] += __shfl_xor(sk[c], off); }
            s1qr += __shfl_xor(s1qr, off); s1kr += __shfl_xor(s1kr, off);
            s2qr += __shfl_xor(s2qr, off); s2kr += __shfl_xor(s2kr, off);
        }
        if (t == 0) {
            float s1qk = 0.0f, s2qk = 0.0f;
            int idx = 0;
#pragma unroll
            for (int c = 0; c < 8; c++) {
                s1qk += sq[c] * sk[c];
#pragma unroll
                for (int c2 = c; c2 < 8; c2++) {
                    float w = (c2 == c) ? 1.0f : 2.0f;
                    s2qk += w * gq[idx] * gk[idx];
                    idx++;
                }
            }
            red[0 * 8 + g] = s1qk;  red[1 * 8 + g] = s1qr;  red[2 * 8 + g] = s1kr;
            red[3 * 8 + g] = s2qk;  red[4 * 8 + g] = s2qr;  red[5 * 8 + g] = s2kr;
        }
    }
    __syncthreads();
    if (tid < 48) atomicAdd(&sstat[tid], red[tid]);
}

// ================= tier-1 stage1 (VALU, reads X directly) =================
__global__ __launch_bounds__(256) void k_stage1(const void* Xv, const float* weff, const float* beff,
        const float* mq, const float* mk, const float* e1q, const float* e1k,
        const int* flag, float* sstat, u16* qkv) {
    __shared__ __align__(16) float xs[3072];
    __shared__ __align__(16) float qk[6144];
    __shared__ float red[48];
    int f32 = flag[0];
    int b = blockIdx.x, tid = threadIdx.x;
    for (int idx = tid; idx < 3072; idx += 256) {
        int c = idx / 48, h = idx % 48;
        xs[idx] = ldf(Xv, c * N_S + h * 2304 + b, f32);
    }
    __syncthreads();
    {
        int g = tid >> 5, r = tid & 31;
        int o;
        if (r < 8)       o = 192 + g * 8 + r;
        else if (r < 16) o = g * 24 + (r - 8);
        else             o = g * 24 + 8 + (r - 16);
        float wr[64];
        const float4* wrow = (const float4*)(weff + o * 64);
#pragma unroll
        for (int c4 = 0; c4 < 16; c4++) {
            float4 t4 = wrow[c4];
            wr[c4 * 4 + 0] = t4.x; wr[c4 * 4 + 1] = t4.y; wr[c4 * 4 + 2] = t4.z; wr[c4 * 4 + 3] = t4.w;
        }
        float bias = beff[o];
        u16* gdst = qkv + (b * 256 + tid) * 48;
        float* ldst = (r < 8) ? (qk + g * 768 + r * 48)
                    : (r < 16 ? (qk + g * 768 + 384 + (r - 8) * 48) : nullptr);
#pragma unroll
        for (int hb = 0; hb < 6; hb++) {
            float acc[8];
#pragma unroll
            for (int u = 0; u < 8; u++) acc[u] = bias;
#pragma unroll
            for (int c = 0; c < 64; c++) {
                float wv = wr[c];
                const float4* xp = (const float4*)(xs + c * 48 + hb * 8);
                float4 x0 = xp[0], x1 = xp[1];
                acc[0] += wv * x0.x; acc[1] += wv * x0.y; acc[2] += wv * x0.z; acc[3] += wv * x0.w;
                acc[4] += wv * x1.x; acc[5] += wv * x1.y; acc[6] += wv * x1.z; acc[7] += wv * x1.w;
            }
            ushort4 p0 = make_ushort4(f2b(acc[0]), f2b(acc[1]), f2b(acc[2]), f2b(acc[3]));
            ushort4 p1 = make_ushort4(f2b(acc[4]), f2b(acc[5]), f2b(acc[6]), f2b(acc[7]));
            *(ushort4*)(gdst + hb * 8)     = p0;
            *(ushort4*)(gdst + hb * 8 + 4) = p1;
            if (ldst) {
                *(float4*)(ldst + hb * 8)     = make_float4(acc[0], acc[1], acc[2], acc[3]);
                *(float4*)(ldst + hb * 8 + 4) = make_float4(acc[4], acc[5], acc[6], acc[7]);
            }
        }
    }
    __syncthreads();
    {
        int g = tid >> 5, t = tid & 31;
        float gq[36], gk[36], sq[8], sk[8];
        float s1qr = 0, s1kr = 0, s2qr = 0, s2kr = 0;
#pragma unroll
        for (int x = 0; x < 36; x++) { gq[x] = 0.0f; gk[x] = 0.0f; }
#pragma unroll
        for (int c = 0; c < 8; c++) { sq[c] = 0.0f; sk[c] = 0.0f; }
#pragma unroll
        for (int pass = 0; pass < 2; pass++) {
            int i = t + pass * 32;
            if (i >= 48) break;
            float qv[8], kvv[8];
#pragma unroll
            for (int c = 0; c < 8; c++) {
                qv[c]  = qk[g * 768 + c * 48 + i];
                kvv[c] = qk[g * 768 + 384 + c * 48 + i];
            }
            const float* mqr = mq + i * 40;
            const float* mkr = mk + i * 40;
            const float* eqr = e1q + i * 8;
            const float* ekr = e1k + i * 8;
            int idx = 0;
#pragma unroll
            for (int c = 0; c < 8; c++) {
                sq[c] += qv[c]; sk[c] += kvv[c];
                s1qr += qv[c] * eqr[c];
                s1kr += kvv[c] * ekr[c];
#pragma unroll
                for (int c2 = c; c2 < 8; c2++) {
                    float oq = qv[c] * qv[c2], ok = kvv[c] * kvv[c2];
                    gq[idx] += oq; gk[idx] += ok;
                    s2qr += mqr[idx] * oq;
                    s2kr += mkr[idx] * ok;
                    idx++;
                }
            }
        }
#pragma unroll
        for (int off = 1; off <= 16; off <<= 1) {
#pragma unroll
            for (int x = 0; x < 36; x++) { gq[x] += __shfl_xor(gq[x], off); gk[x] += __shfl_xor(gk[x], off); }
#pragma unroll
            for (int c = 0; c < 8; c++) { sq[c] += __shfl_xor(sq[c], off); sk[c] += __shfl_xor(sk[c], off); }
            s1qr += __shfl_xor(s1qr, off); s1kr += __shfl_xor(s1kr, off);
            s2qr += __shfl_xor(s2qr, off); s2kr += __shfl_xor(s2kr, off);
        }
        if (t == 0) {
            float s1qk = 0.0f, s2qk = 0.0f;
            int idx = 0;
#pragma unroll
            for (int c = 0; c < 8; c++) {
                s1qk += sq[c] * sk[c];
#pragma unroll
                for (int c2 = c; c2 < 8; c2++) {
                    float w = (c2 == c) ? 1.0f : 2.0f;
                    s2qk += w * gq[idx] * gk[idx];
                    idx++;
                }
            }
            red[0 * 8 + g] = s1qk;  red[1 * 8 + g] = s1qr;  red[2 * 8 + g] = s1kr;
            red[3 * 8 + g] = s2qk;  red[4 * 8 + g] = s2qr;  red[5 * 8 + g] = s2kr;
        }
    }
    __syncthreads();
    if (tid < 48) atomicAdd(&sstat[tid], red[tid]);
}

// scaled=1: sstat already includes fqr/fkr (fallback). scaled=0: apply here.
__global__ void k_simcoef(const float* sstat, const void* gsim, const void* fqrp, const void* fkrp,
                          const int* flag, int scaled, float* scoef) {
    int ch = threadIdx.x;
    if (ch >= 24) return;
    int f32 = flag[0];
    float f = 1.0f;
    if (!scaled) {
        if (ch >= 16)     f = ldf(fkrp, 0, f32);
        else if (ch >= 8) f = ldf(fqrp, 0, f32);
    }
    const float n = 2304.0f * 2304.0f;
    float mean = f * sstat[ch] / n;
    float var = f * f * sstat[24 + ch] / n - mean * mean;
    if (var < 0.0f) var = 0.0f;
    scoef[ch] = ldf(gsim, ch, f32) * rsqrtf(var + 1e-5f);
}

// attn3: one WAVE per (b, g). All heavy phases on MFMA. LDS ~34.6KB -> 4 blk/CU.
__global__ __launch_bounds__(64) void k_attn3(const u16* qkv,
        const u16* rq2, const u16* rk2, const u16* rv2,
        const float* scoef, const void* fqrp, const void* fkrp,
        const void* fsvp, const void* fsvep, const int* flag,
        float* ostat, u16* pre2) {
    __shared__ __align__(16) u16 qT[384];     // [i][c]
    __shared__ __align__(16) u16 kT[384];     // [j][c]
    __shared__ __align__(16) u16 vls[768];    // [c][j]
    __shared__ __align__(16) u16 rvC[1536];   // [c][d<96]
    __shared__ __align__(16) float zf[2496];  // [48][52]
    __shared__ __align__(16) u16 R1[9216];    // union {rqT,rkT,qrB,krB} -> {zb,zd}
    int f32 = flag[0];
    int b = blockIdx.x, g = blockIdx.y, tid = threadIdx.x;
    int lr = tid & 15, lk = tid >> 4;
    u16* rqT = R1;              // [d<96][c]
    u16* rkT = R1 + 768;
    u16* qrB = R1 + 1536;       // [i][dd<48]
    u16* krB = R1 + 3840;
    const u16* src = qkv + (b * 256 + g * 32) * 48;
    // stage q,k transposed [h][c]
#pragma unroll
    for (int e = 0; e < 6; e++) {
        int idx = tid + 64 * e;
        int c = idx / 48, h = idx % 48;
        qT[h * 8 + c] = src[c * 48 + h];
        kT[h * 8 + c] = src[(8 + c) * 48 + h];
    }
    // stage v [c][j] (contiguous copy) + rel tables
#pragma unroll
    for (int e = 0; e < 2; e++) {
        int idx = tid + 64 * e;
        if (idx < 96) {
            ((uint4*)vls)[idx] = ((const uint4*)(src + 768))[idx];
            ((uint4*)rqT)[idx] = ((const uint4*)rq2)[idx];
            ((uint4*)rkT)[idx] = ((const uint4*)rk2)[idx];
        }
    }
#pragma unroll
    for (int e = 0; e < 3; e++)
        ((uint4*)rvC)[tid + 64 * e] = ((const uint4*)rv2)[tid + 64 * e];
    __syncthreads();
    short8v z8 = {0, 0, 0, 0, 0, 0, 0, 0};
    // A-frags (K=8 padded to 32: only lanes lk==0 carry data)
    short8v aq[3], ak[3];
#pragma unroll
    for (int tm = 0; tm < 3; tm++) {
        aq[tm] = (lk == 0) ? *(const short8v*)(qT + (tm * 16 + lr) * 8) : z8;
        ak[tm] = (lk == 0) ? *(const short8v*)(kT + (tm * 16 + lr) * 8) : z8;
    }
    // QR = q^T rel_q, KR = k^T rel_k -> banded stores
#pragma unroll
    for (int tn = 0; tn < 6; tn++) {
        short8v bq = (lk == 0) ? *(const short8v*)(rqT + (tn * 16 + lr) * 8) : z8;
        short8v bk = (lk == 0) ? *(const short8v*)(rkT + (tn * 16 + lr) * 8) : z8;
#pragma unroll
        for (int tm = 0; tm < 3; tm++) {
            float4v a0 = {0, 0, 0, 0}, a1 = {0, 0, 0, 0};
            a0 = __builtin_amdgcn_mfma_f32_16x16x32_bf16(aq[tm], bq, a0, 0, 0, 0);
            a1 = __builtin_amdgcn_mfma_f32_16x16x32_bf16(ak[tm], bk, a1, 0, 0, 0);
#pragma unroll
            for (int r = 0; r < 4; r++) {
                int i = tm * 16 + lk * 4 + r;
                int dd = tn * 16 + lr - i;
                if (dd >= 0 && dd < 48) {
                    qrB[i * 48 + dd] = f2b(a0[r]);
                    krB[i * 48 + dd] = f2b(a1[r]);
                }
            }
        }
    }
    // QK = q^T k (kept in regs)
    float4v qk[3][3];
#pragma unroll
    for (int tn = 0; tn < 3; tn++) {
        short8v bkf = (lk == 0) ? *(const short8v*)(kT + (tn * 16 + lr) * 8) : z8;
#pragma unroll
        for (int tm = 0; tm < 3; tm++) {
            float4v a = {0, 0, 0, 0};
            qk[tm][tn] = __builtin_amdgcn_mfma_f32_16x16x32_bf16(aq[tm], bkf, a, 0, 0, 0);
        }
    }
    __syncthreads();
    float fqr = ldf(fqrp, 0, f32), fkr = ldf(fkrp, 0, f32);
    float fsv = ldf(fsvp, 0, f32), fsve = ldf(fsvep, 0, f32);
    float c0 = scoef[g], c1f = scoef[8 + g] * fqr, c2f = scoef[16 + g] * fkr;
    // combine: z = c0*qk + c1f*QR[i][i-j+47] + c2f*KR[j][j-i+47]
#pragma unroll
    for (int tm = 0; tm < 3; tm++)
#pragma unroll
        for (int tn = 0; tn < 3; tn++)
#pragma unroll
            for (int r = 0; r < 4; r++) {
                int i = tm * 16 + lk * 4 + r, j = tn * 16 + lr;
                float zv = c0 * qk[tm][tn][r]
                         + c1f * b2f(qrB[i * 48 + 47 - j])
                         + c2f * b2f(krB[j * 48 + 47 - i]);
                zf[i * 52 + j] = zv;
            }
    __syncthreads();
    // re-purpose R1: zero it for zb/zd
#pragma unroll
    for (int e = 0; e < 18; e++) {
        uint4 zz = {0, 0, 0, 0};
        ((uint4*)R1)[tid + 64 * e] = zz;
    }
    __syncthreads();
    u16* zb = R1;          // [i][96], cols 0..47 = P, 48..63 zero (K-pad)
    u16* zd = R1 + 4608;   // [i][96], zd[i][i+47-j] = P[i][j]
    if (tid < 48) {
        int i = tid;
        float p[48];
#pragma unroll
        for (int k4 = 0; k4 < 12; k4++) {
            float4 t4 = *(const float4*)(zf + i * 52 + k4 * 4);
            p[k4 * 4 + 0] = t4.x; p[k4 * 4 + 1] = t4.y;
            p[k4 * 4 + 2] = t4.z; p[k4 * 4 + 3] = t4.w;
        }
        float m = p[0];
#pragma unroll
        for (int k = 1; k < 48; k++) m = fmaxf(m, p[k]);
        float s = 0.0f;
#pragma unroll
        for (int k = 0; k < 48; k++) { p[k] = __expf(p[k] - m); s += p[k]; }
        float inv = 1.0f / s;
#pragma unroll
        for (int k = 0; k < 48; k++) p[k] *= inv;
#pragma unroll
        for (int k4 = 0; k4 < 12; k4++)
            *(ushort4*)(zb + i * 96 + k4 * 4) =
                make_ushort4(f2b(p[k4 * 4]), f2b(p[k4 * 4 + 1]), f2b(p[k4 * 4 + 2]), f2b(p[k4 * 4 + 3]));
#pragma unroll
        for (int j = 0; j < 48; j++)
            zd[i * 96 + i + 47 - j] = f2b(p[j]);
    }
    __syncthreads();
    // SV = P v^T (K=64, pad), SVE = Zd rel_v^T (K=96)
    float4v sv[3], se[3];
#pragma unroll
    for (int tm = 0; tm < 3; tm++) { sv[tm] = (float4v){0,0,0,0}; se[tm] = (float4v){0,0,0,0}; }
#pragma unroll
    for (int ks = 0; ks < 2; ks++) {
        short8v bv = (ks == 0 || lk < 2) ? *(const short8v*)(vls + lr * 48 + ks * 32 + lk * 8) : z8;
#pragma unroll
        for (int tm = 0; tm < 3; tm++) {
            short8v af = *(const short8v*)(zb + (tm * 16 + lr) * 96 + ks * 32 + lk * 8);
            sv[tm] = __builtin_amdgcn_mfma_f32_16x16x32_bf16(af, bv, sv[tm], 0, 0, 0);
        }
    }
#pragma unroll
    for (int ks = 0; ks < 3; ks++) {
        short8v br = *(const short8v*)(rvC + lr * 96 + ks * 32 + lk * 8);
#pragma unroll
        for (int tm = 0; tm < 3; tm++) {
            short8v ad = *(const short8v*)(zd + (tm * 16 + lr) * 96 + ks * 32 + lk * 8);
            se[tm] = __builtin_amdgcn_mfma_f32_16x16x32_bf16(ad, br, se[tm], 0, 0, 0);
        }
    }
    // epilogue: lane holds (c=lr, 12 i's); write pre2 pairs + stats
    int c = lr;
    float sA = 0, qA = 0, sB = 0, qB = 0;
    u16* pdst = pre2 + ((b * 128 + g * 16 + c) * 48) * 2;
#pragma unroll
    for (int tm = 0; tm < 3; tm++)
#pragma unroll
        for (int r = 0; r < 4; r++) {
            int i = tm * 16 + lk * 4 + r;
            float a = sv[tm][r] * fsv, bb = se[tm][r] * fsve;
            *(ushort2*)(pdst + i * 2) = make_ushort2(f2b(a), f2b(bb));
            sA += a; qA += a * a; sB += bb; qB += bb * bb;
        }
    sA += __shfl_xor(sA, 16); qA += __shfl_xor(qA, 16);
    sB += __shfl_xor(sB, 16); qB += __shfl_xor(qB, 16);
    sA += __shfl_xor(sA, 32); qA += __shfl_xor(qA, 32);
    sB += __shfl_xor(sB, 32); qB += __shfl_xor(qB, 32);
    if (lk == 0) {
        int ch2 = g * 32 + c * 2;
        atomicAdd(&ostat[ch2 * 2 + 0], sA);
        atomicAdd(&ostat[ch2 * 2 + 1], qA);
        atomicAdd(&ostat[ch2 * 2 + 2], sB);
        atomicAdd(&ostat[ch2 * 2 + 3], qB);
    }
}

__global__ void k_outcoef(const float* ostat, const void* gout, const void* bout,
                          const int* flag, float* ocoef) {
    int f32 = flag[0];
    int o = threadIdx.x;
    const float n = 110592.0f;
    float mean = ostat[o * 2] / n;
    float var = ostat[o * 2 + 1] / n - mean * mean;
    if (var < 0.0f) var = 0.0f;
    float sc = ldf(gout, o, f32) * rsqrtf(var + 1e-5f);
    ocoef[o * 2] = sc;
    ocoef[o * 2 + 1] = ldf(bout, o, f32) - mean * sc;
}

// final: BN + pair-sum + transpose.
__global__ __launch_bounds__(256) void k_final(const u16* pre2, const float* ocoef,
                                               const int* flag, void* outp) {
    __shared__ float tile[48 * 49];
    int f32 = flag[0];
    int ch = blockIdx.x, w = blockIdx.y, tid = threadIdx.x;
    float sc0 = ocoef[(ch * 2) * 2],     sh0 = ocoef[(ch * 2) * 2 + 1];
    float sc1 = ocoef[(ch * 2 + 1) * 2], sh1 = ocoef[(ch * 2 + 1) * 2 + 1];
    float shs = sh0 + sh1;
#pragma unroll
    for (int r = 0; r < 9; r++) {
        int idx = tid + 256 * r;
        int d = idx / 48, i = idx % 48;
        ushort2 p = ((const ushort2*)pre2)[((w * 48 + d) * 128 + ch) * 48 + i];
        tile[d * 49 + i] = b2f(p.x) * sc0 + b2f(p.y) * sc1 + shs;
    }
    __syncthreads();
#pragma unroll
    for (int r = 0; r < 9; r++) {
        int idx = tid + 256 * r;
        int i = idx / 48, d = idx % 48;
        float v = tile[d * 49 + i];
        int oidx = ch * N_S + i * 2304 + w * 48 + d;
        if (f32) ((float*)outp)[oidx] = v;
        else     ((u16*)outp)[oidx] = f2b(v);
    }
}

// ================= FALLBACK PATH =================
__global__ __launch_bounds__(256) void k_qkstat(const void* Xv, const float* weff, const float* beff,
        const u16* qe, const u16* keT, const void* fqrp, const void* fkrp,
        const int* flag, float* sstat) {
    __shared__ __align__(16) float xs[3072];
    __shared__ __align__(16) float qsh[3072];
    __shared__ __align__(16) float ksh[3072];
    __shared__ float red[48];
    int f32 = flag[0];
    int b = blockIdx.x, tid = threadIdx.x;
    for (int idx = tid; idx < 3072; idx += 256) {
        int c = idx / 48, h = idx % 48;
        xs[idx] = ldf(Xv, c * N_S + h * 2304 + b, f32);
    }
    if (tid < 48) red[tid] = 0.0f;
    __syncthreads();
    {
        int r = tid >> 1, half = tid & 1;
        int o; float* dst;
        if (r < 64) { o = 192 + r; dst = qsh + r * 48; }
        else { int rk = r - 64; o = (rk >> 3) * 24 + (rk & 7); dst = ksh + rk * 48; }
        float wr[64];
        const float4* wrow = (const float4*)(weff + o * 64);
#pragma unroll
        for (int c4 = 0; c4 < 16; c4++) {
            float4 t4 = wrow[c4];
            wr[c4 * 4 + 0] = t4.x; wr[c4 * 4 + 1] = t4.y; wr[c4 * 4 + 2] = t4.z; wr[c4 * 4 + 3] = t4.w;
        }
        float bias = beff[o];
        int h0 = half * 24;
#pragma unroll
        for (int hb = 0; hb < 3; hb++) {
            float acc[8];
#pragma unroll
            for (int u = 0; u < 8; u++) acc[u] = bias;
#pragma unroll
            for (int c = 0; c < 64; c++) {
                float wv = wr[c];
                const float4* xp = (const float4*)(xs + c * 48 + h0 + hb * 8);
                float4 x0 = xp[0], x1 = xp[1];
                acc[0] += wv * x0.x; acc[1] += wv * x0.y; acc[2] += wv * x0.z; acc[3] += wv * x0.w;
                acc[4] += wv * x1.x; acc[5] += wv * x1.y; acc[6] += wv * x1.z; acc[7] += wv * x1.w;
            }
            *(float4*)(dst + h0 + hb * 8)     = make_float4(acc[0], acc[1], acc[2], acc[3]);
            *(float4*)(dst + h0 + hb * 8 + 4) = make_float4(acc[4], acc[5], acc[6], acc[7]);
        }
    }
    __syncthreads();
    float fqr = ldf(fqrp, 0, f32), fkr = ldf(fkrp, 0, f32);
    float sum[24], sq[24];
#pragma unroll
    for (int k = 0; k < 24; k++) { sum[k] = 0.0f; sq[k] = 0.0f; }
    for (int r = 0; r < 3; r++) {
        int chunk = tid + 256 * r;
        if (chunk >= 576) break;
        int i = chunk / 12, j0 = (chunk % 12) * 4;
        float qv[8][4], kv[8][4];
#pragma unroll
        for (int c = 0; c < 8; c++) {
            ushort4 uq = *(const ushort4*)(qe + c * 2304 + i * 48 + j0);
            ushort4 uk = *(const ushort4*)(keT + c * 2304 + i * 48 + j0);
            qv[c][0] = b2f(uq.x); qv[c][1] = b2f(uq.y); qv[c][2] = b2f(uq.z); qv[c][3] = b2f(uq.w);
            kv[c][0] = b2f(uk.x); kv[c][1] = b2f(uk.y); kv[c][2] = b2f(uk.z); kv[c][3] = b2f(uk.w);
        }
#pragma unroll
        for (int g = 0; g < 8; g++) {
            float zq[4] = {0,0,0,0}, zr[4] = {0,0,0,0}, zk[4] = {0,0,0,0};
#pragma unroll
            for (int c = 0; c < 8; c++) {
                float qi = qsh[(g * 8 + c) * 48 + i];
                float4 kk = *(const float4*)(ksh + (g * 8 + c) * 48 + j0);
                zq[0] += qi * kk.x; zq[1] += qi * kk.y; zq[2] += qi * kk.z; zq[3] += qi * kk.w;
                zr[0] += qi * qv[c][0]; zr[1] += qi * qv[c][1]; zr[2] += qi * qv[c][2]; zr[3] += qi * qv[c][3];
                zk[0] += kk.x * kv[c][0]; zk[1] += kk.y * kv[c][1]; zk[2] += kk.z * kv[c][2]; zk[3] += kk.w * kv[c][3];
            }
#pragma unroll
            for (int u = 0; u < 4; u++) {
                float a = zq[u];        sum[g] += a;       sq[g] += a * a;
                float r1 = zr[u] * fqr; sum[8 + g] += r1;  sq[8 + g] += r1 * r1;
                float r2 = zk[u] * fkr; sum[16 + g] += r2; sq[16 + g] += r2 * r2;
            }
        }
    }
#pragma unroll
    for (int k = 0; k < 24; k++) {
        float s = sum[k], q = sq[k];
        for (int off = 32; off >= 1; off >>= 1) { s += __shfl_xor(s, off); q += __shfl_xor(q, off); }
        if ((tid & 63) == 0) { atomicAdd(&red[k], s); atomicAdd(&red[24 + k], q); }
    }
    __syncthreads();
    if (tid < 48) atomicAdd(&sstat[tid], red[tid]);
}

__global__ __launch_bounds__(256) void k_attn(const void* Xv, const float* weff, const float* beff,
        const u16* qe, const u16* keT, const u16* ve,
        const float* scoef, const float* ocoef,
        const void* fqrp, const void* fkrp, const void* fsvp, const void* fsvep,
        const int* flag, float* ostat, void* outp, int mode) {
    __shared__ __align__(16) float zx[3072];
    __shared__ __align__(16) float qsh[3072];
    __shared__ __align__(16) float ksh[3072];
    __shared__ __align__(16) float vsh[6144];
    __shared__ float osl[512];
    int f32 = flag[0];
    int b = blockIdx.x, tid = threadIdx.x;
    for (int idx = tid; idx < 3072; idx += 256) {
        int c = idx / 48, h = idx % 48;
        zx[idx] = ldf(Xv, c * N_S + h * 2304 + b, f32);
    }
    __syncthreads();
    {
        int o; float* dst;
        if (tid < 64)       { o = 192 + tid; dst = qsh + tid * 48; }
        else if (tid < 128) { int rk = tid - 64; o = (rk >> 3) * 24 + (rk & 7); dst = ksh + rk * 48; }
        else                { int rv = tid - 128; o = (rv >> 4) * 24 + 8 + (rv & 15); dst = vsh + rv * 48; }
        float wr[64];
        const float4* wrow = (const float4*)(weff + o * 64);
#pragma unroll
        for (int c4 = 0; c4 < 16; c4++) {
            float4 t4 = wrow[c4];
            wr[c4 * 4 + 0] = t4.x; wr[c4 * 4 + 1] = t4.y; wr[c4 * 4 + 2] = t4.z; wr[c4 * 4 + 3] = t4.w;
        }
        float bias = beff[o];
#pragma unroll
        for (int hb = 0; hb < 6; hb++) {
            float acc[8];
#pragma unroll
            for (int u = 0; u < 8; u++) acc[u] = bias;
#pragma unroll
            for (int c = 0; c < 64; c++) {
                float wv = wr[c];
                const float4* xp = (const float4*)(zx + c * 48 + hb * 8);
                float4 x0 = xp[0], x1 = xp[1];
                acc[0] += wv * x0.x; acc[1] += wv * x0.y; acc[2] += wv * x0.z; acc[3] += wv * x0.w;
                acc[4] += wv * x1.x; acc[5] += wv * x1.y; acc[6] += wv * x1.z; acc[7] += wv * x1.w;
            }
            *(float4*)(dst + hb * 8)     = make_float4(acc[0], acc[1], acc[2], acc[3]);
            *(float4*)(dst + hb * 8 + 4) = make_float4(acc[4], acc[5], acc[6], acc[7]);
        }
    }
    __syncthreads();
    float fqr = ldf(fqrp, 0, f32), fkr = ldf(fkrp, 0, f32);
    float fsv = ldf(fsvp, 0, f32), fsve = ldf(fsvep, 0, f32);
    float* z = zx;
    for (int g = 0; g < 8; g++) {
        float c0 = scoef[g], c1 = scoef[8 + g], c2 = scoef[16 + g];
        for (int r = 0; r < 3; r++) {
            int chunk = tid + 256 * r;
            if (chunk >= 576) break;
            int i = chunk / 12, j0 = (chunk % 12) * 4;
            float zq[4] = {0,0,0,0}, zr[4] = {0,0,0,0}, zk[4] = {0,0,0,0};
#pragma unroll
            for (int c = 0; c < 8; c++) {
                ushort4 uq = *(const ushort4*)(qe + c * 2304 + i * 48 + j0);
                ushort4 uk = *(const ushort4*)(keT + c * 2304 + i * 48 + j0);
                float qi = qsh[(g * 8 + c) * 48 + i];
                float4 kk = *(const float4*)(ksh + (g * 8 + c) * 48 + j0);
                zq[0] += qi * kk.x; zq[1] += qi * kk.y; zq[2] += qi * kk.z; zq[3] += qi * kk.w;
                zr[0] += qi * b2f(uq.x); zr[1] += qi * b2f(uq.y); zr[2] += qi * b2f(uq.z); zr[3] += qi * b2f(uq.w);
                zk[0] += kk.x * b2f(uk.x); zk[1] += kk.y * b2f(uk.y); zk[2] += kk.z * b2f(uk.z); zk[3] += kk.w * b2f(uk.w);
            }
            float4 o4;
            o4.x = c0 * zq[0] + c1 * (fqr * zr[0]) + c2 * (fkr * zk[0]);
            o4.y = c0 * zq[1] + c1 * (fqr * zr[1]) + c2 * (fkr * zk[1]);
            o4.z = c0 * zq[2] + c1 * (fqr * zr[2]) + c2 * (fkr * zk[2]);
            o4.w = c0 * zq[3] + c1 * (fqr * zr[3]) + c2 * (fkr * zk[3]);
            *(float4*)(z + i * 52 + j0) = o4;
        }
        __syncthreads();
        {
            int wv = tid >> 6, lane = tid & 63;
            for (int rr = 0; rr < 12; rr++) {
                int i = wv * 12 + rr;
                float val = (lane < 48) ? z[i * 52 + lane] : -1e30f;
                float m = val;
                for (int off = 32; off >= 1; off >>= 1) m = fmaxf(m, __shfl_xor(m, off));
                float e = (lane < 48) ? __expf(val - m) : 0.0f;
                float s = e;
                for (int off = 32; off >= 1; off >>= 1) s += __shfl_xor(s, off);
                if (lane < 48) z[i * 52 + lane] = e / s;
            }
        }
        __syncthreads();
        {
            int c = tid >> 4, u = tid & 15;
            int ch2 = g * 32 + c * 2;
            float oc0 = 0, oc1 = 0, osh = 0;
            if (mode != 0) {
                oc0 = ocoef[ch2 * 2]; oc1 = ocoef[(ch2 + 1) * 2];
                osh = ocoef[ch2 * 2 + 1] + ocoef[(ch2 + 1) * 2 + 1];
            }
            float sumA = 0, sqA = 0, sumB = 0, sqB = 0;
#pragma unroll
            for (int r = 0; r < 3; r++) {
                int i = u + 16 * r;
                float sv = 0.0f, se = 0.0f;
#pragma unroll
                for (int j4 = 0; j4 < 12; j4++) {
                    float4 sm = *(const float4*)(z + i * 52 + j4 * 4);
                    float4 vv = *(const float4*)(vsh + (g * 16 + c) * 48 + j4 * 4);
                    ushort4 veu = *(const ushort4*)(ve + c * 2304 + i * 48 + j4 * 4);
                    sv += sm.x * vv.x + sm.y * vv.y + sm.z * vv.z + sm.w * vv.w;
                    se += sm.x * b2f(veu.x) + sm.y * b2f(veu.y) + sm.z * b2f(veu.z) + sm.w * b2f(veu.w);
                }
                float a = sv * fsv, bb = se * fsve;
                if (mode == 0) {
                    sumA += a; sqA += a * a; sumB += bb; sqB += bb * bb;
                } else {
                    float outv = a * oc0 + bb * oc1 + osh;
                    int oidx = (g * 16 + c) * N_S + i * 2304 + b;
                    if (f32) ((float*)outp)[oidx] = outv;
                    else     ((u16*)outp)[oidx] = f2b(outv);
                }
            }
            if (mode == 0) {
                for (int off = 1; off <= 8; off <<= 1) {
                    sumA += __shfl_xor(sumA, off); sqA += __shfl_xor(sqA, off);
                    sumB += __shfl_xor(sumB, off); sqB += __shfl_xor(sqB, off);
                }
                if (u == 0) {
                    int base = ch2 * 2;
                    osl[base + 0] = sumA; osl[base + 1] = sqA;
                    osl[base + 2] = sumB; osl[base + 3] = sqB;
                }
            }
        }
        __syncthreads();
    }
    if (mode == 0) {
        atomicAdd(&ostat[tid], osl[tid]);
        atomicAdd(&ostat[tid + 256], osl[tid + 256]);
    }
}

extern "C" void kernel_launch(void* const* d_in, const int* in_sizes, int n_in,
                              void* d_out, int out_size, void* d_ws, size_t ws_size,
                              hipStream_t stream) {
    const void* X    = d_in[0];
    const void* Wkv  = d_in[1];
    const void* Wq   = d_in[2];
    const void* gkv  = d_in[3];
    const void* bkv  = d_in[4];
    const void* gq   = d_in[5];
    const void* bq   = d_in[6];
    const void* gsim = d_in[7];
    const void* gout = d_in[9];
    const void* bout = d_in[10];
    const void* rel  = d_in[11];
    const void* fqrp = d_in[12];
    const void* fkrp = d_in[13];
    const void* fsvp = d_in[14];
    const void* fsvep= d_in[15];
    const int* fidx  = (const int*)d_in[16];

    float* W      = (float*)d_ws;
    float* musum  = W;            // 64
    float* gram   = W + 64;       // 4096
    float* sstat  = W + 4160;     // 48
    float* ostat  = W + 4208;     // 512  (zeroed region ends at 4720)
    float* weff   = W + 4720;     // 16384
    float* beff   = W + 21104;    // 256
    float* scoef  = W + 21360;    // 24
    float* ocoef  = W + 21384;    // 512
    int*   flag   = (int*)(W + 21896);    // 1 (+3 pad)
    float* mq     = W + 21900;    // 48*40
    float* mk     = W + 23820;    // 48*40
    float* e1q    = W + 25740;    // 48*8
    float* e1k    = W + 26124;    // 48*8  -> ends 26508
    u16*   qe     = (u16*)(W + 26508);    // 8*2304 u16 (c-major, fallback)
    u16*   keT    = (u16*)(W + 35724);
    u16*   ve     = (u16*)(W + 44940);    // 16*2304 u16 -> ends float 63372
    u16*   weffh  = (u16*)(W + 63372);    // 256*64 u16 -> ends 71564
    u16*   rq2    = (u16*)(W + 71564);    // 96*8 u16 -> ends 71948
    u16*   rk2    = (u16*)(W + 71948);    // -> 72332
    u16*   rv2    = (u16*)(W + 72332);    // 16*96 u16 -> 73100
    u16*   qkv    = (u16*)(W + 73100);    // 2304*256*48 bf16 -> ends 14228876
    u16*   pre2   = qkv + 28311552;       // -> ends 28384652
    u16*   Xt     = (u16*)(W + 28384652); // 2304*3456 bf16 -> ends 32365964

    const size_t need1 = (size_t)28384652 * 4;   // ~113.5 MB (tier 1)
    const size_t need2 = (size_t)32365964 * 4;   // ~129.5 MB (tier 2, +Xt)
    const int tier = (ws_size >= need2) ? 2 : ((ws_size >= need1) ? 1 : 0);

    k_detect<<<1, 256, 0, stream>>>((const u16*)X, flag);
    k_zero<<<8, 256, 0, stream>>>(W);
    k_emb<<<9, 256, 0, stream>>>(rel, fidx, flag, qe, keT, ve, rq2, rk2, rv2);
    k_gram<<<256, 256, 0, stream>>>(X, flag, musum, gram);
    k_fold<<<1, 256, 0, stream>>>(Wkv, Wq, gkv, bkv, gq, bq, flag, musum, gram, weff, weffh, beff);
    if (tier > 0) {
        k_mtab<<<1, 128, 0, stream>>>(rel, flag, mq, mk, e1q, e1k);
        if (tier == 2) {
            k_xpose<<<dim3(48, 36), 256, 0, stream>>>(X, flag, Xt);
            k_stage1m<<<2304, 256, 0, stream>>>(Xt, weffh, beff, mq, mk, e1q, e1k, sstat, qkv);
        } else {
            k_stage1<<<2304, 256, 0, stream>>>(X, weff, beff, mq, mk, e1q, e1k, flag, sstat, qkv);
        }
        k_simcoef<<<1, 32, 0, stream>>>(sstat, gsim, fqrp, fkrp, flag, 0, scoef);
        k_attn3<<<dim3(2304, 8), 64, 0, stream>>>(qkv, rq2, rk2, rv2, scoef,
                                                  fqrp, fkrp, fsvp, fsvep, flag, ostat, pre2);
        k_outcoef<<<1, 256, 0, stream>>>(ostat, gout, bout, flag, ocoef);
        k_final<<<dim3(128, 48), 256, 0, stream>>>(pre2, ocoef, flag, d_out);
    } else {
        k_qkstat<<<2304, 256, 0, stream>>>(X, weff, beff, qe, keT, fqrp, fkrp, flag, sstat);
        k_simcoef<<<1, 32, 0, stream>>>(sstat, gsim, fqrp, fkrp, flag, 1, scoef);
        k_attn<<<2304, 256, 0, stream>>>(X, weff, beff, qe, keT, ve, scoef, ocoef,
                                         fqrp, fkrp, fsvp, fsvep, flag, ostat, d_out, 0);
        k_outcoef<<<1, 256, 0, stream>>>(ostat, gout, bout, flag, ocoef);
        k_attn<<<2304, 256, 0, stream>>>(X, weff, beff, qe, keT, ve, scoef, ocoef,
                                         fqrp, fkrp, fsvp, fsvep, flag, ostat, d_out, 2);
    }
}

// Round 9
// 973.605 us; speedup vs baseline: 1.0885x; 1.0397x over previous
//
#include <hip/hip_runtime.h>

// RelativeAxialAttention on MI355X (gfx950). Single-attention-pass design.
// K=48, G=8, DK=8, DV=16, CIN=64, B = 2304.
//
// Math shortcuts:
//  * kv/q BatchNorm folded into GEMM weights via x-gram.
//  * sim BN: softmax-invariant mean/beta; scales from CLOSED-FORM moments
//    (grams + Toeplitz windowed outer-products, k_mtab) -- no logits pass.
//  * k_stage1 GEMM on MFMA bf16 (stage1m) with X pre-transposed (k_xpose).
//  * k_attn3 (round 9): round-8 MFMA version was correct but occupancy-starved
//    (34.8KB LDS -> 4 blk/CU = 1 wave/SIMD, 8.5% occ, 9.7M bank conflicts from
//    stride-96 zb/zd). This round: in-register softmax (no zf, row = one
//    16-lane shuffle group in the QK D-layout), B-frags for v/rel read straight
//    from global (no vls/rvC), padded strides (zb 72, zd 104, krB 56) for 16B
//    alignment + ~2-way banks. LDS 18.4KB -> 8 blk/CU = 2 waves/SIMD.
// Tiers: ws>=129.5MB full path; >=113.5MB VALU stage1; else recompute fallback.

typedef unsigned short u16;
typedef __attribute__((ext_vector_type(8))) short short8v;
typedef __attribute__((ext_vector_type(4))) float float4v;

#define N_S 110592
#define N_B 2304

__device__ __forceinline__ float b2f(u16 v) {
    return __builtin_bit_cast(float, ((unsigned)v) << 16);
}
__device__ __forceinline__ u16 f2b(float f) {
    unsigned u = __builtin_bit_cast(unsigned, f);
    u = (u + 0x7FFFu + ((u >> 16) & 1u)) >> 16;
    return (u16)u;
}
__device__ __forceinline__ float ldf(const void* p, int idx, int f32) {
    return f32 ? ((const float*)p)[idx] : b2f(((const u16*)p)[idx]);
}

// ---------------- dtype detection ----------------
__global__ void k_detect(const u16* X, int* flag) {
    __shared__ int tot;
    if (threadIdx.x == 0) tot = 0;
    __syncthreads();
    int cnt = 0;
#pragma unroll
    for (int k = 0; k < 8; k++) {
        u16 v = X[(threadIdx.x * 8 + k) * 2];
        int e = (v >> 7) & 0xFF;
        cnt += (e >= 0x70 && e <= 0x8F) ? 1 : 0;
    }
    atomicAdd(&tot, cnt);
    __syncthreads();
    if (threadIdx.x == 0) flag[0] = (tot < 1024) ? 1 : 0;   // 1 = f32
}

// ---------------- zero stats region ----------------
__global__ void k_zero(float* w) {
    for (int i = blockIdx.x * blockDim.x + threadIdx.x; i < 4720; i += gridDim.x * blockDim.x)
        w[i] = 0.0f;
}

// ---------------- build emb tables ----------------
// qe/keT/ve (c-major, fallback) + raw Toeplitz rel tables for k_attn3:
//   rq2[d*8+c], rk2[d*8+c] (d<96, row 95 zero), rv2[c*96+d] (col 95 zero)
__global__ void k_emb(const void* rel, const int* fidx, const int* flag,
                      u16* qe, u16* keT, u16* ve, u16* rq2, u16* rk2, u16* rv2) {
    int f32 = flag[0];
    if (blockIdx.x == 0 && threadIdx.x < 96) {
        int d = threadIdx.x;
#pragma unroll
        for (int c = 0; c < 8; c++) {
            rq2[d * 8 + c] = (d < 95) ? f2b(ldf(rel, c * 95 + d, f32)) : (u16)0;
            rk2[d * 8 + c] = (d < 95) ? f2b(ldf(rel, (8 + c) * 95 + d, f32)) : (u16)0;
        }
#pragma unroll
        for (int c = 0; c < 16; c++)
            rv2[c * 96 + d] = (d < 95) ? f2b(ldf(rel, (16 + c) * 95 + d, f32)) : (u16)0;
    }
    int t = blockIdx.x * 256 + threadIdx.x;
    if (t >= 2304) return;
    int i = t / 48, j = t % 48;
    int fij = fidx[i * 48 + j];
    int fji = fidx[j * 48 + i];
#pragma unroll
    for (int c = 0; c < 8; c++) {
        qe[c * 2304 + t]  = f2b(ldf(rel, c * 95 + fij, f32));
        keT[c * 2304 + t] = f2b(ldf(rel, (8 + c) * 95 + fji, f32));
    }
#pragma unroll
    for (int c = 0; c < 16; c++)
        ve[c * 2304 + t] = f2b(ldf(rel, (16 + c) * 95 + fij, f32));
}

// ---------------- Toeplitz moment tables ----------------
__global__ void k_mtab(const void* rel, const int* flag,
                       float* mq, float* mk, float* e1q, float* e1k) {
    __shared__ float rl[1520];
    int f32 = flag[0];
    int tid = threadIdx.x;
    for (int idx = tid; idx < 1520; idx += 128) rl[idx] = ldf(rel, idx, f32);
    __syncthreads();
    if (tid >= 96) return;
    int tbl = tid / 48, i = tid % 48;
    const float* R = rl + tbl * 760;
    float* M = (tbl ? mk : mq) + i * 40;
    float* E = (tbl ? e1k : e1q) + i * 8;
    float acc[36], e[8];
#pragma unroll
    for (int x = 0; x < 36; x++) acc[x] = 0.0f;
#pragma unroll
    for (int c = 0; c < 8; c++) e[c] = 0.0f;
    for (int d = i; d < i + 48; d++) {
        float v[8];
#pragma unroll
        for (int c = 0; c < 8; c++) { v[c] = R[c * 95 + d]; e[c] += v[c]; }
        int idx = 0;
#pragma unroll
        for (int c = 0; c < 8; c++)
#pragma unroll
            for (int c2 = c; c2 < 8; c2++) { acc[idx] += v[c] * v[c2]; idx++; }
    }
    int idx = 0;
#pragma unroll
    for (int c = 0; c < 8; c++) {
        E[c] = e[c];
#pragma unroll
        for (int c2 = c; c2 < 8; c2++) {
            M[idx] = (c2 == c ? 1.0f : 2.0f) * acc[idx];
            idx++;
        }
    }
}

// ---------------- x gram ----------------
__global__ __launch_bounds__(256) void k_gram(const void* Xv, const int* flag,
                                              float* musum, float* gram) {
    __shared__ float xs[64 * 65];
    int f32 = flag[0];
    int tid = threadIdx.x;
    int cb1 = tid >> 4, cb2 = tid & 15;
    float acc[4][4];
#pragma unroll
    for (int a = 0; a < 4; a++)
#pragma unroll
        for (int b = 0; b < 4; b++) acc[a][b] = 0.0f;
    float mur = 0.0f;
    for (int tile = blockIdx.x; tile < 1728; tile += gridDim.x) {
        int s0 = tile * 64;
        __syncthreads();
#pragma unroll
        for (int r = 0; r < 4; r++) {
            int idx4 = tid + 256 * r;
            int c = idx4 >> 4, sl = (idx4 & 15) * 4;
            if (f32) {
                float4 u = *(const float4*)((const float*)Xv + c * N_S + s0 + sl);
                xs[c * 65 + sl + 0] = u.x; xs[c * 65 + sl + 1] = u.y;
                xs[c * 65 + sl + 2] = u.z; xs[c * 65 + sl + 3] = u.w;
            } else {
                ushort4 u = *(const ushort4*)((const u16*)Xv + c * N_S + s0 + sl);
                xs[c * 65 + sl + 0] = b2f(u.x); xs[c * 65 + sl + 1] = b2f(u.y);
                xs[c * 65 + sl + 2] = b2f(u.z); xs[c * 65 + sl + 3] = b2f(u.w);
            }
        }
        __syncthreads();
        for (int s = 0; s < 64; s++) {
            float av[4], bv[4];
#pragma unroll
            for (int a = 0; a < 4; a++) av[a] = xs[(cb1 + 16 * a) * 65 + s];
#pragma unroll
            for (int b = 0; b < 4; b++) bv[b] = xs[(cb2 + 16 * b) * 65 + s];
#pragma unroll
            for (int a = 0; a < 4; a++)
#pragma unroll
                for (int b = 0; b < 4; b++) acc[a][b] += av[a] * bv[b];
        }
        if (tid < 64) {
            for (int s = 0; s < 64; s++) mur += xs[tid * 65 + s];
        }
    }
#pragma unroll
    for (int a = 0; a < 4; a++)
#pragma unroll
        for (int b = 0; b < 4; b++)
            atomicAdd(&gram[(cb1 + 16 * a) * 64 + (cb2 + 16 * b)], acc[a][b]);
    if (tid < 64) atomicAdd(&musum[tid], mur);
}

// ---------------- fold BN into weights (f32 + bf16 copies) ----------------
__global__ __launch_bounds__(256) void k_fold(const void* Wkv, const void* Wq,
        const void* gkv, const void* bkv, const void* gq, const void* bq,
        const int* flag, const float* musum, const float* gram,
        float* weff, u16* weffh, float* beff) {
    int f32 = flag[0];
    int o = threadIdx.x;
    float gam, bet;
    float w[64];
    if (o < 192) {
#pragma unroll
        for (int c = 0; c < 64; c++) w[c] = ldf(Wkv, o * 64 + c, f32);
        gam = ldf(gkv, o, f32); bet = ldf(bkv, o, f32);
    } else {
        int oq = o - 192;
#pragma unroll
        for (int c = 0; c < 64; c++) w[c] = ldf(Wq, oq * 64 + c, f32);
        gam = ldf(gq, oq, f32); bet = ldf(bq, oq, f32);
    }
    const float inv = 1.0f / (float)N_S;
    float mean = 0.0f;
#pragma unroll
    for (int c = 0; c < 64; c++) mean += w[c] * musum[c];
    mean *= inv;
    float e2 = 0.0f;
    for (int c = 0; c < 64; c++) {
        float t = 0.0f;
#pragma unroll
        for (int c2 = 0; c2 < 64; c2++) t += w[c2] * gram[c * 64 + c2];
        e2 += w[c] * t;
    }
    e2 *= inv;
    float var = e2 - mean * mean;
    if (var < 0.0f) var = 0.0f;
    float sc = gam * rsqrtf(var + 1e-5f);
#pragma unroll
    for (int c = 0; c < 64; c++) {
        float wv = sc * w[c];
        weff[o * 64 + c] = wv;
        weffh[o * 64 + c] = f2b(wv);
    }
    beff[o] = bet - sc * mean;
}

// ---------------- transpose X -> Xt[b][h][c] bf16, h-stride 72 ----------------
__global__ __launch_bounds__(256) void k_xpose(const void* Xv, const int* flag, u16* Xt) {
    __shared__ float tile[64][65];
    int f32 = flag[0];
    int h = blockIdx.x, b0 = blockIdx.y * 64, tid = threadIdx.x;
#pragma unroll
    for (int r = 0; r < 4; r++) {
        int idx = tid + 256 * r;
        int c = idx >> 4, bq = (idx & 15) * 4;
        if (f32) {
            float4 u = *(const float4*)((const float*)Xv + (size_t)c * N_S + h * 2304 + b0 + bq);
            tile[c][bq + 0] = u.x; tile[c][bq + 1] = u.y;
            tile[c][bq + 2] = u.z; tile[c][bq + 3] = u.w;
        } else {
            ushort4 u = *(const ushort4*)((const u16*)Xv + (size_t)c * N_S + h * 2304 + b0 + bq);
            tile[c][bq + 0] = b2f(u.x); tile[c][bq + 1] = b2f(u.y);
            tile[c][bq + 2] = b2f(u.z); tile[c][bq + 3] = b2f(u.w);
        }
    }
    __syncthreads();
#pragma unroll
    for (int r = 0; r < 4; r++) {
        int idx = tid + 256 * r;
        int bb = idx >> 4, cq = (idx & 15) * 4;
        ushort4 o4 = make_ushort4(f2b(tile[cq + 0][bb]), f2b(tile[cq + 1][bb]),
                                  f2b(tile[cq + 2][bb]), f2b(tile[cq + 3][bb]));
        *(ushort4*)(Xt + (size_t)(b0 + bb) * 3456 + h * 72 + cq) = o4;
    }
}

// ================= FAST PATH (tier 2) =================
// stage1m: MFMA qkv GEMM + closed-form sim-BN moments.
__global__ __launch_bounds__(256) void k_stage1m(const u16* Xt, const u16* weffh, const float* beff,
        const float* mq, const float* mk, const float* e1q, const float* e1k,
        float* sstat, u16* qkv) {
    __shared__ __align__(16) u16 xs[3456];      // [h][72] bf16
    __shared__ __align__(16) u16 qkbf[6144];    // q at [(g*8+c)*48+i], k at +3072
    __shared__ float sbias[256];
    __shared__ float red[48];
    int b = blockIdx.x, tid = threadIdx.x;
    {
        const uint4* src = (const uint4*)(Xt + (size_t)b * 3456);
        uint4* dst = (uint4*)xs;
        for (int idx = tid; idx < 432; idx += 256) dst[idx] = src[idx];
    }
    sbias[tid] = beff[tid];
    if (tid < 48) red[tid] = 0.0f;
    __syncthreads();
    {
        int wv = tid >> 6, l = tid & 63;
        int lm = l & 15, lk8 = (l >> 4) * 8;
        short8v Bf[3][2];
#pragma unroll
        for (int ct = 0; ct < 3; ct++)
#pragma unroll
            for (int ks = 0; ks < 2; ks++)
                Bf[ct][ks] = *(const short8v*)(xs + (ct * 16 + lm) * 72 + ks * 32 + lk8);
        float4v acc[4][3];
#pragma unroll
        for (int a = 0; a < 4; a++)
#pragma unroll
            for (int c = 0; c < 3; c++)
#pragma unroll
                for (int e = 0; e < 4; e++) acc[a][c][e] = 0.0f;
#pragma unroll
        for (int rt = 0; rt < 4; rt++) {
            int orow = wv * 64 + rt * 16 + lm;
#pragma unroll
            for (int ks = 0; ks < 2; ks++) {
                short8v Af = *(const short8v*)(weffh + orow * 64 + ks * 32 + lk8);
#pragma unroll
                for (int ct = 0; ct < 3; ct++)
                    acc[rt][ct] = __builtin_amdgcn_mfma_f32_16x16x32_bf16(Af, Bf[ct][ks], acc[rt][ct], 0, 0, 0);
            }
        }
        int rbase = (l >> 4) * 4;
        u16* qdst = qkv + (size_t)b * 12288;
#pragma unroll
        for (int rt = 0; rt < 4; rt++) {
#pragma unroll
            for (int ct = 0; ct < 3; ct++) {
                int h = ct * 16 + lm;
#pragma unroll
                for (int rg = 0; rg < 4; rg++) {
                    int o = wv * 64 + rt * 16 + rbase + rg;
                    u16 vb = f2b(acc[rt][ct][rg] + sbias[o]);
                    int row, lq = -1;
                    if (o >= 192) {
                        int g = (o - 192) >> 3, c = (o - 192) & 7;
                        row = g * 32 + c;
                        lq = (g * 8 + c) * 48;
                    } else {
                        int g = o / 24, t = o % 24;
                        if (t < 8) { row = g * 32 + 8 + t; lq = 3072 + (g * 8 + t) * 48; }
                        else       { row = g * 32 + 16 + (t - 8); }
                    }
                    qdst[row * 48 + h] = vb;
                    if (lq >= 0) qkbf[lq + h] = vb;
                }
            }
        }
    }
    __syncthreads();
    {
        int g = tid >> 5, t = tid & 31;
        float gq[36], gk[36], sq[8], sk[8];
        float s1qr = 0, s1kr = 0, s2qr = 0, s2kr = 0;
#pragma unroll
        for (int x = 0; x < 36; x++) { gq[x] = 0.0f; gk[x] = 0.0f; }
#pragma unroll
        for (int c = 0; c < 8; c++) { sq[c] = 0.0f; sk[c] = 0.0f; }
#pragma unroll
        for (int pass = 0; pass < 2; pass++) {
            int i = t + pass * 32;
            if (i >= 48) break;
            float qv[8], kvv[8];
#pragma unroll
            for (int c = 0; c < 8; c++) {
                qv[c]  = b2f(qkbf[(g * 8 + c) * 48 + i]);
                kvv[c] = b2f(qkbf[3072 + (g * 8 + c) * 48 + i]);
            }
            const float* mqr = mq + i * 40;
            const float* mkr = mk + i * 40;
            const float* eqr = e1q + i * 8;
            const float* ekr = e1k + i * 8;
            int idx = 0;
#pragma unroll
            for (int c = 0; c < 8; c++) {
                sq[c] += qv[c]; sk[c] += kvv[c];
                s1qr += qv[c] * eqr[c];
                s1kr += kvv[c] * ekr[c];
#pragma unroll
                for (int c2 = c; c2 < 8; c2++) {
                    float oq = qv[c] * qv[c2], ok = kvv[c] * kvv[c2];
                    gq[idx] += oq; gk[idx] += ok;
                    s2qr += mqr[idx] * oq;
                    s2kr += mkr[idx] * ok;
                    idx++;
                }
            }
        }
#pragma unroll
        for (int off = 1; off <= 16; off <<= 1) {
#pragma unroll
            for (int x = 0; x < 36; x++) { gq[x] += __shfl_xor(gq[x], off); gk[x] += __shfl_xor(gk[x], off); }
#pragma unroll
            for (int c = 0; c < 8; c++) { sq[c] += __shfl_xor(sq[c], off); sk[c] += __shfl_xor(sk[c], off); }
            s1qr += __shfl_xor(s1qr, off); s1kr += __shfl_xor(s1kr, off);
            s2qr += __shfl_xor(s2qr, off); s2kr += __shfl_xor(s2kr, off);
        }
        if (t == 0) {
            float s1qk = 0.0f, s2qk = 0.0f;
            int idx = 0;
#pragma unroll
            for (int c = 0; c < 8; c++) {
                s1qk += sq[c] * sk[c];
#pragma unroll
                for (int c2 = c; c2 < 8; c2++) {
                    float w = (c2 == c) ? 1.0f : 2.0f;
                    s2qk += w * gq[idx] * gk[idx];
                    idx++;
                }
            }
            red[0 * 8 + g] = s1qk;  red[1 * 8 + g] = s1qr;  red[2 * 8 + g] = s1kr;
            red[3 * 8 + g] = s2qk;  red[4 * 8 + g] = s2qr;  red[5 * 8 + g] = s2kr;
        }
    }
    __syncthreads();
    if (tid < 48) atomicAdd(&sstat[tid], red[tid]);
}

// ================= tier-1 stage1 (VALU, reads X directly) =================
__global__ __launch_bounds__(256) void k_stage1(const void* Xv, const float* weff, const float* beff,
        const float* mq, const float* mk, const float* e1q, const float* e1k,
        const int* flag, float* sstat, u16* qkv) {
    __shared__ __align__(16) float xs[3072];
    __shared__ __align__(16) float qk[6144];
    __shared__ float red[48];
    int f32 = flag[0];
    int b = blockIdx.x, tid = threadIdx.x;
    for (int idx = tid; idx < 3072; idx += 256) {
        int c = idx / 48, h = idx % 48;
        xs[idx] = ldf(Xv, c * N_S + h * 2304 + b, f32);
    }
    __syncthreads();
    {
        int g = tid >> 5, r = tid & 31;
        int o;
        if (r < 8)       o = 192 + g * 8 + r;
        else if (r < 16) o = g * 24 + (r - 8);
        else             o = g * 24 + 8 + (r - 16);
        float wr[64];
        const float4* wrow = (const float4*)(weff + o * 64);
#pragma unroll
        for (int c4 = 0; c4 < 16; c4++) {
            float4 t4 = wrow[c4];
            wr[c4 * 4 + 0] = t4.x; wr[c4 * 4 + 1] = t4.y; wr[c4 * 4 + 2] = t4.z; wr[c4 * 4 + 3] = t4.w;
        }
        float bias = beff[o];
        u16* gdst = qkv + (b * 256 + tid) * 48;
        float* ldst = (r < 8) ? (qk + g * 768 + r * 48)
                    : (r < 16 ? (qk + g * 768 + 384 + (r - 8) * 48) : nullptr);
#pragma unroll
        for (int hb = 0; hb < 6; hb++) {
            float acc[8];
#pragma unroll
            for (int u = 0; u < 8; u++) acc[u] = bias;
#pragma unroll
            for (int c = 0; c < 64; c++) {
                float wv = wr[c];
                const float4* xp = (const float4*)(xs + c * 48 + hb * 8);
                float4 x0 = xp[0], x1 = xp[1];
                acc[0] += wv * x0.x; acc[1] += wv * x0.y; acc[2] += wv * x0.z; acc[3] += wv * x0.w;
                acc[4] += wv * x1.x; acc[5] += wv * x1.y; acc[6] += wv * x1.z; acc[7] += wv * x1.w;
            }
            ushort4 p0 = make_ushort4(f2b(acc[0]), f2b(acc[1]), f2b(acc[2]), f2b(acc[3]));
            ushort4 p1 = make_ushort4(f2b(acc[4]), f2b(acc[5]), f2b(acc[6]), f2b(acc[7]));
            *(ushort4*)(gdst + hb * 8)     = p0;
            *(ushort4*)(gdst + hb * 8 + 4) = p1;
            if (ldst) {
                *(float4*)(ldst + hb * 8)     = make_float4(acc[0], acc[1], acc[2], acc[3]);
                *(float4*)(ldst + hb * 8 + 4) = make_float4(acc[4], acc[5], acc[6], acc[7]);
            }
        }
    }
    __syncthreads();
    {
        int g = tid >> 5, t = tid & 31;
        float gq[36], gk[36], sq[8], sk[8];
        float s1qr = 0, s1kr = 0, s2qr = 0, s2kr = 0;
#pragma unroll
        for (int x = 0; x < 36; x++) { gq[x] = 0.0f; gk[x] = 0.0f; }
#pragma unroll
        for (int c = 0; c < 8; c++) { sq[c] = 0.0f; sk[c] = 0.0f; }
#pragma unroll
        for (int pass = 0; pass < 2; pass++) {
            int i = t + pass * 32;
            if (i >= 48) break;
            float qv[8], kvv[8];
#pragma unroll
            for (int c = 0; c < 8; c++) {
                qv[c]  = qk[g * 768 + c * 48 + i];
                kvv[c] = qk[g * 768 + 384 + c * 48 + i];
            }
            const float* mqr = mq + i * 40;
            const float* mkr = mk + i * 40;
            const float* eqr = e1q + i * 8;
            const float* ekr = e1k + i * 8;
            int idx = 0;
#pragma unroll
            for (int c = 0; c < 8; c++) {
                sq[c] += qv[c]; sk[c] += kvv[c];
                s1qr += qv[c] * eqr[c];
                s1kr += kvv[c] * ekr[c];
#pragma unroll
                for (int c2 = c; c2 < 8; c2++) {
                    float oq = qv[c] * qv[c2], ok = kvv[c] * kvv[c2];
                    gq[idx] += oq; gk[idx] += ok;
                    s2qr += mqr[idx] * oq;
                    s2kr += mkr[idx] * ok;
                    idx++;
                }
            }
        }
#pragma unroll
        for (int off = 1; off <= 16; off <<= 1) {
#pragma unroll
            for (int x = 0; x < 36; x++) { gq[x] += __shfl_xor(gq[x], off); gk[x] += __shfl_xor(gk[x], off); }
#pragma unroll
            for (int c = 0; c < 8; c++) { sq[c] += __shfl_xor(sq[c], off); sk[c] += __shfl_xor(sk[c], off); }
            s1qr += __shfl_xor(s1qr, off); s1kr += __shfl_xor(s1kr, off);
            s2qr += __shfl_xor(s2qr, off); s2kr += __shfl_xor(s2kr, off);
        }
        if (t == 0) {
            float s1qk = 0.0f, s2qk = 0.0f;
            int idx = 0;
#pragma unroll
            for (int c = 0; c < 8; c++) {
                s1qk += sq[c] * sk[c];
#pragma unroll
                for (int c2 = c; c2 < 8; c2++) {
                    float w = (c2 == c) ? 1.0f : 2.0f;
                    s2qk += w * gq[idx] * gk[idx];
                    idx++;
                }
            }
            red[0 * 8 + g] = s1qk;  red[1 * 8 + g] = s1qr;  red[2 * 8 + g] = s1kr;
            red[3 * 8 + g] = s2qk;  red[4 * 8 + g] = s2qr;  red[5 * 8 + g] = s2kr;
        }
    }
    __syncthreads();
    if (tid < 48) atomicAdd(&sstat[tid], red[tid]);
}

// scaled=1: sstat already includes fqr/fkr (fallback). scaled=0: apply here.
__global__ void k_simcoef(const float* sstat, const void* gsim, const void* fqrp, const void* fkrp,
                          const int* flag, int scaled, float* scoef) {
    int ch = threadIdx.x;
    if (ch >= 24) return;
    int f32 = flag[0];
    float f = 1.0f;
    if (!scaled) {
        if (ch >= 16)     f = ldf(fkrp, 0, f32);
        else if (ch >= 8) f = ldf(fqrp, 0, f32);
    }
    const float n = 2304.0f * 2304.0f;
    float mean = f * sstat[ch] / n;
    float var = f * f * sstat[24 + ch] / n - mean * mean;
    if (var < 0.0f) var = 0.0f;
    scoef[ch] = ldf(gsim, ch, f32) * rsqrtf(var + 1e-5f);
}

// attn3: one WAVE per (b, g). MFMA everywhere; in-register softmax; LDS 18432 B
// -> 8 blocks/CU = 2 waves/SIMD. v/rel B-frags read directly from global.
__global__ __launch_bounds__(64) void k_attn3(const u16* qkv,
        const u16* rq2, const u16* rk2, const u16* rv2,
        const float* scoef, const void* fqrp, const void* fkrp,
        const void* fsvp, const void* fsvep, const int* flag,
        float* ostat, u16* pre2) {
    __shared__ __align__(16) u16 qT[384];   // [i][c]
    __shared__ __align__(16) u16 kT[384];   // [j][c]
    __shared__ __align__(16) u16 R[8448];   // union {qrB[48][48], krB[48][56]} -> {zb[48][72], zd[48][104]}
    int f32 = flag[0];
    int b = blockIdx.x, g = blockIdx.y, tid = threadIdx.x;
    int lr = tid & 15, lk = tid >> 4;
    u16* qrB = R;             // stride 48
    u16* krB = R + 2304;      // stride 56
    u16* zb  = R;             // stride 72 (cols 48..71 zero pad, K=64)
    u16* zd  = R + 3456;      // stride 104 (cols 95..103 pad, K=96)
    const u16* src = qkv + (b * 256 + g * 32) * 48;
    // stage q,k transposed [h][c]
#pragma unroll
    for (int e = 0; e < 6; e++) {
        int idx = tid + 64 * e;
        int c = idx / 48, h = idx % 48;
        qT[h * 8 + c] = src[c * 48 + h];
        kT[h * 8 + c] = src[(8 + c) * 48 + h];
    }
    __syncthreads();
    short8v z8 = {0, 0, 0, 0, 0, 0, 0, 0};
    // A-frags (K=8 padded to 32: only lanes lk==0 carry data)
    short8v aq[3], ak[3];
#pragma unroll
    for (int tm = 0; tm < 3; tm++) {
        aq[tm] = (lk == 0) ? *(const short8v*)(qT + (tm * 16 + lr) * 8) : z8;
        ak[tm] = (lk == 0) ? *(const short8v*)(kT + (tm * 16 + lr) * 8) : z8;
    }
    // QR = q^T rel_q, KR = k^T rel_k (B-frags straight from global) -> banded stores
#pragma unroll
    for (int tn = 0; tn < 6; tn++) {
        short8v bq = (lk == 0) ? *(const short8v*)(rq2 + (tn * 16 + lr) * 8) : z8;
        short8v bk = (lk == 0) ? *(const short8v*)(rk2 + (tn * 16 + lr) * 8) : z8;
#pragma unroll
        for (int tm = 0; tm < 3; tm++) {
            float4v a0 = {0, 0, 0, 0}, a1 = {0, 0, 0, 0};
            a0 = __builtin_amdgcn_mfma_f32_16x16x32_bf16(aq[tm], bq, a0, 0, 0, 0);
            a1 = __builtin_amdgcn_mfma_f32_16x16x32_bf16(ak[tm], bk, a1, 0, 0, 0);
#pragma unroll
            for (int r = 0; r < 4; r++) {
                int i = tm * 16 + lk * 4 + r;
                int dd = tn * 16 + lr - i;
                if (dd >= 0 && dd < 48) {
                    qrB[i * 48 + dd] = f2b(a0[r]);
                    krB[i * 56 + dd] = f2b(a1[r]);
                }
            }
        }
    }
    // QK = q^T k (kept in regs; becomes P in-place)
    float4v qk[3][3];
#pragma unroll
    for (int tn = 0; tn < 3; tn++) {
        short8v bkf = (lk == 0) ? *(const short8v*)(kT + (tn * 16 + lr) * 8) : z8;
#pragma unroll
        for (int tm = 0; tm < 3; tm++) {
            float4v a = {0, 0, 0, 0};
            qk[tm][tn] = __builtin_amdgcn_mfma_f32_16x16x32_bf16(aq[tm], bkf, a, 0, 0, 0);
        }
    }
    __syncthreads();
    float fqr = ldf(fqrp, 0, f32), fkr = ldf(fkrp, 0, f32);
    float fsv = ldf(fsvp, 0, f32), fsve = ldf(fsvep, 0, f32);
    float c0 = scoef[g], c1f = scoef[8 + g] * fqr, c2f = scoef[16 + g] * fkr;
    // combine + in-register softmax. Row i's 48 cols live in the 16-lane group
    // sharing lk (cols j = tn*16+lr) -> shuffle-xor 1,2,4,8 reduces a row.
#pragma unroll
    for (int tm = 0; tm < 3; tm++)
#pragma unroll
        for (int r = 0; r < 4; r++) {
            int i = tm * 16 + lk * 4 + r;
            float v0[3];
#pragma unroll
            for (int tn = 0; tn < 3; tn++) {
                int j = tn * 16 + lr;
                v0[tn] = c0 * qk[tm][tn][r]
                       + c1f * b2f(qrB[i * 48 + 47 - j])
                       + c2f * b2f(krB[j * 56 + 47 - i]);
            }
            float m = fmaxf(fmaxf(v0[0], v0[1]), v0[2]);
#pragma unroll
            for (int off = 1; off <= 8; off <<= 1) m = fmaxf(m, __shfl_xor(m, off));
            float e0 = __expf(v0[0] - m), e1 = __expf(v0[1] - m), e2 = __expf(v0[2] - m);
            float s = e0 + e1 + e2;
#pragma unroll
            for (int off = 1; off <= 8; off <<= 1) s += __shfl_xor(s, off);
            float inv = 1.0f / s;
            qk[tm][0][r] = e0 * inv;
            qk[tm][1][r] = e1 * inv;
            qk[tm][2][r] = e2 * inv;
        }
    __syncthreads();
    // zero zb+zd (8448 u16 = 1056 uint4), then scatter P into zb (dense) + zd (diag)
#pragma unroll
    for (int e = 0; e < 17; e++) {
        int idx = tid + 64 * e;
        if (idx < 1056) {
            uint4 zz = {0, 0, 0, 0};
            ((uint4*)R)[idx] = zz;
        }
    }
    __syncthreads();
#pragma unroll
    for (int tm = 0; tm < 3; tm++)
#pragma unroll
        for (int r = 0; r < 4; r++) {
            int i = tm * 16 + lk * 4 + r;
#pragma unroll
            for (int tn = 0; tn < 3; tn++) {
                int j = tn * 16 + lr;
                u16 pb = f2b(qk[tm][tn][r]);
                zb[i * 72 + j] = pb;
                zd[i * 104 + i + 47 - j] = pb;
            }
        }
    __syncthreads();
    // SV = P v^T (K=64 pad; v B-frags from global qkv), SVE = Zd rel_v^T (K=96)
    float4v sv[3], se[3];
#pragma unroll
    for (int tm = 0; tm < 3; tm++) { sv[tm] = (float4v){0,0,0,0}; se[tm] = (float4v){0,0,0,0}; }
#pragma unroll
    for (int ks = 0; ks < 2; ks++) {
        short8v bv = (ks == 0 || lk < 2) ? *(const short8v*)(src + (16 + lr) * 48 + ks * 32 + lk * 8) : z8;
#pragma unroll
        for (int tm = 0; tm < 3; tm++) {
            short8v af = *(const short8v*)(zb + (tm * 16 + lr) * 72 + ks * 32 + lk * 8);
            sv[tm] = __builtin_amdgcn_mfma_f32_16x16x32_bf16(af, bv, sv[tm], 0, 0, 0);
        }
    }
#pragma unroll
    for (int ks = 0; ks < 3; ks++) {
        short8v br = *(const short8v*)(rv2 + lr * 96 + ks * 32 + lk * 8);
#pragma unroll
        for (int tm = 0; tm < 3; tm++) {
            short8v ad = *(const short8v*)(zd + (tm * 16 + lr) * 104 + ks * 32 + lk * 8);
            se[tm] = __builtin_amdgcn_mfma_f32_16x16x32_bf16(ad, br, se[tm], 0, 0, 0);
        }
    }
    // epilogue: lane holds (c=lr, 12 i's); write pre2 pairs + stats
    int c = lr;
    float sA = 0, qA = 0, sB = 0, qB = 0;
    u16* pdst = pre2 + ((b * 128 + g * 16 + c) * 48) * 2;
#pragma unroll
    for (int tm = 0; tm < 3; tm++)
#pragma unroll
        for (int r = 0; r < 4; r++) {
            int i = tm * 16 + lk * 4 + r;
            float a = sv[tm][r] * fsv, bb = se[tm][r] * fsve;
            *(ushort2*)(pdst + i * 2) = make_ushort2(f2b(a), f2b(bb));
            sA += a; qA += a * a; sB += bb; qB += bb * bb;
        }
    sA += __shfl_xor(sA, 16); qA += __shfl_xor(qA, 16);
    sB += __shfl_xor(sB, 16); qB += __shfl_xor(qB, 16);
    sA += __shfl_xor(sA, 32); qA += __shfl_xor(qA, 32);
    sB += __shfl_xor(sB, 32); qB += __shfl_xor(qB, 32);
    if (lk == 0) {
        int ch2 = g * 32 + c * 2;
        atomicAdd(&ostat[ch2 * 2 + 0], sA);
        atomicAdd(&ostat[ch2 * 2 + 1], qA);
        atomicAdd(&ostat[ch2 * 2 + 2], sB);
        atomicAdd(&ostat[ch2 * 2 + 3], qB);
    }
}

__global__ void k_outcoef(const float* ostat, const void* gout, const void* bout,
                          const int* flag, float* ocoef) {
    int f32 = flag[0];
    int o = threadIdx.x;
    const float n = 110592.0f;
    float mean = ostat[o * 2] / n;
    float var = ostat[o * 2 + 1] / n - mean * mean;
    if (var < 0.0f) var = 0.0f;
    float sc = ldf(gout, o, f32) * rsqrtf(var + 1e-5f);
    ocoef[o * 2] = sc;
    ocoef[o * 2 + 1] = ldf(bout, o, f32) - mean * sc;
}

// final: BN + pair-sum + transpose.
__global__ __launch_bounds__(256) void k_final(const u16* pre2, const float* ocoef,
                                               const int* flag, void* outp) {
    __shared__ float tile[48 * 49];
    int f32 = flag[0];
    int ch = blockIdx.x, w = blockIdx.y, tid = threadIdx.x;
    float sc0 = ocoef[(ch * 2) * 2],     sh0 = ocoef[(ch * 2) * 2 + 1];
    float sc1 = ocoef[(ch * 2 + 1) * 2], sh1 = ocoef[(ch * 2 + 1) * 2 + 1];
    float shs = sh0 + sh1;
#pragma unroll
    for (int r = 0; r < 9; r++) {
        int idx = tid + 256 * r;
        int d = idx / 48, i = idx % 48;
        ushort2 p = ((const ushort2*)pre2)[((w * 48 + d) * 128 + ch) * 48 + i];
        tile[d * 49 + i] = b2f(p.x) * sc0 + b2f(p.y) * sc1 + shs;
    }
    __syncthreads();
#pragma unroll
    for (int r = 0; r < 9; r++) {
        int idx = tid + 256 * r;
        int i = idx / 48, d = idx % 48;
        float v = tile[d * 49 + i];
        int oidx = ch * N_S + i * 2304 + w * 48 + d;
        if (f32) ((float*)outp)[oidx] = v;
        else     ((u16*)outp)[oidx] = f2b(v);
    }
}

// ================= FALLBACK PATH =================
__global__ __launch_bounds__(256) void k_qkstat(const void* Xv, const float* weff, const float* beff,
        const u16* qe, const u16* keT, const void* fqrp, const void* fkrp,
        const int* flag, float* sstat) {
    __shared__ __align__(16) float xs[3072];
    __shared__ __align__(16) float qsh[3072];
    __shared__ __align__(16) float ksh[3072];
    __shared__ float red[48];
    int f32 = flag[0];
    int b = blockIdx.x, tid = threadIdx.x;
    for (int idx = tid; idx < 3072; idx += 256) {
        int c = idx / 48, h = idx % 48;
        xs[idx] = ldf(Xv, c * N_S + h * 2304 + b, f32);
    }
    if (tid < 48) red[tid] = 0.0f;
    __syncthreads();
    {
        int r = tid >> 1, half = tid & 1;
        int o; float* dst;
        if (r < 64) { o = 192 + r; dst = qsh + r * 48; }
        else { int rk = r - 64; o = (rk >> 3) * 24 + (rk & 7); dst = ksh + rk * 48; }
        float wr[64];
        const float4* wrow = (const float4*)(weff + o * 64);
#pragma unroll
        for (int c4 = 0; c4 < 16; c4++) {
            float4 t4 = wrow[c4];
            wr[c4 * 4 + 0] = t4.x; wr[c4 * 4 + 1] = t4.y; wr[c4 * 4 + 2] = t4.z; wr[c4 * 4 + 3] = t4.w;
        }
        float bias = beff[o];
        int h0 = half * 24;
#pragma unroll
        for (int hb = 0; hb < 3; hb++) {
            float acc[8];
#pragma unroll
            for (int u = 0; u < 8; u++) acc[u] = bias;
#pragma unroll
            for (int c = 0; c < 64; c++) {
                float wv = wr[c];
                const float4* xp = (const float4*)(xs + c * 48 + h0 + hb * 8);
                float4 x0 = xp[0], x1 = xp[1];
                acc[0] += wv * x0.x; acc[1] += wv * x0.y; acc[2] += wv * x0.z; acc[3] += wv * x0.w;
                acc[4] += wv * x1.x; acc[5] += wv * x1.y; acc[6] += wv * x1.z; acc[7] += wv * x1.w;
            }
            *(float4*)(dst + h0 + hb * 8)     = make_float4(acc[0], acc[1], acc[2], acc[3]);
            *(float4*)(dst + h0 + hb * 8 + 4) = make_float4(acc[4], acc[5], acc[6], acc[7]);
        }
    }
    __syncthreads();
    float fqr = ldf(fqrp, 0, f32), fkr = ldf(fkrp, 0, f32);
    float sum[24], sq[24];
#pragma unroll
    for (int k = 0; k < 24; k++) { sum[k] = 0.0f; sq[k] = 0.0f; }
    for (int r = 0; r < 3; r++) {
        int chunk = tid + 256 * r;
        if (chunk >= 576) break;
        int i = chunk / 12, j0 = (chunk % 12) * 4;
        float qv[8][4], kv[8][4];
#pragma unroll
        for (int c = 0; c < 8; c++) {
            ushort4 uq = *(const ushort4*)(qe + c * 2304 + i * 48 + j0);
            ushort4 uk = *(const ushort4*)(keT + c * 2304 + i * 48 + j0);
            qv[c][0] = b2f(uq.x); qv[c][1] = b2f(uq.y); qv[c][2] = b2f(uq.z); qv[c][3] = b2f(uq.w);
            kv[c][0] = b2f(uk.x); kv[c][1] = b2f(uk.y); kv[c][2] = b2f(uk.z); kv[c][3] = b2f(uk.w);
        }
#pragma unroll
        for (int g = 0; g < 8; g++) {
            float zq[4] = {0,0,0,0}, zr[4] = {0,0,0,0}, zk[4] = {0,0,0,0};
#pragma unroll
            for (int c = 0; c < 8; c++) {
                float qi = qsh[(g * 8 + c) * 48 + i];
                float4 kk = *(const float4*)(ksh + (g * 8 + c) * 48 + j0);
                zq[0] += qi * kk.x; zq[1] += qi * kk.y; zq[2] += qi * kk.z; zq[3] += qi * kk.w;
                zr[0] += qi * qv[c][0]; zr[1] += qi * qv[c][1]; zr[2] += qi * qv[c][2]; zr[3] += qi * qv[c][3];
                zk[0] += kk.x * kv[c][0]; zk[1] += kk.y * kv[c][1]; zk[2] += kk.z * kv[c][2]; zk[3] += kk.w * kv[c][3];
            }
#pragma unroll
            for (int u = 0; u < 4; u++) {
                float a = zq[u];        sum[g] += a;       sq[g] += a * a;
                float r1 = zr[u] * fqr; sum[8 + g] += r1;  sq[8 + g] += r1 * r1;
                float r2 = zk[u] * fkr; sum[16 + g] += r2; sq[16 + g] += r2 * r2;
            }
        }
    }
#pragma unroll
    for (int k = 0; k < 24; k++) {
        float s = sum[k], q = sq[k];
        for (int off = 32; off >= 1; off >>= 1) { s += __shfl_xor(s, off); q += __shfl_xor(q, off); }
        if ((tid & 63) == 0) { atomicAdd(&red[k], s); atomicAdd(&red[24 + k], q); }
    }
    __syncthreads();
    if (tid < 48) atomicAdd(&sstat[tid], red[tid]);
}

__global__ __launch_bounds__(256) void k_attn(const void* Xv, const float* weff, const float* beff,
        const u16* qe, const u16* keT, const u16* ve,
        const float* scoef, const float* ocoef,
        const void* fqrp, const void* fkrp, const void* fsvp, const void* fsvep,
        const int* flag, float* ostat, void* outp, int mode) {
    __shared__ __align__(16) float zx[3072];
    __shared__ __align__(16) float qsh[3072];
    __shared__ __align__(16) float ksh[3072];
    __shared__ __align__(16) float vsh[6144];
    __shared__ float osl[512];
    int f32 = flag[0];
    int b = blockIdx.x, tid = threadIdx.x;
    for (int idx = tid; idx < 3072; idx += 256) {
        int c = idx / 48, h = idx % 48;
        zx[idx] = ldf(Xv, c * N_S + h * 2304 + b, f32);
    }
    __syncthreads();
    {
        int o; float* dst;
        if (tid < 64)       { o = 192 + tid; dst = qsh + tid * 48; }
        else if (tid < 128) { int rk = tid - 64; o = (rk >> 3) * 24 + (rk & 7); dst = ksh + rk * 48; }
        else                { int rv = tid - 128; o = (rv >> 4) * 24 + 8 + (rv & 15); dst = vsh + rv * 48; }
        float wr[64];
        const float4* wrow = (const float4*)(weff + o * 64);
#pragma unroll
        for (int c4 = 0; c4 < 16; c4++) {
            float4 t4 = wrow[c4];
            wr[c4 * 4 + 0] = t4.x; wr[c4 * 4 + 1] = t4.y; wr[c4 * 4 + 2] = t4.z; wr[c4 * 4 + 3] = t4.w;
        }
        float bias = beff[o];
#pragma unroll
        for (int hb = 0; hb < 6; hb++) {
            float acc[8];
#pragma unroll
            for (int u = 0; u < 8; u++) acc[u] = bias;
#pragma unroll
            for (int c = 0; c < 64; c++) {
                float wv = wr[c];
                const float4* xp = (const float4*)(zx + c * 48 + hb * 8);
                float4 x0 = xp[0], x1 = xp[1];
                acc[0] += wv * x0.x; acc[1] += wv * x0.y; acc[2] += wv * x0.z; acc[3] += wv * x0.w;
                acc[4] += wv * x1.x; acc[5] += wv * x1.y; acc[6] += wv * x1.z; acc[7] += wv * x1.w;
            }
            *(float4*)(dst + hb * 8)     = make_float4(acc[0], acc[1], acc[2], acc[3]);
            *(float4*)(dst + hb * 8 + 4) = make_float4(acc[4], acc[5], acc[6], acc[7]);
        }
    }
    __syncthreads();
    float fqr = ldf(fqrp, 0, f32), fkr = ldf(fkrp, 0, f32);
    float fsv = ldf(fsvp, 0, f32), fsve = ldf(fsvep, 0, f32);
    float* z = zx;
    for (int g = 0; g < 8; g++) {
        float c0 = scoef[g], c1 = scoef[8 + g], c2 = scoef[16 + g];
        for (int r = 0; r < 3; r++) {
            int chunk = tid + 256 * r;
            if (chunk >= 576) break;
            int i = chunk / 12, j0 = (chunk % 12) * 4;
            float zq[4] = {0,0,0,0}, zr[4] = {0,0,0,0}, zk[4] = {0,0,0,0};
#pragma unroll
            for (int c = 0; c < 8; c++) {
                ushort4 uq = *(const ushort4*)(qe + c * 2304 + i * 48 + j0);
                ushort4 uk = *(const ushort4*)(keT + c * 2304 + i * 48 + j0);
                float qi = qsh[(g * 8 + c) * 48 + i];
                float4 kk = *(const float4*)(ksh + (g * 8 + c) * 48 + j0);
                zq[0] += qi * kk.x; zq[1] += qi * kk.y; zq[2] += qi * kk.z; zq[3] += qi * kk.w;
                zr[0] += qi * b2f(uq.x); zr[1] += qi * b2f(uq.y); zr[2] += qi * b2f(uq.z); zr[3] += qi * b2f(uq.w);
                zk[0] += kk.x * b2f(uk.x); zk[1] += kk.y * b2f(uk.y); zk[2] += kk.z * b2f(uk.z); zk[3] += kk.w * b2f(uk.w);
            }
            float4 o4;
            o4.x = c0 * zq[0] + c1 * (fqr * zr[0]) + c2 * (fkr * zk[0]);
            o4.y = c0 * zq[1] + c1 * (fqr * zr[1]) + c2 * (fkr * zk[1]);
            o4.z = c0 * zq[2] + c1 * (fqr * zr[2]) + c2 * (fkr * zk[2]);
            o4.w = c0 * zq[3] + c1 * (fqr * zr[3]) + c2 * (fkr * zk[3]);
            *(float4*)(z + i * 52 + j0) = o4;
        }
        __syncthreads();
        {
            int wv = tid >> 6, lane = tid & 63;
            for (int rr = 0; rr < 12; rr++) {
                int i = wv * 12 + rr;
                float val = (lane < 48) ? z[i * 52 + lane] : -1e30f;
                float m = val;
                for (int off = 32; off >= 1; off >>= 1) m = fmaxf(m, __shfl_xor(m, off));
                float e = (lane < 48) ? __expf(val - m) : 0.0f;
                float s = e;
                for (int off = 32; off >= 1; off >>= 1) s += __shfl_xor(s, off);
                if (lane < 48) z[i * 52 + lane] = e / s;
            }
        }
        __syncthreads();
        {
            int c = tid >> 4, u = tid & 15;
            int ch2 = g * 32 + c * 2;
            float oc0 = 0, oc1 = 0, osh = 0;
            if (mode != 0) {
                oc0 = ocoef[ch2 * 2]; oc1 = ocoef[(ch2 + 1) * 2];
                osh = ocoef[ch2 * 2 + 1] + ocoef[(ch2 + 1) * 2 + 1];
            }
            float sumA = 0, sqA = 0, sumB = 0, sqB = 0;
#pragma unroll
            for (int r = 0; r < 3; r++) {
                int i = u + 16 * r;
                float sv = 0.0f, se = 0.0f;
#pragma unroll
                for (int j4 = 0; j4 < 12; j4++) {
                    float4 sm = *(const float4*)(z + i * 52 + j4 * 4);
                    float4 vv = *(const float4*)(vsh + (g * 16 + c) * 48 + j4 * 4);
                    ushort4 veu = *(const ushort4*)(ve + c * 2304 + i * 48 + j4 * 4);
                    sv += sm.x * vv.x + sm.y * vv.y + sm.z * vv.z + sm.w * vv.w;
                    se += sm.x * b2f(veu.x) + sm.y * b2f(veu.y) + sm.z * b2f(veu.z) + sm.w * b2f(veu.w);
                }
                float a = sv * fsv, bb = se * fsve;
                if (mode == 0) {
                    sumA += a; sqA += a * a; sumB += bb; sqB += bb * bb;
                } else {
                    float outv = a * oc0 + bb * oc1 + osh;
                    int oidx = (g * 16 + c) * N_S + i * 2304 + b;
                    if (f32) ((float*)outp)[oidx] = outv;
                    else     ((u16*)outp)[oidx] = f2b(outv);
                }
            }
            if (mode == 0) {
                for (int off = 1; off <= 8; off <<= 1) {
                    sumA += __shfl_xor(sumA, off); sqA += __shfl_xor(sqA, off);
                    sumB += __shfl_xor(sumB, off); sqB += __shfl_xor(sqB, off);
                }
                if (u == 0) {
                    int base = ch2 * 2;
                    osl[base + 0] = sumA; osl[base + 1] = sqA;
                    osl[base + 2] = sumB; osl[base + 3] = sqB;
                }
            }
        }
        __syncthreads();
    }
    if (mode == 0) {
        atomicAdd(&ostat[tid], osl[tid]);
        atomicAdd(&ostat[tid + 256], osl[tid + 256]);
    }
}

extern "C" void kernel_launch(void* const* d_in, const int* in_sizes, int n_in,
                              void* d_out, int out_size, void* d_ws, size_t ws_size,
                              hipStream_t stream) {
    const void* X    = d_in[0];
    const void* Wkv  = d_in[1];
    const void* Wq   = d_in[2];
    const void* gkv  = d_in[3];
    const void* bkv  = d_in[4];
    const void* gq   = d_in[5];
    const void* bq   = d_in[6];
    const void* gsim = d_in[7];
    const void* gout = d_in[9];
    const void* bout = d_in[10];
    const void* rel  = d_in[11];
    const void* fqrp = d_in[12];
    const void* fkrp = d_in[13];
    const void* fsvp = d_in[14];
    const void* fsvep= d_in[15];
    const int* fidx  = (const int*)d_in[16];

    float* W      = (float*)d_ws;
    float* musum  = W;            // 64
    float* gram   = W + 64;       // 4096
    float* sstat  = W + 4160;     // 48
    float* ostat  = W + 4208;     // 512  (zeroed region ends at 4720)
    float* weff   = W + 4720;     // 16384
    float* beff   = W + 21104;    // 256
    float* scoef  = W + 21360;    // 24
    float* ocoef  = W + 21384;    // 512
    int*   flag   = (int*)(W + 21896);    // 1 (+3 pad)
    float* mq     = W + 21900;    // 48*40
    float* mk     = W + 23820;    // 48*40
    float* e1q    = W + 25740;    // 48*8
    float* e1k    = W + 26124;    // 48*8  -> ends 26508
    u16*   qe     = (u16*)(W + 26508);    // 8*2304 u16 (c-major, fallback)
    u16*   keT    = (u16*)(W + 35724);
    u16*   ve     = (u16*)(W + 44940);    // 16*2304 u16 -> ends float 63372
    u16*   weffh  = (u16*)(W + 63372);    // 256*64 u16 -> ends 71564
    u16*   rq2    = (u16*)(W + 71564);    // 96*8 u16 -> ends 71948
    u16*   rk2    = (u16*)(W + 71948);    // -> 72332
    u16*   rv2    = (u16*)(W + 72332);    // 16*96 u16 -> 73100
    u16*   qkv    = (u16*)(W + 73100);    // 2304*256*48 bf16 -> ends 14228876
    u16*   pre2   = qkv + 28311552;       // -> ends 28384652
    u16*   Xt     = (u16*)(W + 28384652); // 2304*3456 bf16 -> ends 32365964

    const size_t need1 = (size_t)28384652 * 4;   // ~113.5 MB (tier 1)
    const size_t need2 = (size_t)32365964 * 4;   // ~129.5 MB (tier 2, +Xt)
    const int tier = (ws_size >= need2) ? 2 : ((ws_size >= need1) ? 1 : 0);

    k_detect<<<1, 256, 0, stream>>>((const u16*)X, flag);
    k_zero<<<8, 256, 0, stream>>>(W);
    k_emb<<<9, 256, 0, stream>>>(rel, fidx, flag, qe, keT, ve, rq2, rk2, rv2);
    k_gram<<<256, 256, 0, stream>>>(X, flag, musum, gram);
    k_fold<<<1, 256, 0, stream>>>(Wkv, Wq, gkv, bkv, gq, bq, flag, musum, gram, weff, weffh, beff);
    if (tier > 0) {
        k_mtab<<<1, 128, 0, stream>>>(rel, flag, mq, mk, e1q, e1k);
        if (tier == 2) {
            k_xpose<<<dim3(48, 36), 256, 0, stream>>>(X, flag, Xt);
            k_stage1m<<<2304, 256, 0, stream>>>(Xt, weffh, beff, mq, mk, e1q, e1k, sstat, qkv);
        } else {
            k_stage1<<<2304, 256, 0, stream>>>(X, weff, beff, mq, mk, e1q, e1k, flag, sstat, qkv);
        }
        k_simcoef<<<1, 32, 0, stream>>>(sstat, gsim, fqrp, fkrp, flag, 0, scoef);
        k_attn3<<<dim3(2304, 8), 64, 0, stream>>>(qkv, rq2, rk2, rv2, scoef,
                                                  fqrp, fkrp, fsvp, fsvep, flag, ostat, pre2);
        k_outcoef<<<1, 256, 0, stream>>>(ostat, gout, bout, flag, ocoef);
        k_final<<<dim3(128, 48), 256, 0, stream>>>(pre2, ocoef, flag, d_out);
    } else {
        k_qkstat<<<2304, 256, 0, stream>>>(X, weff, beff, qe, keT, fqrp, fkrp, flag, sstat);
        k_simcoef<<<1, 32, 0, stream>>>(sstat, gsim, fqrp, fkrp, flag, 1, scoef);
        k_attn<<<2304, 256, 0, stream>>>(X, weff, beff, qe, keT, ve, scoef, ocoef,
                                         fqrp, fkrp, fsvp, fsvep, flag, ostat, d_out, 0);
        k_outcoef<<<1, 256, 0, stream>>>(ostat, gout, bout, flag, ocoef);
        k_attn<<<2304, 256, 0, stream>>>(X, weff, beff, qe, keT, ve, scoef, ocoef,
                                         fqrp, fkrp, fsvp, fsvep, flag, ostat, d_out, 2);
    }
}

// Round 11
// 562.475 us; speedup vs baseline: 1.8841x; 1.7309x over previous
//
#include <hip/hip_runtime.h>

// RelativeAxialAttention on MI355X (gfx950). Single-attention-pass design.
// K=48, G=8, DK=8, DV=16, CIN=64, B = 2304.
//
// Math shortcuts:
//  * kv/q BatchNorm folded into GEMM weights via x-gram.
//  * sim BN: softmax-invariant mean/beta; scales from CLOSED-FORM moments
//    (grams + Toeplitz windowed outer-products, k_mtab) -- no logits pass.
//  * k_stage1 GEMM on MFMA bf16 (stage1m) with X pre-transposed (k_xpose).
//  * k_attn3 MFMA single-wave per (b,g) (round 9 version).
//  * ROUND 11 = round 10 (replicated accumulators: ostat x256 by b&255,
//    sstat x256, gram/musum x8 + reduction kernels) with the WORKSPACE LAYOUT
//    BUG FIXED: round 10 transcribed u16 buffer extents at half size, so ve
//    overwrote rq2/rk2/rv2 (absmax 27). All u16 extents now correct.
// Tiers: ws>=130.2MB full path; >=114.3MB VALU stage1; else recompute fallback.

typedef unsigned short u16;
typedef __attribute__((ext_vector_type(8))) short short8v;
typedef __attribute__((ext_vector_type(4))) float float4v;

#define N_S 110592
#define N_B 2304

__device__ __forceinline__ float b2f(u16 v) {
    return __builtin_bit_cast(float, ((unsigned)v) << 16);
}
__device__ __forceinline__ u16 f2b(float f) {
    unsigned u = __builtin_bit_cast(unsigned, f);
    u = (u + 0x7FFFu + ((u >> 16) & 1u)) >> 16;
    return (u16)u;
}
__device__ __forceinline__ float ldf(const void* p, int idx, int f32) {
    return f32 ? ((const float*)p)[idx] : b2f(((const u16*)p)[idx]);
}

// ---------------- dtype detection ----------------
__global__ void k_detect(const u16* X, int* flag) {
    __shared__ int tot;
    if (threadIdx.x == 0) tot = 0;
    __syncthreads();
    int cnt = 0;
#pragma unroll
    for (int k = 0; k < 8; k++) {
        u16 v = X[(threadIdx.x * 8 + k) * 2];
        int e = (v >> 7) & 0xFF;
        cnt += (e >= 0x70 && e <= 0x8F) ? 1 : 0;
    }
    atomicAdd(&tot, cnt);
    __syncthreads();
    if (threadIdx.x == 0) flag[0] = (tot < 1024) ? 1 : 0;   // 1 = f32
}

// ---------------- zero stats region (includes all replicas) ----------------
#define ZERO_N 180800
__global__ void k_zero(float* w) {
    for (int i = blockIdx.x * blockDim.x + threadIdx.x; i < ZERO_N; i += gridDim.x * blockDim.x)
        w[i] = 0.0f;
}

// ---------------- build emb tables ----------------
__global__ void k_emb(const void* rel, const int* fidx, const int* flag,
                      u16* qe, u16* keT, u16* ve, u16* rq2, u16* rk2, u16* rv2) {
    int f32 = flag[0];
    if (blockIdx.x == 0 && threadIdx.x < 96) {
        int d = threadIdx.x;
#pragma unroll
        for (int c = 0; c < 8; c++) {
            rq2[d * 8 + c] = (d < 95) ? f2b(ldf(rel, c * 95 + d, f32)) : (u16)0;
            rk2[d * 8 + c] = (d < 95) ? f2b(ldf(rel, (8 + c) * 95 + d, f32)) : (u16)0;
        }
#pragma unroll
        for (int c = 0; c < 16; c++)
            rv2[c * 96 + d] = (d < 95) ? f2b(ldf(rel, (16 + c) * 95 + d, f32)) : (u16)0;
    }
    int t = blockIdx.x * 256 + threadIdx.x;
    if (t >= 2304) return;
    int i = t / 48, j = t % 48;
    int fij = fidx[i * 48 + j];
    int fji = fidx[j * 48 + i];
#pragma unroll
    for (int c = 0; c < 8; c++) {
        qe[c * 2304 + t]  = f2b(ldf(rel, c * 95 + fij, f32));
        keT[c * 2304 + t] = f2b(ldf(rel, (8 + c) * 95 + fji, f32));
    }
#pragma unroll
    for (int c = 0; c < 16; c++)
        ve[c * 2304 + t] = f2b(ldf(rel, (16 + c) * 95 + fij, f32));
}

// ---------------- Toeplitz moment tables ----------------
__global__ void k_mtab(const void* rel, const int* flag,
                       float* mq, float* mk, float* e1q, float* e1k) {
    __shared__ float rl[1520];
    int f32 = flag[0];
    int tid = threadIdx.x;
    for (int idx = tid; idx < 1520; idx += 128) rl[idx] = ldf(rel, idx, f32);
    __syncthreads();
    if (tid >= 96) return;
    int tbl = tid / 48, i = tid % 48;
    const float* R = rl + tbl * 760;
    float* M = (tbl ? mk : mq) + i * 40;
    float* E = (tbl ? e1k : e1q) + i * 8;
    float acc[36], e[8];
#pragma unroll
    for (int x = 0; x < 36; x++) acc[x] = 0.0f;
#pragma unroll
    for (int c = 0; c < 8; c++) e[c] = 0.0f;
    for (int d = i; d < i + 48; d++) {
        float v[8];
#pragma unroll
        for (int c = 0; c < 8; c++) { v[c] = R[c * 95 + d]; e[c] += v[c]; }
        int idx = 0;
#pragma unroll
        for (int c = 0; c < 8; c++)
#pragma unroll
            for (int c2 = c; c2 < 8; c2++) { acc[idx] += v[c] * v[c2]; idx++; }
    }
    int idx = 0;
#pragma unroll
    for (int c = 0; c < 8; c++) {
        E[c] = e[c];
#pragma unroll
        for (int c2 = c; c2 < 8; c2++) {
            M[idx] = (c2 == c ? 1.0f : 2.0f) * acc[idx];
            idx++;
        }
    }
}

// ---------------- x gram (8-way replicated accumulators) ----------------
__global__ __launch_bounds__(256) void k_gram(const void* Xv, const int* flag,
                                              float* musumR, float* gramR) {
    __shared__ float xs[64 * 65];
    int f32 = flag[0];
    int tid = threadIdx.x;
    int rep = blockIdx.x & 7;
    int cb1 = tid >> 4, cb2 = tid & 15;
    float acc[4][4];
#pragma unroll
    for (int a = 0; a < 4; a++)
#pragma unroll
        for (int b = 0; b < 4; b++) acc[a][b] = 0.0f;
    float mur = 0.0f;
    for (int tile = blockIdx.x; tile < 1728; tile += gridDim.x) {
        int s0 = tile * 64;
        __syncthreads();
#pragma unroll
        for (int r = 0; r < 4; r++) {
            int idx4 = tid + 256 * r;
            int c = idx4 >> 4, sl = (idx4 & 15) * 4;
            if (f32) {
                float4 u = *(const float4*)((const float*)Xv + c * N_S + s0 + sl);
                xs[c * 65 + sl + 0] = u.x; xs[c * 65 + sl + 1] = u.y;
                xs[c * 65 + sl + 2] = u.z; xs[c * 65 + sl + 3] = u.w;
            } else {
                ushort4 u = *(const ushort4*)((const u16*)Xv + c * N_S + s0 + sl);
                xs[c * 65 + sl + 0] = b2f(u.x); xs[c * 65 + sl + 1] = b2f(u.y);
                xs[c * 65 + sl + 2] = b2f(u.z); xs[c * 65 + sl + 3] = b2f(u.w);
            }
        }
        __syncthreads();
        for (int s = 0; s < 64; s++) {
            float av[4], bv[4];
#pragma unroll
            for (int a = 0; a < 4; a++) av[a] = xs[(cb1 + 16 * a) * 65 + s];
#pragma unroll
            for (int b = 0; b < 4; b++) bv[b] = xs[(cb2 + 16 * b) * 65 + s];
#pragma unroll
            for (int a = 0; a < 4; a++)
#pragma unroll
                for (int b = 0; b < 4; b++) acc[a][b] += av[a] * bv[b];
        }
        if (tid < 64) {
            for (int s = 0; s < 64; s++) mur += xs[tid * 65 + s];
        }
    }
#pragma unroll
    for (int a = 0; a < 4; a++)
#pragma unroll
        for (int b = 0; b < 4; b++)
            atomicAdd(&gramR[rep * 4096 + (cb1 + 16 * a) * 64 + (cb2 + 16 * b)], acc[a][b]);
    if (tid < 64) atomicAdd(&musumR[rep * 64 + tid], mur);
}

// ---------------- reduce gram/musum replicas ----------------
__global__ void k_gsum(const float* musumR, const float* gramR, float* musum, float* gram) {
    int idx = blockIdx.x * 256 + threadIdx.x;
    if (idx < 4096) {
        float s = 0.0f;
#pragma unroll
        for (int r = 0; r < 8; r++) s += gramR[r * 4096 + idx];
        gram[idx] = s;
    } else if (idx < 4160) {
        int c = idx - 4096;
        float s = 0.0f;
#pragma unroll
        for (int r = 0; r < 8; r++) s += musumR[r * 64 + c];
        musum[c] = s;
    }
}

// ---------------- fold BN into weights (f32 + bf16 copies) ----------------
__global__ __launch_bounds__(256) void k_fold(const void* Wkv, const void* Wq,
        const void* gkv, const void* bkv, const void* gq, const void* bq,
        const int* flag, const float* musum, const float* gram,
        float* weff, u16* weffh, float* beff) {
    int f32 = flag[0];
    int o = threadIdx.x;
    float gam, bet;
    float w[64];
    if (o < 192) {
#pragma unroll
        for (int c = 0; c < 64; c++) w[c] = ldf(Wkv, o * 64 + c, f32);
        gam = ldf(gkv, o, f32); bet = ldf(bkv, o, f32);
    } else {
        int oq = o - 192;
#pragma unroll
        for (int c = 0; c < 64; c++) w[c] = ldf(Wq, oq * 64 + c, f32);
        gam = ldf(gq, oq, f32); bet = ldf(bq, oq, f32);
    }
    const float inv = 1.0f / (float)N_S;
    float mean = 0.0f;
#pragma unroll
    for (int c = 0; c < 64; c++) mean += w[c] * musum[c];
    mean *= inv;
    float e2 = 0.0f;
    for (int c = 0; c < 64; c++) {
        float t = 0.0f;
#pragma unroll
        for (int c2 = 0; c2 < 64; c2++) t += w[c2] * gram[c * 64 + c2];
        e2 += w[c] * t;
    }
    e2 *= inv;
    float var = e2 - mean * mean;
    if (var < 0.0f) var = 0.0f;
    float sc = gam * rsqrtf(var + 1e-5f);
#pragma unroll
    for (int c = 0; c < 64; c++) {
        float wv = sc * w[c];
        weff[o * 64 + c] = wv;
        weffh[o * 64 + c] = f2b(wv);
    }
    beff[o] = bet - sc * mean;
}

// ---------------- transpose X -> Xt[b][h][c] bf16, h-stride 72 ----------------
__global__ __launch_bounds__(256) void k_xpose(const void* Xv, const int* flag, u16* Xt) {
    __shared__ float tile[64][65];
    int f32 = flag[0];
    int h = blockIdx.x, b0 = blockIdx.y * 64, tid = threadIdx.x;
#pragma unroll
    for (int r = 0; r < 4; r++) {
        int idx = tid + 256 * r;
        int c = idx >> 4, bq = (idx & 15) * 4;
        if (f32) {
            float4 u = *(const float4*)((const float*)Xv + (size_t)c * N_S + h * 2304 + b0 + bq);
            tile[c][bq + 0] = u.x; tile[c][bq + 1] = u.y;
            tile[c][bq + 2] = u.z; tile[c][bq + 3] = u.w;
        } else {
            ushort4 u = *(const ushort4*)((const u16*)Xv + (size_t)c * N_S + h * 2304 + b0 + bq);
            tile[c][bq + 0] = b2f(u.x); tile[c][bq + 1] = b2f(u.y);
            tile[c][bq + 2] = b2f(u.z); tile[c][bq + 3] = b2f(u.w);
        }
    }
    __syncthreads();
#pragma unroll
    for (int r = 0; r < 4; r++) {
        int idx = tid + 256 * r;
        int bb = idx >> 4, cq = (idx & 15) * 4;
        ushort4 o4 = make_ushort4(f2b(tile[cq + 0][bb]), f2b(tile[cq + 1][bb]),
                                  f2b(tile[cq + 2][bb]), f2b(tile[cq + 3][bb]));
        *(ushort4*)(Xt + (size_t)(b0 + bb) * 3456 + h * 72 + cq) = o4;
    }
}

// ================= FAST PATH (tier 2) =================
// stage1m: MFMA qkv GEMM + closed-form sim-BN moments (replicated sstat).
__global__ __launch_bounds__(256) void k_stage1m(const u16* Xt, const u16* weffh, const float* beff,
        const float* mq, const float* mk, const float* e1q, const float* e1k,
        float* sstatR, u16* qkv) {
    __shared__ __align__(16) u16 xs[3456];      // [h][72] bf16
    __shared__ __align__(16) u16 qkbf[6144];    // q at [(g*8+c)*48+i], k at +3072
    __shared__ float sbias[256];
    __shared__ float red[48];
    int b = blockIdx.x, tid = threadIdx.x;
    {
        const uint4* src = (const uint4*)(Xt + (size_t)b * 3456);
        uint4* dst = (uint4*)xs;
        for (int idx = tid; idx < 432; idx += 256) dst[idx] = src[idx];
    }
    sbias[tid] = beff[tid];
    if (tid < 48) red[tid] = 0.0f;
    __syncthreads();
    {
        int wv = tid >> 6, l = tid & 63;
        int lm = l & 15, lk8 = (l >> 4) * 8;
        short8v Bf[3][2];
#pragma unroll
        for (int ct = 0; ct < 3; ct++)
#pragma unroll
            for (int ks = 0; ks < 2; ks++)
                Bf[ct][ks] = *(const short8v*)(xs + (ct * 16 + lm) * 72 + ks * 32 + lk8);
        float4v acc[4][3];
#pragma unroll
        for (int a = 0; a < 4; a++)
#pragma unroll
            for (int c = 0; c < 3; c++)
#pragma unroll
                for (int e = 0; e < 4; e++) acc[a][c][e] = 0.0f;
#pragma unroll
        for (int rt = 0; rt < 4; rt++) {
            int orow = wv * 64 + rt * 16 + lm;
#pragma unroll
            for (int ks = 0; ks < 2; ks++) {
                short8v Af = *(const short8v*)(weffh + orow * 64 + ks * 32 + lk8);
#pragma unroll
                for (int ct = 0; ct < 3; ct++)
                    acc[rt][ct] = __builtin_amdgcn_mfma_f32_16x16x32_bf16(Af, Bf[ct][ks], acc[rt][ct], 0, 0, 0);
            }
        }
        int rbase = (l >> 4) * 4;
        u16* qdst = qkv + (size_t)b * 12288;
#pragma unroll
        for (int rt = 0; rt < 4; rt++) {
#pragma unroll
            for (int ct = 0; ct < 3; ct++) {
                int h = ct * 16 + lm;
#pragma unroll
                for (int rg = 0; rg < 4; rg++) {
                    int o = wv * 64 + rt * 16 + rbase + rg;
                    u16 vb = f2b(acc[rt][ct][rg] + sbias[o]);
                    int row, lq = -1;
                    if (o >= 192) {
                        int g = (o - 192) >> 3, c = (o - 192) & 7;
                        row = g * 32 + c;
                        lq = (g * 8 + c) * 48;
                    } else {
                        int g = o / 24, t = o % 24;
                        if (t < 8) { row = g * 32 + 8 + t; lq = 3072 + (g * 8 + t) * 48; }
                        else       { row = g * 32 + 16 + (t - 8); }
                    }
                    qdst[row * 48 + h] = vb;
                    if (lq >= 0) qkbf[lq + h] = vb;
                }
            }
        }
    }
    __syncthreads();
    {
        int g = tid >> 5, t = tid & 31;
        float gq[36], gk[36], sq[8], sk[8];
        float s1qr = 0, s1kr = 0, s2qr = 0, s2kr = 0;
#pragma unroll
        for (int x = 0; x < 36; x++) { gq[x] = 0.0f; gk[x] = 0.0f; }
#pragma unroll
        for (int c = 0; c < 8; c++) { sq[c] = 0.0f; sk[c] = 0.0f; }
#pragma unroll
        for (int pass = 0; pass < 2; pass++) {
            int i = t + pass * 32;
            if (i >= 48) break;
            float qv[8], kvv[8];
#pragma unroll
            for (int c = 0; c < 8; c++) {
                qv[c]  = b2f(qkbf[(g * 8 + c) * 48 + i]);
                kvv[c] = b2f(qkbf[3072 + (g * 8 + c) * 48 + i]);
            }
            const float* mqr = mq + i * 40;
            const float* mkr = mk + i * 40;
            const float* eqr = e1q + i * 8;
            const float* ekr = e1k + i * 8;
            int idx = 0;
#pragma unroll
            for (int c = 0; c < 8; c++) {
                sq[c] += qv[c]; sk[c] += kvv[c];
                s1qr += qv[c] * eqr[c];
                s1kr += kvv[c] * ekr[c];
#pragma unroll
                for (int c2 = c; c2 < 8; c2++) {
                    float oq = qv[c] * qv[c2], ok = kvv[c] * kvv[c2];
                    gq[idx] += oq; gk[idx] += ok;
                    s2qr += mqr[idx] * oq;
                    s2kr += mkr[idx] * ok;
                    idx++;
                }
            }
        }
#pragma unroll
        for (int off = 1; off <= 16; off <<= 1) {
#pragma unroll
            for (int x = 0; x < 36; x++) { gq[x] += __shfl_xor(gq[x], off); gk[x] += __shfl_xor(gk[x], off); }
#pragma unroll
            for (int c = 0; c < 8; c++) { sq[c] += __shfl_xor(sq[c], off); sk[c] += __shfl_xor(sk[c], off); }
            s1qr += __shfl_xor(s1qr, off); s1kr += __shfl_xor(s1kr, off);
            s2qr += __shfl_xor(s2qr, off); s2kr += __shfl_xor(s2kr, off);
        }
        if (t == 0) {
            float s1qk = 0.0f, s2qk = 0.0f;
            int idx = 0;
#pragma unroll
            for (int c = 0; c < 8; c++) {
                s1qk += sq[c] * sk[c];
#pragma unroll
                for (int c2 = c; c2 < 8; c2++) {
                    float w = (c2 == c) ? 1.0f : 2.0f;
                    s2qk += w * gq[idx] * gk[idx];
                    idx++;
                }
            }
            red[0 * 8 + g] = s1qk;  red[1 * 8 + g] = s1qr;  red[2 * 8 + g] = s1kr;
            red[3 * 8 + g] = s2qk;  red[4 * 8 + g] = s2qr;  red[5 * 8 + g] = s2kr;
        }
    }
    __syncthreads();
    if (tid < 48) atomicAdd(&sstatR[(b & 255) * 48 + tid], red[tid]);
}

// ================= tier-1 stage1 (VALU, reads X directly) =================
__global__ __launch_bounds__(256) void k_stage1(const void* Xv, const float* weff, const float* beff,
        const float* mq, const float* mk, const float* e1q, const float* e1k,
        const int* flag, float* sstatR, u16* qkv) {
    __shared__ __align__(16) float xs[3072];
    __shared__ __align__(16) float qk[6144];
    __shared__ float red[48];
    int f32 = flag[0];
    int b = blockIdx.x, tid = threadIdx.x;
    for (int idx = tid; idx < 3072; idx += 256) {
        int c = idx / 48, h = idx % 48;
        xs[idx] = ldf(Xv, c * N_S + h * 2304 + b, f32);
    }
    __syncthreads();
    {
        int g = tid >> 5, r = tid & 31;
        int o;
        if (r < 8)       o = 192 + g * 8 + r;
        else if (r < 16) o = g * 24 + (r - 8);
        else             o = g * 24 + 8 + (r - 16);
        float wr[64];
        const float4* wrow = (const float4*)(weff + o * 64);
#pragma unroll
        for (int c4 = 0; c4 < 16; c4++) {
            float4 t4 = wrow[c4];
            wr[c4 * 4 + 0] = t4.x; wr[c4 * 4 + 1] = t4.y; wr[c4 * 4 + 2] = t4.z; wr[c4 * 4 + 3] = t4.w;
        }
        float bias = beff[o];
        u16* gdst = qkv + (b * 256 + tid) * 48;
        float* ldst = (r < 8) ? (qk + g * 768 + r * 48)
                    : (r < 16 ? (qk + g * 768 + 384 + (r - 8) * 48) : nullptr);
#pragma unroll
        for (int hb = 0; hb < 6; hb++) {
            float acc[8];
#pragma unroll
            for (int u = 0; u < 8; u++) acc[u] = bias;
#pragma unroll
            for (int c = 0; c < 64; c++) {
                float wv = wr[c];
                const float4* xp = (const float4*)(xs + c * 48 + hb * 8);
                float4 x0 = xp[0], x1 = xp[1];
                acc[0] += wv * x0.x; acc[1] += wv * x0.y; acc[2] += wv * x0.z; acc[3] += wv * x0.w;
                acc[4] += wv * x1.x; acc[5] += wv * x1.y; acc[6] += wv * x1.z; acc[7] += wv * x1.w;
            }
            ushort4 p0 = make_ushort4(f2b(acc[0]), f2b(acc[1]), f2b(acc[2]), f2b(acc[3]));
            ushort4 p1 = make_ushort4(f2b(acc[4]), f2b(acc[5]), f2b(acc[6]), f2b(acc[7]));
            *(ushort4*)(gdst + hb * 8)     = p0;
            *(ushort4*)(gdst + hb * 8 + 4) = p1;
            if (ldst) {
                *(float4*)(ldst + hb * 8)     = make_float4(acc[0], acc[1], acc[2], acc[3]);
                *(float4*)(ldst + hb * 8 + 4) = make_float4(acc[4], acc[5], acc[6], acc[7]);
            }
        }
    }
    __syncthreads();
    {
        int g = tid >> 5, t = tid & 31;
        float gq[36], gk[36], sq[8], sk[8];
        float s1qr = 0, s1kr = 0, s2qr = 0, s2kr = 0;
#pragma unroll
        for (int x = 0; x < 36; x++) { gq[x] = 0.0f; gk[x] = 0.0f; }
#pragma unroll
        for (int c = 0; c < 8; c++) { sq[c] = 0.0f; sk[c] = 0.0f; }
#pragma unroll
        for (int pass = 0; pass < 2; pass++) {
            int i = t + pass * 32;
            if (i >= 48) break;
            float qv[8], kvv[8];
#pragma unroll
            for (int c = 0; c < 8; c++) {
                qv[c]  = qk[g * 768 + c * 48 + i];
                kvv[c] = qk[g * 768 + 384 + c * 48 + i];
            }
            const float* mqr = mq + i * 40;
            const float* mkr = mk + i * 40;
            const float* eqr = e1q + i * 8;
            const float* ekr = e1k + i * 8;
            int idx = 0;
#pragma unroll
            for (int c = 0; c < 8; c++) {
                sq[c] += qv[c]; sk[c] += kvv[c];
                s1qr += qv[c] * eqr[c];
                s1kr += kvv[c] * ekr[c];
#pragma unroll
                for (int c2 = c; c2 < 8; c2++) {
                    float oq = qv[c] * qv[c2], ok = kvv[c] * kvv[c2];
                    gq[idx] += oq; gk[idx] += ok;
                    s2qr += mqr[idx] * oq;
                    s2kr += mkr[idx] * ok;
                    idx++;
                }
            }
        }
#pragma unroll
        for (int off = 1; off <= 16; off <<= 1) {
#pragma unroll
            for (int x = 0; x < 36; x++) { gq[x] += __shfl_xor(gq[x], off); gk[x] += __shfl_xor(gk[x], off); }
#pragma unroll
            for (int c = 0; c < 8; c++) { sq[c] += __shfl_xor(sq[c], off); sk[c] += __shfl_xor(sk[c], off); }
            s1qr += __shfl_xor(s1qr, off); s1kr += __shfl_xor(s1kr, off);
            s2qr += __shfl_xor(s2qr, off); s2kr += __shfl_xor(s2kr, off);
        }
        if (t == 0) {
            float s1qk = 0.0f, s2qk = 0.0f;
            int idx = 0;
#pragma unroll
            for (int c = 0; c < 8; c++) {
                s1qk += sq[c] * sk[c];
#pragma unroll
                for (int c2 = c; c2 < 8; c2++) {
                    float w = (c2 == c) ? 1.0f : 2.0f;
                    s2qk += w * gq[idx] * gk[idx];
                    idx++;
                }
            }
            red[0 * 8 + g] = s1qk;  red[1 * 8 + g] = s1qr;  red[2 * 8 + g] = s1kr;
            red[3 * 8 + g] = s2qk;  red[4 * 8 + g] = s2qr;  red[5 * 8 + g] = s2kr;
        }
    }
    __syncthreads();
    if (tid < 48) atomicAdd(&sstatR[(b & 255) * 48 + tid], red[tid]);
}

// scaled=1: sstat already includes fqr/fkr (fallback). scaled=0: apply here.
// Reduces 256 sstat replicas inline.
__global__ void k_simcoef(const float* sstatR, const void* gsim, const void* fqrp, const void* fkrp,
                          const int* flag, int scaled, float* scoef) {
    int ch = threadIdx.x;
    if (ch >= 24) return;
    int f32 = flag[0];
    float f = 1.0f;
    if (!scaled) {
        if (ch >= 16)     f = ldf(fkrp, 0, f32);
        else if (ch >= 8) f = ldf(fqrp, 0, f32);
    }
    float s1 = 0.0f, s2 = 0.0f;
#pragma unroll 8
    for (int r = 0; r < 256; r++) {
        s1 += sstatR[r * 48 + ch];
        s2 += sstatR[r * 48 + 24 + ch];
    }
    const float n = 2304.0f * 2304.0f;
    float mean = f * s1 / n;
    float var = f * f * s2 / n - mean * mean;
    if (var < 0.0f) var = 0.0f;
    scoef[ch] = ldf(gsim, ch, f32) * rsqrtf(var + 1e-5f);
}

// attn3: one WAVE per (b, g). MFMA everywhere; in-register softmax; LDS 18432 B.
// Stats go to 256-way replicated ostat (b & 255) -> 9-way contention max.
__global__ __launch_bounds__(64) void k_attn3(const u16* qkv,
        const u16* rq2, const u16* rk2, const u16* rv2,
        const float* scoef, const void* fqrp, const void* fkrp,
        const void* fsvp, const void* fsvep, const int* flag,
        float* ostatR, u16* pre2) {
    __shared__ __align__(16) u16 qT[384];   // [i][c]
    __shared__ __align__(16) u16 kT[384];   // [j][c]
    __shared__ __align__(16) u16 R[8448];   // union {qrB[48][48], krB[48][56]} -> {zb[48][72], zd[48][104]}
    int f32 = flag[0];
    int b = blockIdx.x, g = blockIdx.y, tid = threadIdx.x;
    int lr = tid & 15, lk = tid >> 4;
    u16* qrB = R;             // stride 48
    u16* krB = R + 2304;      // stride 56
    u16* zb  = R;             // stride 72 (cols 48..71 zero pad, K=64)
    u16* zd  = R + 3456;      // stride 104 (cols 95..103 pad, K=96)
    const u16* src = qkv + (b * 256 + g * 32) * 48;
    // stage q,k transposed [h][c]
#pragma unroll
    for (int e = 0; e < 6; e++) {
        int idx = tid + 64 * e;
        int c = idx / 48, h = idx % 48;
        qT[h * 8 + c] = src[c * 48 + h];
        kT[h * 8 + c] = src[(8 + c) * 48 + h];
    }
    __syncthreads();
    short8v z8 = {0, 0, 0, 0, 0, 0, 0, 0};
    // A-frags (K=8 padded to 32: only lanes lk==0 carry data)
    short8v aq[3], ak[3];
#pragma unroll
    for (int tm = 0; tm < 3; tm++) {
        aq[tm] = (lk == 0) ? *(const short8v*)(qT + (tm * 16 + lr) * 8) : z8;
        ak[tm] = (lk == 0) ? *(const short8v*)(kT + (tm * 16 + lr) * 8) : z8;
    }
    // QR = q^T rel_q, KR = k^T rel_k (B-frags straight from global) -> banded stores
#pragma unroll
    for (int tn = 0; tn < 6; tn++) {
        short8v bq = (lk == 0) ? *(const short8v*)(rq2 + (tn * 16 + lr) * 8) : z8;
        short8v bk = (lk == 0) ? *(const short8v*)(rk2 + (tn * 16 + lr) * 8) : z8;
#pragma unroll
        for (int tm = 0; tm < 3; tm++) {
            float4v a0 = {0, 0, 0, 0}, a1 = {0, 0, 0, 0};
            a0 = __builtin_amdgcn_mfma_f32_16x16x32_bf16(aq[tm], bq, a0, 0, 0, 0);
            a1 = __builtin_amdgcn_mfma_f32_16x16x32_bf16(ak[tm], bk, a1, 0, 0, 0);
#pragma unroll
            for (int r = 0; r < 4; r++) {
                int i = tm * 16 + lk * 4 + r;
                int dd = tn * 16 + lr - i;
                if (dd >= 0 && dd < 48) {
                    qrB[i * 48 + dd] = f2b(a0[r]);
                    krB[i * 56 + dd] = f2b(a1[r]);
                }
            }
        }
    }
    // QK = q^T k (kept in regs; becomes P in-place)
    float4v qk[3][3];
#pragma unroll
    for (int tn = 0; tn < 3; tn++) {
        short8v bkf = (lk == 0) ? *(const short8v*)(kT + (tn * 16 + lr) * 8) : z8;
#pragma unroll
        for (int tm = 0; tm < 3; tm++) {
            float4v a = {0, 0, 0, 0};
            qk[tm][tn] = __builtin_amdgcn_mfma_f32_16x16x32_bf16(aq[tm], bkf, a, 0, 0, 0);
        }
    }
    __syncthreads();
    float fqr = ldf(fqrp, 0, f32), fkr = ldf(fkrp, 0, f32);
    float fsv = ldf(fsvp, 0, f32), fsve = ldf(fsvep, 0, f32);
    float c0 = scoef[g], c1f = scoef[8 + g] * fqr, c2f = scoef[16 + g] * fkr;
    // combine + in-register softmax (row = 16-lane group sharing lk)
#pragma unroll
    for (int tm = 0; tm < 3; tm++)
#pragma unroll
        for (int r = 0; r < 4; r++) {
            int i = tm * 16 + lk * 4 + r;
            float v0[3];
#pragma unroll
            for (int tn = 0; tn < 3; tn++) {
                int j = tn * 16 + lr;
                v0[tn] = c0 * qk[tm][tn][r]
                       + c1f * b2f(qrB[i * 48 + 47 - j])
                       + c2f * b2f(krB[j * 56 + 47 - i]);
            }
            float m = fmaxf(fmaxf(v0[0], v0[1]), v0[2]);
#pragma unroll
            for (int off = 1; off <= 8; off <<= 1) m = fmaxf(m, __shfl_xor(m, off));
            float e0 = __expf(v0[0] - m), e1 = __expf(v0[1] - m), e2 = __expf(v0[2] - m);
            float s = e0 + e1 + e2;
#pragma unroll
            for (int off = 1; off <= 8; off <<= 1) s += __shfl_xor(s, off);
            float inv = 1.0f / s;
            qk[tm][0][r] = e0 * inv;
            qk[tm][1][r] = e1 * inv;
            qk[tm][2][r] = e2 * inv;
        }
    __syncthreads();
    // zero zb+zd (8448 u16 = 1056 uint4), then scatter P into zb (dense) + zd (diag)
#pragma unroll
    for (int e = 0; e < 17; e++) {
        int idx = tid + 64 * e;
        if (idx < 1056) {
            uint4 zz = {0, 0, 0, 0};
            ((uint4*)R)[idx] = zz;
        }
    }
    __syncthreads();
#pragma unroll
    for (int tm = 0; tm < 3; tm++)
#pragma unroll
        for (int r = 0; r < 4; r++) {
            int i = tm * 16 + lk * 4 + r;
#pragma unroll
            for (int tn = 0; tn < 3; tn++) {
                int j = tn * 16 + lr;
                u16 pb = f2b(qk[tm][tn][r]);
                zb[i * 72 + j] = pb;
                zd[i * 104 + i + 47 - j] = pb;
            }
        }
    __syncthreads();
    // SV = P v^T (K=64 pad; v B-frags from global qkv), SVE = Zd rel_v^T (K=96)
    float4v sv[3], se[3];
#pragma unroll
    for (int tm = 0; tm < 3; tm++) { sv[tm] = (float4v){0,0,0,0}; se[tm] = (float4v){0,0,0,0}; }
#pragma unroll
    for (int ks = 0; ks < 2; ks++) {
        short8v bv = (ks == 0 || lk < 2) ? *(const short8v*)(src + (16 + lr) * 48 + ks * 32 + lk * 8) : z8;
#pragma unroll
        for (int tm = 0; tm < 3; tm++) {
            short8v af = *(const short8v*)(zb + (tm * 16 + lr) * 72 + ks * 32 + lk * 8);
            sv[tm] = __builtin_amdgcn_mfma_f32_16x16x32_bf16(af, bv, sv[tm], 0, 0, 0);
        }
    }
#pragma unroll
    for (int ks = 0; ks < 3; ks++) {
        short8v br = *(const short8v*)(rv2 + lr * 96 + ks * 32 + lk * 8);
#pragma unroll
        for (int tm = 0; tm < 3; tm++) {
            short8v ad = *(const short8v*)(zd + (tm * 16 + lr) * 104 + ks * 32 + lk * 8);
            se[tm] = __builtin_amdgcn_mfma_f32_16x16x32_bf16(ad, br, se[tm], 0, 0, 0);
        }
    }
    // epilogue: lane holds (c=lr, 12 i's); write pre2 pairs + stats
    int c = lr;
    float sA = 0, qA = 0, sB = 0, qB = 0;
    u16* pdst = pre2 + ((b * 128 + g * 16 + c) * 48) * 2;
#pragma unroll
    for (int tm = 0; tm < 3; tm++)
#pragma unroll
        for (int r = 0; r < 4; r++) {
            int i = tm * 16 + lk * 4 + r;
            float a = sv[tm][r] * fsv, bb = se[tm][r] * fsve;
            *(ushort2*)(pdst + i * 2) = make_ushort2(f2b(a), f2b(bb));
            sA += a; qA += a * a; sB += bb; qB += bb * bb;
        }
    sA += __shfl_xor(sA, 16); qA += __shfl_xor(qA, 16);
    sB += __shfl_xor(sB, 16); qB += __shfl_xor(qB, 16);
    sA += __shfl_xor(sA, 32); qA += __shfl_xor(qA, 32);
    sB += __shfl_xor(sB, 32); qB += __shfl_xor(qB, 32);
    if (lk == 0) {
        int ch2 = g * 32 + c * 2;
        float* od = ostatR + (b & 255) * 512;
        atomicAdd(&od[ch2 * 2 + 0], sA);
        atomicAdd(&od[ch2 * 2 + 1], qA);
        atomicAdd(&od[ch2 * 2 + 2], sB);
        atomicAdd(&od[ch2 * 2 + 3], qB);
    }
}

// k_outcoef: reduces 256 ostat replicas inline.
__global__ void k_outcoef(const float* ostatR, const void* gout, const void* bout,
                          const int* flag, float* ocoef) {
    int f32 = flag[0];
    int o = threadIdx.x;
    float s1 = 0.0f, s2 = 0.0f;
#pragma unroll 8
    for (int r = 0; r < 256; r++) {
        s1 += ostatR[r * 512 + o * 2];
        s2 += ostatR[r * 512 + o * 2 + 1];
    }
    const float n = 110592.0f;
    float mean = s1 / n;
    float var = s2 / n - mean * mean;
    if (var < 0.0f) var = 0.0f;
    float sc = ldf(gout, o, f32) * rsqrtf(var + 1e-5f);
    ocoef[o * 2] = sc;
    ocoef[o * 2 + 1] = ldf(bout, o, f32) - mean * sc;
}

// final: BN + pair-sum + transpose.
__global__ __launch_bounds__(256) void k_final(const u16* pre2, const float* ocoef,
                                               const int* flag, void* outp) {
    __shared__ float tile[48 * 49];
    int f32 = flag[0];
    int ch = blockIdx.x, w = blockIdx.y, tid = threadIdx.x;
    float sc0 = ocoef[(ch * 2) * 2],     sh0 = ocoef[(ch * 2) * 2 + 1];
    float sc1 = ocoef[(ch * 2 + 1) * 2], sh1 = ocoef[(ch * 2 + 1) * 2 + 1];
    float shs = sh0 + sh1;
#pragma unroll
    for (int r = 0; r < 9; r++) {
        int idx = tid + 256 * r;
        int d = idx / 48, i = idx % 48;
        ushort2 p = ((const ushort2*)pre2)[((w * 48 + d) * 128 + ch) * 48 + i];
        tile[d * 49 + i] = b2f(p.x) * sc0 + b2f(p.y) * sc1 + shs;
    }
    __syncthreads();
#pragma unroll
    for (int r = 0; r < 9; r++) {
        int idx = tid + 256 * r;
        int i = idx / 48, d = idx % 48;
        float v = tile[d * 49 + i];
        int oidx = ch * N_S + i * 2304 + w * 48 + d;
        if (f32) ((float*)outp)[oidx] = v;
        else     ((u16*)outp)[oidx] = f2b(v);
    }
}

// ================= FALLBACK PATH =================
__global__ __launch_bounds__(256) void k_qkstat(const void* Xv, const float* weff, const float* beff,
        const u16* qe, const u16* keT, const void* fqrp, const void* fkrp,
        const int* flag, float* sstatR) {
    __shared__ __align__(16) float xs[3072];
    __shared__ __align__(16) float qsh[3072];
    __shared__ __align__(16) float ksh[3072];
    __shared__ float red[48];
    int f32 = flag[0];
    int b = blockIdx.x, tid = threadIdx.x;
    for (int idx = tid; idx < 3072; idx += 256) {
        int c = idx / 48, h = idx % 48;
        xs[idx] = ldf(Xv, c * N_S + h * 2304 + b, f32);
    }
    if (tid < 48) red[tid] = 0.0f;
    __syncthreads();
    {
        int r = tid >> 1, half = tid & 1;
        int o; float* dst;
        if (r < 64) { o = 192 + r; dst = qsh + r * 48; }
        else { int rk = r - 64; o = (rk >> 3) * 24 + (rk & 7); dst = ksh + rk * 48; }
        float wr[64];
        const float4* wrow = (const float4*)(weff + o * 64);
#pragma unroll
        for (int c4 = 0; c4 < 16; c4++) {
            float4 t4 = wrow[c4];
            wr[c4 * 4 + 0] = t4.x; wr[c4 * 4 + 1] = t4.y; wr[c4 * 4 + 2] = t4.z; wr[c4 * 4 + 3] = t4.w;
        }
        float bias = beff[o];
        int h0 = half * 24;
#pragma unroll
        for (int hb = 0; hb < 3; hb++) {
            float acc[8];
#pragma unroll
            for (int u = 0; u < 8; u++) acc[u] = bias;
#pragma unroll
            for (int c = 0; c < 64; c++) {
                float wv = wr[c];
                const float4* xp = (const float4*)(xs + c * 48 + h0 + hb * 8);
                float4 x0 = xp[0], x1 = xp[1];
                acc[0] += wv * x0.x; acc[1] += wv * x0.y; acc[2] += wv * x0.z; acc[3] += wv * x0.w;
                acc[4] += wv * x1.x; acc[5] += wv * x1.y; acc[6] += wv * x1.z; acc[7] += wv * x1.w;
            }
            *(float4*)(dst + h0 + hb * 8)     = make_float4(acc[0], acc[1], acc[2], acc[3]);
            *(float4*)(dst + h0 + hb * 8 + 4) = make_float4(acc[4], acc[5], acc[6], acc[7]);
        }
    }
    __syncthreads();
    float fqr = ldf(fqrp, 0, f32), fkr = ldf(fkrp, 0, f32);
    float sum[24], sq[24];
#pragma unroll
    for (int k = 0; k < 24; k++) { sum[k] = 0.0f; sq[k] = 0.0f; }
    for (int r = 0; r < 3; r++) {
        int chunk = tid + 256 * r;
        if (chunk >= 576) break;
        int i = chunk / 12, j0 = (chunk % 12) * 4;
        float qv[8][4], kv[8][4];
#pragma unroll
        for (int c = 0; c < 8; c++) {
            ushort4 uq = *(const ushort4*)(qe + c * 2304 + i * 48 + j0);
            ushort4 uk = *(const ushort4*)(keT + c * 2304 + i * 48 + j0);
            qv[c][0] = b2f(uq.x); qv[c][1] = b2f(uq.y); qv[c][2] = b2f(uq.z); qv[c][3] = b2f(uq.w);
            kv[c][0] = b2f(uk.x); kv[c][1] = b2f(uk.y); kv[c][2] = b2f(uk.z); kv[c][3] = b2f(uk.w);
        }
#pragma unroll
        for (int g = 0; g < 8; g++) {
            float zq[4] = {0,0,0,0}, zr[4] = {0,0,0,0}, zk[4] = {0,0,0,0};
#pragma unroll
            for (int c = 0; c < 8; c++) {
                float qi = qsh[(g * 8 + c) * 48 + i];
                float4 kk = *(const float4*)(ksh + (g * 8 + c) * 48 + j0);
                zq[0] += qi * kk.x; zq[1] += qi * kk.y; zq[2] += qi * kk.z; zq[3] += qi * kk.w;
                zr[0] += qi * qv[c][0]; zr[1] += qi * qv[c][1]; zr[2] += qi * qv[c][2]; zr[3] += qi * qv[c][3];
                zk[0] += kk.x * kv[c][0]; zk[1] += kk.y * kv[c][1]; zk[2] += kk.z * kv[c][2]; zk[3] += kk.w * kv[c][3];
            }
#pragma unroll
            for (int u = 0; u < 4; u++) {
                float a = zq[u];        sum[g] += a;       sq[g] += a * a;
                float r1 = zr[u] * fqr; sum[8 + g] += r1;  sq[8 + g] += r1 * r1;
                float r2 = zk[u] * fkr; sum[16 + g] += r2; sq[16 + g] += r2 * r2;
            }
        }
    }
#pragma unroll
    for (int k = 0; k < 24; k++) {
        float s = sum[k], q = sq[k];
        for (int off = 32; off >= 1; off >>= 1) { s += __shfl_xor(s, off); q += __shfl_xor(q, off); }
        if ((tid & 63) == 0) { atomicAdd(&red[k], s); atomicAdd(&red[24 + k], q); }
    }
    __syncthreads();
    if (tid < 48) atomicAdd(&sstatR[(b & 255) * 48 + tid], red[tid]);
}

__global__ __launch_bounds__(256) void k_attn(const void* Xv, const float* weff, const float* beff,
        const u16* qe, const u16* keT, const u16* ve,
        const float* scoef, const float* ocoef,
        const void* fqrp, const void* fkrp, const void* fsvp, const void* fsvep,
        const int* flag, float* ostatR, void* outp, int mode) {
    __shared__ __align__(16) float zx[3072];
    __shared__ __align__(16) float qsh[3072];
    __shared__ __align__(16) float ksh[3072];
    __shared__ __align__(16) float vsh[6144];
    __shared__ float osl[512];
    int f32 = flag[0];
    int b = blockIdx.x, tid = threadIdx.x;
    for (int idx = tid; idx < 3072; idx += 256) {
        int c = idx / 48, h = idx % 48;
        zx[idx] = ldf(Xv, c * N_S + h * 2304 + b, f32);
    }
    __syncthreads();
    {
        int o; float* dst;
        if (tid < 64)       { o = 192 + tid; dst = qsh + tid * 48; }
        else if (tid < 128) { int rk = tid - 64; o = (rk >> 3) * 24 + (rk & 7); dst = ksh + rk * 48; }
        else                { int rv = tid - 128; o = (rv >> 4) * 24 + 8 + (rv & 15); dst = vsh + rv * 48; }
        float wr[64];
        const float4* wrow = (const float4*)(weff + o * 64);
#pragma unroll
        for (int c4 = 0; c4 < 16; c4++) {
            float4 t4 = wrow[c4];
            wr[c4 * 4 + 0] = t4.x; wr[c4 * 4 + 1] = t4.y; wr[c4 * 4 + 2] = t4.z; wr[c4 * 4 + 3] = t4.w;
        }
        float bias = beff[o];
#pragma unroll
        for (int hb = 0; hb < 6; hb++) {
            float acc[8];
#pragma unroll
            for (int u = 0; u < 8; u++) acc[u] = bias;
#pragma unroll
            for (int c = 0; c < 64; c++) {
                float wv = wr[c];
                const float4* xp = (const float4*)(zx + c * 48 + hb * 8);
                float4 x0 = xp[0], x1 = xp[1];
                acc[0] += wv * x0.x; acc[1] += wv * x0.y; acc[2] += wv * x0.z; acc[3] += wv * x0.w;
                acc[4] += wv * x1.x; acc[5] += wv * x1.y; acc[6] += wv * x1.z; acc[7] += wv * x1.w;
            }
            *(float4*)(dst + hb * 8)     = make_float4(acc[0], acc[1], acc[2], acc[3]);
            *(float4*)(dst + hb * 8 + 4) = make_float4(acc[4], acc[5], acc[6], acc[7]);
        }
    }
    __syncthreads();
    float fqr = ldf(fqrp, 0, f32), fkr = ldf(fkrp, 0, f32);
    float fsv = ldf(fsvp, 0, f32), fsve = ldf(fsvep, 0, f32);
    float* z = zx;
    for (int g = 0; g < 8; g++) {
        float c0 = scoef[g], c1 = scoef[8 + g], c2 = scoef[16 + g];
        for (int r = 0; r < 3; r++) {
            int chunk = tid + 256 * r;
            if (chunk >= 576) break;
            int i = chunk / 12, j0 = (chunk % 12) * 4;
            float zq[4] = {0,0,0,0}, zr[4] = {0,0,0,0}, zk[4] = {0,0,0,0};
#pragma unroll
            for (int c = 0; c < 8; c++) {
                ushort4 uq = *(const ushort4*)(qe + c * 2304 + i * 48 + j0);
                ushort4 uk = *(const ushort4*)(keT + c * 2304 + i * 48 + j0);
                float qi = qsh[(g * 8 + c) * 48 + i];
                float4 kk = *(const float4*)(ksh + (g * 8 + c) * 48 + j0);
                zq[0] += qi * kk.x; zq[1] += qi * kk.y; zq[2] += qi * kk.z; zq[3] += qi * kk.w;
                zr[0] += qi * b2f(uq.x); zr[1] += qi * b2f(uq.y); zr[2] += qi * b2f(uq.z); zr[3] += qi * b2f(uq.w);
                zk[0] += kk.x * b2f(uk.x); zk[1] += kk.y * b2f(uk.y); zk[2] += kk.z * b2f(uk.z); zk[3] += kk.w * b2f(uk.w);
            }
            float4 o4;
            o4.x = c0 * zq[0] + c1 * (fqr * zr[0]) + c2 * (fkr * zk[0]);
            o4.y = c0 * zq[1] + c1 * (fqr * zr[1]) + c2 * (fkr * zk[1]);
            o4.z = c0 * zq[2] + c1 * (fqr * zr[2]) + c2 * (fkr * zk[2]);
            o4.w = c0 * zq[3] + c1 * (fqr * zr[3]) + c2 * (fkr * zk[3]);
            *(float4*)(z + i * 52 + j0) = o4;
        }
        __syncthreads();
        {
            int wv = tid >> 6, lane = tid & 63;
            for (int rr = 0; rr < 12; rr++) {
                int i = wv * 12 + rr;
                float val = (lane < 48) ? z[i * 52 + lane] : -1e30f;
                float m = val;
                for (int off = 32; off >= 1; off >>= 1) m = fmaxf(m, __shfl_xor(m, off));
                float e = (lane < 48) ? __expf(val - m) : 0.0f;
                float s = e;
                for (int off = 32; off >= 1; off >>= 1) s += __shfl_xor(s, off);
                if (lane < 48) z[i * 52 + lane] = e / s;
            }
        }
        __syncthreads();
        {
            int c = tid >> 4, u = tid & 15;
            int ch2 = g * 32 + c * 2;
            float oc0 = 0, oc1 = 0, osh = 0;
            if (mode != 0) {
                oc0 = ocoef[ch2 * 2]; oc1 = ocoef[(ch2 + 1) * 2];
                osh = ocoef[ch2 * 2 + 1] + ocoef[(ch2 + 1) * 2 + 1];
            }
            float sumA = 0, sqA = 0, sumB = 0, sqB = 0;
#pragma unroll
            for (int r = 0; r < 3; r++) {
                int i = u + 16 * r;
                float sv = 0.0f, se = 0.0f;
#pragma unroll
                for (int j4 = 0; j4 < 12; j4++) {
                    float4 sm = *(const float4*)(z + i * 52 + j4 * 4);
                    float4 vv = *(const float4*)(vsh + (g * 16 + c) * 48 + j4 * 4);
                    ushort4 veu = *(const ushort4*)(ve + c * 2304 + i * 48 + j4 * 4);
                    sv += sm.x * vv.x + sm.y * vv.y + sm.z * vv.z + sm.w * vv.w;
                    se += sm.x * b2f(veu.x) + sm.y * b2f(veu.y) + sm.z * b2f(veu.z) + sm.w * b2f(veu.w);
                }
                float a = sv * fsv, bb = se * fsve;
                if (mode == 0) {
                    sumA += a; sqA += a * a; sumB += bb; sqB += bb * bb;
                } else {
                    float outv = a * oc0 + bb * oc1 + osh;
                    int oidx = (g * 16 + c) * N_S + i * 2304 + b;
                    if (f32) ((float*)outp)[oidx] = outv;
                    else     ((u16*)outp)[oidx] = f2b(outv);
                }
            }
            if (mode == 0) {
                for (int off = 1; off <= 8; off <<= 1) {
                    sumA += __shfl_xor(sumA, off); sqA += __shfl_xor(sqA, off);
                    sumB += __shfl_xor(sumB, off); sqB += __shfl_xor(sqB, off);
                }
                if (u == 0) {
                    int base = ch2 * 2;
                    osl[base + 0] = sumA; osl[base + 1] = sqA;
                    osl[base + 2] = sumB; osl[base + 3] = sqB;
                }
            }
        }
        __syncthreads();
    }
    if (mode == 0) {
        float* od = ostatR + (b & 255) * 512;
        atomicAdd(&od[tid], osl[tid]);
        atomicAdd(&od[tid + 256], osl[tid + 256]);
    }
}

extern "C" void kernel_launch(void* const* d_in, const int* in_sizes, int n_in,
                              void* d_out, int out_size, void* d_ws, size_t ws_size,
                              hipStream_t stream) {
    const void* X    = d_in[0];
    const void* Wkv  = d_in[1];
    const void* Wq   = d_in[2];
    const void* gkv  = d_in[3];
    const void* bkv  = d_in[4];
    const void* gq   = d_in[5];
    const void* bq   = d_in[6];
    const void* gsim = d_in[7];
    const void* gout = d_in[9];
    const void* bout = d_in[10];
    const void* rel  = d_in[11];
    const void* fqrp = d_in[12];
    const void* fkrp = d_in[13];
    const void* fsvp = d_in[14];
    const void* fsvep= d_in[15];
    const int* fidx  = (const int*)d_in[16];

    float* W      = (float*)d_ws;
    float* musum  = W;             // 64 -> 64
    float* gram   = W + 64;        // 4096 -> 4160
    float* musumR = W + 4160;      // 8*64 -> 4672
    float* gramR  = W + 4672;      // 8*4096 -> 37440
    float* sstatR = W + 37440;     // 256*48 -> 49728
    float* ostatR = W + 49728;     // 256*512 -> 180800  (zero region = [0,180800))
    float* weff   = W + 180800;    // 16384 -> 197184
    float* beff   = W + 197184;    // 256 -> 197440
    float* scoef  = W + 197440;    // 24 -> 197464
    float* ocoef  = W + 197464;    // 512 -> 197976
    int*   flag   = (int*)(W + 197976);   // 1 (+3 pad) -> 197980
    float* mq     = W + 197980;    // 1920 -> 199900
    float* mk     = W + 199900;    // 1920 -> 201820
    float* e1q    = W + 201820;    // 384 -> 202204
    float* e1k    = W + 202204;    // 384 -> 202588
    u16*   qe     = (u16*)(W + 202588);   // 18432 u16 = 9216 fl -> 211804
    u16*   keT    = (u16*)(W + 211804);   // 18432 u16 = 9216 fl -> 221020
    u16*   ve     = (u16*)(W + 221020);   // 36864 u16 = 18432 fl -> 239452
    u16*   weffh  = (u16*)(W + 239452);   // 16384 u16 = 8192 fl -> 247644
    u16*   rq2    = (u16*)(W + 247644);   // 768 u16 = 384 fl -> 248028
    u16*   rk2    = (u16*)(W + 248028);   // 768 u16 = 384 fl -> 248412
    u16*   rv2    = (u16*)(W + 248412);   // 1536 u16 = 768 fl -> 249180
    u16*   qkv    = (u16*)(W + 249180);   // 28,311,552 u16 = 14,155,776 fl -> 14,404,956
    u16*   pre2   = qkv + 28311552;       // 28,311,552 u16 -> 28,560,732
    u16*   Xt     = (u16*)(W + 28560732); // 7,962,624 u16 = 3,981,312 fl -> 32,542,044

    const size_t need1 = (size_t)28560732 * 4;   // ~114.3 MB (tier 1)
    const size_t need2 = (size_t)32542044 * 4;   // ~130.2 MB (tier 2, +Xt)
    const int tier = (ws_size >= need2) ? 2 : ((ws_size >= need1) ? 1 : 0);

    k_detect<<<1, 256, 0, stream>>>((const u16*)X, flag);
    k_zero<<<180, 256, 0, stream>>>(W);
    k_emb<<<9, 256, 0, stream>>>(rel, fidx, flag, qe, keT, ve, rq2, rk2, rv2);
    k_gram<<<256, 256, 0, stream>>>(X, flag, musumR, gramR);
    k_gsum<<<17, 256, 0, stream>>>(musumR, gramR, musum, gram);
    k_fold<<<1, 256, 0, stream>>>(Wkv, Wq, gkv, bkv, gq, bq, flag, musum, gram, weff, weffh, beff);
    if (tier > 0) {
        k_mtab<<<1, 128, 0, stream>>>(rel, flag, mq, mk, e1q, e1k);
        if (tier == 2) {
            k_xpose<<<dim3(48, 36), 256, 0, stream>>>(X, flag, Xt);
            k_stage1m<<<2304, 256, 0, stream>>>(Xt, weffh, beff, mq, mk, e1q, e1k, sstatR, qkv);
        } else {
            k_stage1<<<2304, 256, 0, stream>>>(X, weff, beff, mq, mk, e1q, e1k, flag, sstatR, qkv);
        }
        k_simcoef<<<1, 32, 0, stream>>>(sstatR, gsim, fqrp, fkrp, flag, 0, scoef);
        k_attn3<<<dim3(2304, 8), 64, 0, stream>>>(qkv, rq2, rk2, rv2, scoef,
                                                  fqrp, fkrp, fsvp, fsvep, flag, ostatR, pre2);
        k_outcoef<<<1, 256, 0, stream>>>(ostatR, gout, bout, flag, ocoef);
        k_final<<<dim3(128, 48), 256, 0, stream>>>(pre2, ocoef, flag, d_out);
    } else {
        k_qkstat<<<2304, 256, 0, stream>>>(X, weff, beff, qe, keT, fqrp, fkrp, flag, sstatR);
        k_simcoef<<<1, 32, 0, stream>>>(sstatR, gsim, fqrp, fkrp, flag, 1, scoef);
        k_attn<<<2304, 256, 0, stream>>>(X, weff, beff, qe, keT, ve, scoef, ocoef,
                                         fqrp, fkrp, fsvp, fsvep, flag, ostatR, d_out, 0);
        k_outcoef<<<1, 256, 0, stream>>>(ostatR, gout, bout, flag, ocoef);
        k_attn<<<2304, 256, 0, stream>>>(X, weff, beff, qe, keT, ve, scoef, ocoef,
                                         fqrp, fkrp, fsvp, fsvep, flag, ostatR, d_out, 2);
    }
}

// Round 12
// 556.122 us; speedup vs baseline: 1.9057x; 1.0114x over previous
//
#include <hip/hip_runtime.h>

// RelativeAxialAttention on MI355X (gfx950). Single-attention-pass design.
// K=48, G=8, DK=8, DV=16, CIN=64, B = 2304.
//
// Math shortcuts:
//  * kv/q BatchNorm folded into GEMM weights via x-gram.
//  * sim BN: softmax-invariant mean/beta; scales from CLOSED-FORM moments
//    (grams + Toeplitz windowed outer-products, k_mtab) -- no logits pass.
//  * k_stage1m: MFMA qkv GEMM from pre-transposed Xt (k_xpose).
//  * k_attn3: MFMA single-wave per (b,g).
//  * Round 11 confirmed ATOMIC CONTENTION was the 11-round ~550us floor:
//    replicated accumulators (ostat x256, sstat x256, gram/musum x8) took
//    total 974 -> 562us. Round 12: (a) stage1m writes qkv via full-tile LDS
//    (qall) + 1536 coalesced uint4 stores instead of 12288 scalar u16 globals;
//    (b) tier-2 gram computed by MFMA from Xt (k_gramm; 16MB bf16 read vs
//    44MB f32 + VALU outer-product). Launch order tier2: xpose -> gramm.
// Tiers: ws>=130.2MB full path; >=114.3MB VALU stage1; else recompute fallback.

typedef unsigned short u16;
typedef __attribute__((ext_vector_type(8))) short short8v;
typedef __attribute__((ext_vector_type(4))) float float4v;

#define N_S 110592
#define N_B 2304

__device__ __forceinline__ float b2f(u16 v) {
    return __builtin_bit_cast(float, ((unsigned)v) << 16);
}
__device__ __forceinline__ u16 f2b(float f) {
    unsigned u = __builtin_bit_cast(unsigned, f);
    u = (u + 0x7FFFu + ((u >> 16) & 1u)) >> 16;
    return (u16)u;
}
__device__ __forceinline__ float ldf(const void* p, int idx, int f32) {
    return f32 ? ((const float*)p)[idx] : b2f(((const u16*)p)[idx]);
}

// ---------------- dtype detection ----------------
__global__ void k_detect(const u16* X, int* flag) {
    __shared__ int tot;
    if (threadIdx.x == 0) tot = 0;
    __syncthreads();
    int cnt = 0;
#pragma unroll
    for (int k = 0; k < 8; k++) {
        u16 v = X[(threadIdx.x * 8 + k) * 2];
        int e = (v >> 7) & 0xFF;
        cnt += (e >= 0x70 && e <= 0x8F) ? 1 : 0;
    }
    atomicAdd(&tot, cnt);
    __syncthreads();
    if (threadIdx.x == 0) flag[0] = (tot < 1024) ? 1 : 0;   // 1 = f32
}

// ---------------- zero stats region (includes all replicas) ----------------
#define ZERO_N 180800
__global__ void k_zero(float* w) {
    for (int i = blockIdx.x * blockDim.x + threadIdx.x; i < ZERO_N; i += gridDim.x * blockDim.x)
        w[i] = 0.0f;
}

// ---------------- build emb tables ----------------
__global__ void k_emb(const void* rel, const int* fidx, const int* flag,
                      u16* qe, u16* keT, u16* ve, u16* rq2, u16* rk2, u16* rv2) {
    int f32 = flag[0];
    if (blockIdx.x == 0 && threadIdx.x < 96) {
        int d = threadIdx.x;
#pragma unroll
        for (int c = 0; c < 8; c++) {
            rq2[d * 8 + c] = (d < 95) ? f2b(ldf(rel, c * 95 + d, f32)) : (u16)0;
            rk2[d * 8 + c] = (d < 95) ? f2b(ldf(rel, (8 + c) * 95 + d, f32)) : (u16)0;
        }
#pragma unroll
        for (int c = 0; c < 16; c++)
            rv2[c * 96 + d] = (d < 95) ? f2b(ldf(rel, (16 + c) * 95 + d, f32)) : (u16)0;
    }
    int t = blockIdx.x * 256 + threadIdx.x;
    if (t >= 2304) return;
    int i = t / 48, j = t % 48;
    int fij = fidx[i * 48 + j];
    int fji = fidx[j * 48 + i];
#pragma unroll
    for (int c = 0; c < 8; c++) {
        qe[c * 2304 + t]  = f2b(ldf(rel, c * 95 + fij, f32));
        keT[c * 2304 + t] = f2b(ldf(rel, (8 + c) * 95 + fji, f32));
    }
#pragma unroll
    for (int c = 0; c < 16; c++)
        ve[c * 2304 + t] = f2b(ldf(rel, (16 + c) * 95 + fij, f32));
}

// ---------------- Toeplitz moment tables ----------------
__global__ void k_mtab(const void* rel, const int* flag,
                       float* mq, float* mk, float* e1q, float* e1k) {
    __shared__ float rl[1520];
    int f32 = flag[0];
    int tid = threadIdx.x;
    for (int idx = tid; idx < 1520; idx += 128) rl[idx] = ldf(rel, idx, f32);
    __syncthreads();
    if (tid >= 96) return;
    int tbl = tid / 48, i = tid % 48;
    const float* R = rl + tbl * 760;
    float* M = (tbl ? mk : mq) + i * 40;
    float* E = (tbl ? e1k : e1q) + i * 8;
    float acc[36], e[8];
#pragma unroll
    for (int x = 0; x < 36; x++) acc[x] = 0.0f;
#pragma unroll
    for (int c = 0; c < 8; c++) e[c] = 0.0f;
    for (int d = i; d < i + 48; d++) {
        float v[8];
#pragma unroll
        for (int c = 0; c < 8; c++) { v[c] = R[c * 95 + d]; e[c] += v[c]; }
        int idx = 0;
#pragma unroll
        for (int c = 0; c < 8; c++)
#pragma unroll
            for (int c2 = c; c2 < 8; c2++) { acc[idx] += v[c] * v[c2]; idx++; }
    }
    int idx = 0;
#pragma unroll
    for (int c = 0; c < 8; c++) {
        E[c] = e[c];
#pragma unroll
        for (int c2 = c; c2 < 8; c2++) {
            M[idx] = (c2 == c ? 1.0f : 2.0f) * acc[idx];
            idx++;
        }
    }
}

// ---------------- x gram (VALU, reads X; tiers 0/1) ----------------
__global__ __launch_bounds__(256) void k_gram(const void* Xv, const int* flag,
                                              float* musumR, float* gramR) {
    __shared__ float xs[64 * 65];
    int f32 = flag[0];
    int tid = threadIdx.x;
    int rep = blockIdx.x & 7;
    int cb1 = tid >> 4, cb2 = tid & 15;
    float acc[4][4];
#pragma unroll
    for (int a = 0; a < 4; a++)
#pragma unroll
        for (int b = 0; b < 4; b++) acc[a][b] = 0.0f;
    float mur = 0.0f;
    for (int tile = blockIdx.x; tile < 1728; tile += gridDim.x) {
        int s0 = tile * 64;
        __syncthreads();
#pragma unroll
        for (int r = 0; r < 4; r++) {
            int idx4 = tid + 256 * r;
            int c = idx4 >> 4, sl = (idx4 & 15) * 4;
            if (f32) {
                float4 u = *(const float4*)((const float*)Xv + c * N_S + s0 + sl);
                xs[c * 65 + sl + 0] = u.x; xs[c * 65 + sl + 1] = u.y;
                xs[c * 65 + sl + 2] = u.z; xs[c * 65 + sl + 3] = u.w;
            } else {
                ushort4 u = *(const ushort4*)((const u16*)Xv + c * N_S + s0 + sl);
                xs[c * 65 + sl + 0] = b2f(u.x); xs[c * 65 + sl + 1] = b2f(u.y);
                xs[c * 65 + sl + 2] = b2f(u.z); xs[c * 65 + sl + 3] = b2f(u.w);
            }
        }
        __syncthreads();
        for (int s = 0; s < 64; s++) {
            float av[4], bv[4];
#pragma unroll
            for (int a = 0; a < 4; a++) av[a] = xs[(cb1 + 16 * a) * 65 + s];
#pragma unroll
            for (int b = 0; b < 4; b++) bv[b] = xs[(cb2 + 16 * b) * 65 + s];
#pragma unroll
            for (int a = 0; a < 4; a++)
#pragma unroll
                for (int b = 0; b < 4; b++) acc[a][b] += av[a] * bv[b];
        }
        if (tid < 64) {
            for (int s = 0; s < 64; s++) mur += xs[tid * 65 + s];
        }
    }
#pragma unroll
    for (int a = 0; a < 4; a++)
#pragma unroll
        for (int b = 0; b < 4; b++)
            atomicAdd(&gramR[rep * 4096 + (cb1 + 16 * a) * 64 + (cb2 + 16 * b)], acc[a][b]);
    if (tid < 64) atomicAdd(&musumR[rep * 64 + tid], mur);
}

// ---------------- x gram via MFMA from Xt (tier 2) ----------------
// gram[c][c2] = sum_r Xt[r][c] Xt[r][c2]; 128-row chunks staged transposed
// [c][136] so A-frag == B-frag reads are contiguous 16B.
__global__ __launch_bounds__(256) void k_gramm(const u16* Xt, float* musumR, float* gramR) {
    __shared__ __align__(16) u16 xl[64 * 136];
    int tid = threadIdx.x;
    int rep = blockIdx.x & 7;
    int wv = tid >> 6, l = tid & 63, lm = l & 15, lk = l >> 4;
    int cc = tid & 63, part = tid >> 6;
    float4v acc[4];
#pragma unroll
    for (int t = 0; t < 4; t++)
#pragma unroll
        for (int e = 0; e < 4; e++) acc[t][e] = 0.0f;
    float msum = 0.0f;
    for (int ch = blockIdx.x; ch < 864; ch += 256) {
        __syncthreads();
#pragma unroll
        for (int e = 0; e < 4; e++) {
            int idx = tid + 256 * e;
            int r = idx >> 3, c8 = (idx & 7) * 8;
            uint4 u = *(const uint4*)(Xt + (size_t)(ch * 128 + r) * 72 + c8);
            const u16* up = (const u16*)&u;
#pragma unroll
            for (int j = 0; j < 8; j++) xl[(c8 + j) * 136 + r] = up[j];
        }
        __syncthreads();
#pragma unroll
        for (int rr = 0; rr < 32; rr++) msum += b2f(xl[cc * 136 + part * 32 + rr]);
#pragma unroll
        for (int ks = 0; ks < 4; ks++) {
            short8v fr[4];
#pragma unroll
            for (int tc = 0; tc < 4; tc++)
                fr[tc] = *(const short8v*)(xl + (tc * 16 + lm) * 136 + ks * 32 + lk * 8);
            short8v fa = fr[wv];
#pragma unroll
            for (int tc = 0; tc < 4; tc++)
                acc[tc] = __builtin_amdgcn_mfma_f32_16x16x32_bf16(fa, fr[tc], acc[tc], 0, 0, 0);
        }
    }
#pragma unroll
    for (int tc = 0; tc < 4; tc++)
#pragma unroll
        for (int rr = 0; rr < 4; rr++) {
            int row = wv * 16 + lk * 4 + rr;
            int col = tc * 16 + lm;
            atomicAdd(&gramR[rep * 4096 + row * 64 + col], acc[tc][rr]);
        }
    atomicAdd(&musumR[rep * 64 + cc], msum);
}

// ---------------- reduce gram/musum replicas ----------------
__global__ void k_gsum(const float* musumR, const float* gramR, float* musum, float* gram) {
    int idx = blockIdx.x * 256 + threadIdx.x;
    if (idx < 4096) {
        float s = 0.0f;
#pragma unroll
        for (int r = 0; r < 8; r++) s += gramR[r * 4096 + idx];
        gram[idx] = s;
    } else if (idx < 4160) {
        int c = idx - 4096;
        float s = 0.0f;
#pragma unroll
        for (int r = 0; r < 8; r++) s += musumR[r * 64 + c];
        musum[c] = s;
    }
}

// ---------------- fold BN into weights (f32 + bf16 copies) ----------------
__global__ __launch_bounds__(256) void k_fold(const void* Wkv, const void* Wq,
        const void* gkv, const void* bkv, const void* gq, const void* bq,
        const int* flag, const float* musum, const float* gram,
        float* weff, u16* weffh, float* beff) {
    int f32 = flag[0];
    int o = threadIdx.x;
    float gam, bet;
    float w[64];
    if (o < 192) {
#pragma unroll
        for (int c = 0; c < 64; c++) w[c] = ldf(Wkv, o * 64 + c, f32);
        gam = ldf(gkv, o, f32); bet = ldf(bkv, o, f32);
    } else {
        int oq = o - 192;
#pragma unroll
        for (int c = 0; c < 64; c++) w[c] = ldf(Wq, oq * 64 + c, f32);
        gam = ldf(gq, oq, f32); bet = ldf(bq, oq, f32);
    }
    const float inv = 1.0f / (float)N_S;
    float mean = 0.0f;
#pragma unroll
    for (int c = 0; c < 64; c++) mean += w[c] * musum[c];
    mean *= inv;
    float e2 = 0.0f;
    for (int c = 0; c < 64; c++) {
        float t = 0.0f;
#pragma unroll
        for (int c2 = 0; c2 < 64; c2++) t += w[c2] * gram[c * 64 + c2];
        e2 += w[c] * t;
    }
    e2 *= inv;
    float var = e2 - mean * mean;
    if (var < 0.0f) var = 0.0f;
    float sc = gam * rsqrtf(var + 1e-5f);
#pragma unroll
    for (int c = 0; c < 64; c++) {
        float wv = sc * w[c];
        weff[o * 64 + c] = wv;
        weffh[o * 64 + c] = f2b(wv);
    }
    beff[o] = bet - sc * mean;
}

// ---------------- transpose X -> Xt[b][h][c] bf16, h-stride 72 ----------------
__global__ __launch_bounds__(256) void k_xpose(const void* Xv, const int* flag, u16* Xt) {
    __shared__ float tile[64][65];
    int f32 = flag[0];
    int h = blockIdx.x, b0 = blockIdx.y * 64, tid = threadIdx.x;
#pragma unroll
    for (int r = 0; r < 4; r++) {
        int idx = tid + 256 * r;
        int c = idx >> 4, bq = (idx & 15) * 4;
        if (f32) {
            float4 u = *(const float4*)((const float*)Xv + (size_t)c * N_S + h * 2304 + b0 + bq);
            tile[c][bq + 0] = u.x; tile[c][bq + 1] = u.y;
            tile[c][bq + 2] = u.z; tile[c][bq + 3] = u.w;
        } else {
            ushort4 u = *(const ushort4*)((const u16*)Xv + (size_t)c * N_S + h * 2304 + b0 + bq);
            tile[c][bq + 0] = b2f(u.x); tile[c][bq + 1] = b2f(u.y);
            tile[c][bq + 2] = b2f(u.z); tile[c][bq + 3] = b2f(u.w);
        }
    }
    __syncthreads();
#pragma unroll
    for (int r = 0; r < 4; r++) {
        int idx = tid + 256 * r;
        int bb = idx >> 4, cq = (idx & 15) * 4;
        ushort4 o4 = make_ushort4(f2b(tile[cq + 0][bb]), f2b(tile[cq + 1][bb]),
                                  f2b(tile[cq + 2][bb]), f2b(tile[cq + 3][bb]));
        *(ushort4*)(Xt + (size_t)(b0 + bb) * 3456 + h * 72 + cq) = o4;
    }
}

// ================= FAST PATH (tier 2) =================
// stage1m: MFMA qkv GEMM; full output tile in LDS (qall), coalesced qkv write;
// closed-form sim-BN moments read from qall. Replicated sstat.
__global__ __launch_bounds__(256) void k_stage1m(const u16* Xt, const u16* weffh, const float* beff,
        const float* mq, const float* mk, const float* e1q, const float* e1k,
        float* sstatR, u16* qkv) {
    __shared__ __align__(16) u16 xs[3456];      // [h][72] bf16
    __shared__ __align__(16) u16 qall[12288];   // [row=g*32+r][48] full tile
    __shared__ float sbias[256];
    __shared__ float red[48];
    int b = blockIdx.x, tid = threadIdx.x;
    {
        const uint4* src = (const uint4*)(Xt + (size_t)b * 3456);
        uint4* dst = (uint4*)xs;
        for (int idx = tid; idx < 432; idx += 256) dst[idx] = src[idx];
    }
    sbias[tid] = beff[tid];
    if (tid < 48) red[tid] = 0.0f;
    __syncthreads();
    {
        int wv = tid >> 6, l = tid & 63;
        int lm = l & 15, lk8 = (l >> 4) * 8;
        short8v Bf[3][2];
#pragma unroll
        for (int ct = 0; ct < 3; ct++)
#pragma unroll
            for (int ks = 0; ks < 2; ks++)
                Bf[ct][ks] = *(const short8v*)(xs + (ct * 16 + lm) * 72 + ks * 32 + lk8);
        float4v acc[4][3];
#pragma unroll
        for (int a = 0; a < 4; a++)
#pragma unroll
            for (int c = 0; c < 3; c++)
#pragma unroll
                for (int e = 0; e < 4; e++) acc[a][c][e] = 0.0f;
#pragma unroll
        for (int rt = 0; rt < 4; rt++) {
            int orow = wv * 64 + rt * 16 + lm;
#pragma unroll
            for (int ks = 0; ks < 2; ks++) {
                short8v Af = *(const short8v*)(weffh + orow * 64 + ks * 32 + lk8);
#pragma unroll
                for (int ct = 0; ct < 3; ct++)
                    acc[rt][ct] = __builtin_amdgcn_mfma_f32_16x16x32_bf16(Af, Bf[ct][ks], acc[rt][ct], 0, 0, 0);
            }
        }
        int rbase = (l >> 4) * 4;
#pragma unroll
        for (int rt = 0; rt < 4; rt++) {
#pragma unroll
            for (int ct = 0; ct < 3; ct++) {
                int h = ct * 16 + lm;
#pragma unroll
                for (int rg = 0; rg < 4; rg++) {
                    int o = wv * 64 + rt * 16 + rbase + rg;
                    u16 vb = f2b(acc[rt][ct][rg] + sbias[o]);
                    int row;
                    if (o >= 192) {
                        int g = (o - 192) >> 3, c = (o - 192) & 7;
                        row = g * 32 + c;
                    } else {
                        int g = o / 24, t = o % 24;
                        if (t < 8) row = g * 32 + 8 + t;
                        else       row = g * 32 + 16 + (t - 8);
                    }
                    qall[row * 48 + h] = vb;
                }
            }
        }
    }
    __syncthreads();
    {   // coalesced qkv write: 12288 u16 = 1536 uint4
        uint4* gq = (uint4*)(qkv + (size_t)b * 12288);
        const uint4* lq = (const uint4*)qall;
#pragma unroll
        for (int e = 0; e < 6; e++) gq[tid + 256 * e] = lq[tid + 256 * e];
    }
    {   // closed-form moments: 32 threads per g, thread handles i = t (+32)
        int g = tid >> 5, t = tid & 31;
        float gq[36], gk[36], sq[8], sk[8];
        float s1qr = 0, s1kr = 0, s2qr = 0, s2kr = 0;
#pragma unroll
        for (int x = 0; x < 36; x++) { gq[x] = 0.0f; gk[x] = 0.0f; }
#pragma unroll
        for (int c = 0; c < 8; c++) { sq[c] = 0.0f; sk[c] = 0.0f; }
#pragma unroll
        for (int pass = 0; pass < 2; pass++) {
            int i = t + pass * 32;
            if (i >= 48) break;
            float qv[8], kvv[8];
#pragma unroll
            for (int c = 0; c < 8; c++) {
                qv[c]  = b2f(qall[(g * 32 + c) * 48 + i]);
                kvv[c] = b2f(qall[(g * 32 + 8 + c) * 48 + i]);
            }
            const float* mqr = mq + i * 40;
            const float* mkr = mk + i * 40;
            const float* eqr = e1q + i * 8;
            const float* ekr = e1k + i * 8;
            int idx = 0;
#pragma unroll
            for (int c = 0; c < 8; c++) {
                sq[c] += qv[c]; sk[c] += kvv[c];
                s1qr += qv[c] * eqr[c];
                s1kr += kvv[c] * ekr[c];
#pragma unroll
                for (int c2 = c; c2 < 8; c2++) {
                    float oq = qv[c] * qv[c2], ok = kvv[c] * kvv[c2];
                    gq[idx] += oq; gk[idx] += ok;
                    s2qr += mqr[idx] * oq;
                    s2kr += mkr[idx] * ok;
                    idx++;
                }
            }
        }
#pragma unroll
        for (int off = 1; off <= 16; off <<= 1) {
#pragma unroll
            for (int x = 0; x < 36; x++) { gq[x] += __shfl_xor(gq[x], off); gk[x] += __shfl_xor(gk[x], off); }
#pragma unroll
            for (int c = 0; c < 8; c++) { sq[c] += __shfl_xor(sq[c], off); sk[c] += __shfl_xor(sk[c], off); }
            s1qr += __shfl_xor(s1qr, off); s1kr += __shfl_xor(s1kr, off);
            s2qr += __shfl_xor(s2qr, off); s2kr += __shfl_xor(s2kr, off);
        }
        if (t == 0) {
            float s1qk = 0.0f, s2qk = 0.0f;
            int idx = 0;
#pragma unroll
            for (int c = 0; c < 8; c++) {
                s1qk += sq[c] * sk[c];
#pragma unroll
                for (int c2 = c; c2 < 8; c2++) {
                    float w = (c2 == c) ? 1.0f : 2.0f;
                    s2qk += w * gq[idx] * gk[idx];
                    idx++;
                }
            }
            red[0 * 8 + g] = s1qk;  red[1 * 8 + g] = s1qr;  red[2 * 8 + g] = s1kr;
            red[3 * 8 + g] = s2qk;  red[4 * 8 + g] = s2qr;  red[5 * 8 + g] = s2kr;
        }
    }
    __syncthreads();
    if (tid < 48) atomicAdd(&sstatR[(b & 255) * 48 + tid], red[tid]);
}

// ================= tier-1 stage1 (VALU, reads X directly) =================
__global__ __launch_bounds__(256) void k_stage1(const void* Xv, const float* weff, const float* beff,
        const float* mq, const float* mk, const float* e1q, const float* e1k,
        const int* flag, float* sstatR, u16* qkv) {
    __shared__ __align__(16) float xs[3072];
    __shared__ __align__(16) float qk[6144];
    __shared__ float red[48];
    int f32 = flag[0];
    int b = blockIdx.x, tid = threadIdx.x;
    for (int idx = tid; idx < 3072; idx += 256) {
        int c = idx / 48, h = idx % 48;
        xs[idx] = ldf(Xv, c * N_S + h * 2304 + b, f32);
    }
    __syncthreads();
    {
        int g = tid >> 5, r = tid & 31;
        int o;
        if (r < 8)       o = 192 + g * 8 + r;
        else if (r < 16) o = g * 24 + (r - 8);
        else             o = g * 24 + 8 + (r - 16);
        float wr[64];
        const float4* wrow = (const float4*)(weff + o * 64);
#pragma unroll
        for (int c4 = 0; c4 < 16; c4++) {
            float4 t4 = wrow[c4];
            wr[c4 * 4 + 0] = t4.x; wr[c4 * 4 + 1] = t4.y; wr[c4 * 4 + 2] = t4.z; wr[c4 * 4 + 3] = t4.w;
        }
        float bias = beff[o];
        u16* gdst = qkv + (b * 256 + tid) * 48;
        float* ldst = (r < 8) ? (qk + g * 768 + r * 48)
                    : (r < 16 ? (qk + g * 768 + 384 + (r - 8) * 48) : nullptr);
#pragma unroll
        for (int hb = 0; hb < 6; hb++) {
            float acc[8];
#pragma unroll
            for (int u = 0; u < 8; u++) acc[u] = bias;
#pragma unroll
            for (int c = 0; c < 64; c++) {
                float wv = wr[c];
                const float4* xp = (const float4*)(xs + c * 48 + hb * 8);
                float4 x0 = xp[0], x1 = xp[1];
                acc[0] += wv * x0.x; acc[1] += wv * x0.y; acc[2] += wv * x0.z; acc[3] += wv * x0.w;
                acc[4] += wv * x1.x; acc[5] += wv * x1.y; acc[6] += wv * x1.z; acc[7] += wv * x1.w;
            }
            ushort4 p0 = make_ushort4(f2b(acc[0]), f2b(acc[1]), f2b(acc[2]), f2b(acc[3]));
            ushort4 p1 = make_ushort4(f2b(acc[4]), f2b(acc[5]), f2b(acc[6]), f2b(acc[7]));
            *(ushort4*)(gdst + hb * 8)     = p0;
            *(ushort4*)(gdst + hb * 8 + 4) = p1;
            if (ldst) {
                *(float4*)(ldst + hb * 8)     = make_float4(acc[0], acc[1], acc[2], acc[3]);
                *(float4*)(ldst + hb * 8 + 4) = make_float4(acc[4], acc[5], acc[6], acc[7]);
            }
        }
    }
    __syncthreads();
    {
        int g = tid >> 5, t = tid & 31;
        float gq[36], gk[36], sq[8], sk[8];
        float s1qr = 0, s1kr = 0, s2qr = 0, s2kr = 0;
#pragma unroll
        for (int x = 0; x < 36; x++) { gq[x] = 0.0f; gk[x] = 0.0f; }
#pragma unroll
        for (int c = 0; c < 8; c++) { sq[c] = 0.0f; sk[c] = 0.0f; }
#pragma unroll
        for (int pass = 0; pass < 2; pass++) {
            int i = t + pass * 32;
            if (i >= 48) break;
            float qv[8], kvv[8];
#pragma unroll
            for (int c = 0; c < 8; c++) {
                qv[c]  = qk[g * 768 + c * 48 + i];
                kvv[c] = qk[g * 768 + 384 + c * 48 + i];
            }
            const float* mqr = mq + i * 40;
            const float* mkr = mk + i * 40;
            const float* eqr = e1q + i * 8;
            const float* ekr = e1k + i * 8;
            int idx = 0;
#pragma unroll
            for (int c = 0; c < 8; c++) {
                sq[c] += qv[c]; sk[c] += kvv[c];
                s1qr += qv[c] * eqr[c];
                s1kr += kvv[c] * ekr[c];
#pragma unroll
                for (int c2 = c; c2 < 8; c2++) {
                    float oq = qv[c] * qv[c2], ok = kvv[c] * kvv[c2];
                    gq[idx] += oq; gk[idx] += ok;
                    s2qr += mqr[idx] * oq;
                    s2kr += mkr[idx] * ok;
                    idx++;
                }
            }
        }
#pragma unroll
        for (int off = 1; off <= 16; off <<= 1) {
#pragma unroll
            for (int x = 0; x < 36; x++) { gq[x] += __shfl_xor(gq[x], off); gk[x] += __shfl_xor(gk[x], off); }
#pragma unroll
            for (int c = 0; c < 8; c++) { sq[c] += __shfl_xor(sq[c], off); sk[c] += __shfl_xor(sk[c], off); }
            s1qr += __shfl_xor(s1qr, off); s1kr += __shfl_xor(s1kr, off);
            s2qr += __shfl_xor(s2qr, off); s2kr += __shfl_xor(s2kr, off);
        }
        if (t == 0) {
            float s1qk = 0.0f, s2qk = 0.0f;
            int idx = 0;
#pragma unroll
            for (int c = 0; c < 8; c++) {
                s1qk += sq[c] * sk[c];
#pragma unroll
                for (int c2 = c; c2 < 8; c2++) {
                    float w = (c2 == c) ? 1.0f : 2.0f;
                    s2qk += w * gq[idx] * gk[idx];
                    idx++;
                }
            }
            red[0 * 8 + g] = s1qk;  red[1 * 8 + g] = s1qr;  red[2 * 8 + g] = s1kr;
            red[3 * 8 + g] = s2qk;  red[4 * 8 + g] = s2qr;  red[5 * 8 + g] = s2kr;
        }
    }
    __syncthreads();
    if (tid < 48) atomicAdd(&sstatR[(b & 255) * 48 + tid], red[tid]);
}

// scaled=1: sstat already includes fqr/fkr (fallback). scaled=0: apply here.
__global__ void k_simcoef(const float* sstatR, const void* gsim, const void* fqrp, const void* fkrp,
                          const int* flag, int scaled, float* scoef) {
    int ch = threadIdx.x;
    if (ch >= 24) return;
    int f32 = flag[0];
    float f = 1.0f;
    if (!scaled) {
        if (ch >= 16)     f = ldf(fkrp, 0, f32);
        else if (ch >= 8) f = ldf(fqrp, 0, f32);
    }
    float s1 = 0.0f, s2 = 0.0f;
#pragma unroll 8
    for (int r = 0; r < 256; r++) {
        s1 += sstatR[r * 48 + ch];
        s2 += sstatR[r * 48 + 24 + ch];
    }
    const float n = 2304.0f * 2304.0f;
    float mean = f * s1 / n;
    float var = f * f * s2 / n - mean * mean;
    if (var < 0.0f) var = 0.0f;
    scoef[ch] = ldf(gsim, ch, f32) * rsqrtf(var + 1e-5f);
}

// attn3: one WAVE per (b, g). MFMA everywhere; in-register softmax; LDS 18432 B.
// Stats go to 256-way replicated ostat (b & 255).
__global__ __launch_bounds__(64) void k_attn3(const u16* qkv,
        const u16* rq2, const u16* rk2, const u16* rv2,
        const float* scoef, const void* fqrp, const void* fkrp,
        const void* fsvp, const void* fsvep, const int* flag,
        float* ostatR, u16* pre2) {
    __shared__ __align__(16) u16 qT[384];   // [i][c]
    __shared__ __align__(16) u16 kT[384];   // [j][c]
    __shared__ __align__(16) u16 R[8448];   // union {qrB[48][48], krB[48][56]} -> {zb[48][72], zd[48][104]}
    int f32 = flag[0];
    int b = blockIdx.x, g = blockIdx.y, tid = threadIdx.x;
    int lr = tid & 15, lk = tid >> 4;
    u16* qrB = R;             // stride 48
    u16* krB = R + 2304;      // stride 56
    u16* zb  = R;             // stride 72 (cols 48..71 zero pad, K=64)
    u16* zd  = R + 3456;      // stride 104 (cols 95..103 pad, K=96)
    const u16* src = qkv + (b * 256 + g * 32) * 48;
#pragma unroll
    for (int e = 0; e < 6; e++) {
        int idx = tid + 64 * e;
        int c = idx / 48, h = idx % 48;
        qT[h * 8 + c] = src[c * 48 + h];
        kT[h * 8 + c] = src[(8 + c) * 48 + h];
    }
    __syncthreads();
    short8v z8 = {0, 0, 0, 0, 0, 0, 0, 0};
    short8v aq[3], ak[3];
#pragma unroll
    for (int tm = 0; tm < 3; tm++) {
        aq[tm] = (lk == 0) ? *(const short8v*)(qT + (tm * 16 + lr) * 8) : z8;
        ak[tm] = (lk == 0) ? *(const short8v*)(kT + (tm * 16 + lr) * 8) : z8;
    }
#pragma unroll
    for (int tn = 0; tn < 6; tn++) {
        short8v bq = (lk == 0) ? *(const short8v*)(rq2 + (tn * 16 + lr) * 8) : z8;
        short8v bk = (lk == 0) ? *(const short8v*)(rk2 + (tn * 16 + lr) * 8) : z8;
#pragma unroll
        for (int tm = 0; tm < 3; tm++) {
            float4v a0 = {0, 0, 0, 0}, a1 = {0, 0, 0, 0};
            a0 = __builtin_amdgcn_mfma_f32_16x16x32_bf16(aq[tm], bq, a0, 0, 0, 0);
            a1 = __builtin_amdgcn_mfma_f32_16x16x32_bf16(ak[tm], bk, a1, 0, 0, 0);
#pragma unroll
            for (int r = 0; r < 4; r++) {
                int i = tm * 16 + lk * 4 + r;
                int dd = tn * 16 + lr - i;
                if (dd >= 0 && dd < 48) {
                    qrB[i * 48 + dd] = f2b(a0[r]);
                    krB[i * 56 + dd] = f2b(a1[r]);
                }
            }
        }
    }
    float4v qk[3][3];
#pragma unroll
    for (int tn = 0; tn < 3; tn++) {
        short8v bkf = (lk == 0) ? *(const short8v*)(kT + (tn * 16 + lr) * 8) : z8;
#pragma unroll
        for (int tm = 0; tm < 3; tm++) {
            float4v a = {0, 0, 0, 0};
            qk[tm][tn] = __builtin_amdgcn_mfma_f32_16x16x32_bf16(aq[tm], bkf, a, 0, 0, 0);
        }
    }
    __syncthreads();
    float fqr = ldf(fqrp, 0, f32), fkr = ldf(fkrp, 0, f32);
    float fsv = ldf(fsvp, 0, f32), fsve = ldf(fsvep, 0, f32);
    float c0 = scoef[g], c1f = scoef[8 + g] * fqr, c2f = scoef[16 + g] * fkr;
#pragma unroll
    for (int tm = 0; tm < 3; tm++)
#pragma unroll
        for (int r = 0; r < 4; r++) {
            int i = tm * 16 + lk * 4 + r;
            float v0[3];
#pragma unroll
            for (int tn = 0; tn < 3; tn++) {
                int j = tn * 16 + lr;
                v0[tn] = c0 * qk[tm][tn][r]
                       + c1f * b2f(qrB[i * 48 + 47 - j])
                       + c2f * b2f(krB[j * 56 + 47 - i]);
            }
            float m = fmaxf(fmaxf(v0[0], v0[1]), v0[2]);
#pragma unroll
            for (int off = 1; off <= 8; off <<= 1) m = fmaxf(m, __shfl_xor(m, off));
            float e0 = __expf(v0[0] - m), e1 = __expf(v0[1] - m), e2 = __expf(v0[2] - m);
            float s = e0 + e1 + e2;
#pragma unroll
            for (int off = 1; off <= 8; off <<= 1) s += __shfl_xor(s, off);
            float inv = 1.0f / s;
            qk[tm][0][r] = e0 * inv;
            qk[tm][1][r] = e1 * inv;
            qk[tm][2][r] = e2 * inv;
        }
    __syncthreads();
#pragma unroll
    for (int e = 0; e < 17; e++) {
        int idx = tid + 64 * e;
        if (idx < 1056) {
            uint4 zz = {0, 0, 0, 0};
            ((uint4*)R)[idx] = zz;
        }
    }
    __syncthreads();
#pragma unroll
    for (int tm = 0; tm < 3; tm++)
#pragma unroll
        for (int r = 0; r < 4; r++) {
            int i = tm * 16 + lk * 4 + r;
#pragma unroll
            for (int tn = 0; tn < 3; tn++) {
                int j = tn * 16 + lr;
                u16 pb = f2b(qk[tm][tn][r]);
                zb[i * 72 + j] = pb;
                zd[i * 104 + i + 47 - j] = pb;
            }
        }
    __syncthreads();
    float4v sv[3], se[3];
#pragma unroll
    for (int tm = 0; tm < 3; tm++) { sv[tm] = (float4v){0,0,0,0}; se[tm] = (float4v){0,0,0,0}; }
#pragma unroll
    for (int ks = 0; ks < 2; ks++) {
        short8v bv = (ks == 0 || lk < 2) ? *(const short8v*)(src + (16 + lr) * 48 + ks * 32 + lk * 8) : z8;
#pragma unroll
        for (int tm = 0; tm < 3; tm++) {
            short8v af = *(const short8v*)(zb + (tm * 16 + lr) * 72 + ks * 32 + lk * 8);
            sv[tm] = __builtin_amdgcn_mfma_f32_16x16x32_bf16(af, bv, sv[tm], 0, 0, 0);
        }
    }
#pragma unroll
    for (int ks = 0; ks < 3; ks++) {
        short8v br = *(const short8v*)(rv2 + lr * 96 + ks * 32 + lk * 8);
#pragma unroll
        for (int tm = 0; tm < 3; tm++) {
            short8v ad = *(const short8v*)(zd + (tm * 16 + lr) * 104 + ks * 32 + lk * 8);
            se[tm] = __builtin_amdgcn_mfma_f32_16x16x32_bf16(ad, br, se[tm], 0, 0, 0);
        }
    }
    int c = lr;
    float sA = 0, qA = 0, sB = 0, qB = 0;
    u16* pdst = pre2 + ((b * 128 + g * 16 + c) * 48) * 2;
#pragma unroll
    for (int tm = 0; tm < 3; tm++)
#pragma unroll
        for (int r = 0; r < 4; r++) {
            int i = tm * 16 + lk * 4 + r;
            float a = sv[tm][r] * fsv, bb = se[tm][r] * fsve;
            *(ushort2*)(pdst + i * 2) = make_ushort2(f2b(a), f2b(bb));
            sA += a; qA += a * a; sB += bb; qB += bb * bb;
        }
    sA += __shfl_xor(sA, 16); qA += __shfl_xor(qA, 16);
    sB += __shfl_xor(sB, 16); qB += __shfl_xor(qB, 16);
    sA += __shfl_xor(sA, 32); qA += __shfl_xor(qA, 32);
    sB += __shfl_xor(sB, 32); qB += __shfl_xor(qB, 32);
    if (lk == 0) {
        int ch2 = g * 32 + c * 2;
        float* od = ostatR + (b & 255) * 512;
        atomicAdd(&od[ch2 * 2 + 0], sA);
        atomicAdd(&od[ch2 * 2 + 1], qA);
        atomicAdd(&od[ch2 * 2 + 2], sB);
        atomicAdd(&od[ch2 * 2 + 3], qB);
    }
}

// k_outcoef: reduces 256 ostat replicas inline.
__global__ void k_outcoef(const float* ostatR, const void* gout, const void* bout,
                          const int* flag, float* ocoef) {
    int f32 = flag[0];
    int o = threadIdx.x;
    float s1 = 0.0f, s2 = 0.0f;
#pragma unroll 8
    for (int r = 0; r < 256; r++) {
        s1 += ostatR[r * 512 + o * 2];
        s2 += ostatR[r * 512 + o * 2 + 1];
    }
    const float n = 110592.0f;
    float mean = s1 / n;
    float var = s2 / n - mean * mean;
    if (var < 0.0f) var = 0.0f;
    float sc = ldf(gout, o, f32) * rsqrtf(var + 1e-5f);
    ocoef[o * 2] = sc;
    ocoef[o * 2 + 1] = ldf(bout, o, f32) - mean * sc;
}

// final: BN + pair-sum + transpose.
__global__ __launch_bounds__(256) void k_final(const u16* pre2, const float* ocoef,
                                               const int* flag, void* outp) {
    __shared__ float tile[48 * 49];
    int f32 = flag[0];
    int ch = blockIdx.x, w = blockIdx.y, tid = threadIdx.x;
    float sc0 = ocoef[(ch * 2) * 2],     sh0 = ocoef[(ch * 2) * 2 + 1];
    float sc1 = ocoef[(ch * 2 + 1) * 2], sh1 = ocoef[(ch * 2 + 1) * 2 + 1];
    float shs = sh0 + sh1;
#pragma unroll
    for (int r = 0; r < 9; r++) {
        int idx = tid + 256 * r;
        int d = idx / 48, i = idx % 48;
        ushort2 p = ((const ushort2*)pre2)[((w * 48 + d) * 128 + ch) * 48 + i];
        tile[d * 49 + i] = b2f(p.x) * sc0 + b2f(p.y) * sc1 + shs;
    }
    __syncthreads();
#pragma unroll
    for (int r = 0; r < 9; r++) {
        int idx = tid + 256 * r;
        int i = idx / 48, d = idx % 48;
        float v = tile[d * 49 + i];
        int oidx = ch * N_S + i * 2304 + w * 48 + d;
        if (f32) ((float*)outp)[oidx] = v;
        else     ((u16*)outp)[oidx] = f2b(v);
    }
}

// ================= FALLBACK PATH =================
__global__ __launch_bounds__(256) void k_qkstat(const void* Xv, const float* weff, const float* beff,
        const u16* qe, const u16* keT, const void* fqrp, const void* fkrp,
        const int* flag, float* sstatR) {
    __shared__ __align__(16) float xs[3072];
    __shared__ __align__(16) float qsh[3072];
    __shared__ __align__(16) float ksh[3072];
    __shared__ float red[48];
    int f32 = flag[0];
    int b = blockIdx.x, tid = threadIdx.x;
    for (int idx = tid; idx < 3072; idx += 256) {
        int c = idx / 48, h = idx % 48;
        xs[idx] = ldf(Xv, c * N_S + h * 2304 + b, f32);
    }
    if (tid < 48) red[tid] = 0.0f;
    __syncthreads();
    {
        int r = tid >> 1, half = tid & 1;
        int o; float* dst;
        if (r < 64) { o = 192 + r; dst = qsh + r * 48; }
        else { int rk = r - 64; o = (rk >> 3) * 24 + (rk & 7); dst = ksh + rk * 48; }
        float wr[64];
        const float4* wrow = (const float4*)(weff + o * 64);
#pragma unroll
        for (int c4 = 0; c4 < 16; c4++) {
            float4 t4 = wrow[c4];
            wr[c4 * 4 + 0] = t4.x; wr[c4 * 4 + 1] = t4.y; wr[c4 * 4 + 2] = t4.z; wr[c4 * 4 + 3] = t4.w;
        }
        float bias = beff[o];
        int h0 = half * 24;
#pragma unroll
        for (int hb = 0; hb < 3; hb++) {
            float acc[8];
#pragma unroll
            for (int u = 0; u < 8; u++) acc[u] = bias;
#pragma unroll
            for (int c = 0; c < 64; c++) {
                float wv = wr[c];
                const float4* xp = (const float4*)(xs + c * 48 + h0 + hb * 8);
                float4 x0 = xp[0], x1 = xp[1];
                acc[0] += wv * x0.x; acc[1] += wv * x0.y; acc[2] += wv * x0.z; acc[3] += wv * x0.w;
                acc[4] += wv * x1.x; acc[5] += wv * x1.y; acc[6] += wv * x1.z; acc[7] += wv * x1.w;
            }
            *(float4*)(dst + h0 + hb * 8)     = make_float4(acc[0], acc[1], acc[2], acc[3]);
            *(float4*)(dst + h0 + hb * 8 + 4) = make_float4(acc[4], acc[5], acc[6], acc[7]);
        }
    }
    __syncthreads();
    float fqr = ldf(fqrp, 0, f32), fkr = ldf(fkrp, 0, f32);
    float sum[24], sq[24];
#pragma unroll
    for (int k = 0; k < 24; k++) { sum[k] = 0.0f; sq[k] = 0.0f; }
    for (int r = 0; r < 3; r++) {
        int chunk = tid + 256 * r;
        if (chunk >= 576) break;
        int i = chunk / 12, j0 = (chunk % 12) * 4;
        float qv[8][4], kv[8][4];
#pragma unroll
        for (int c = 0; c < 8; c++) {
            ushort4 uq = *(const ushort4*)(qe + c * 2304 + i * 48 + j0);
            ushort4 uk = *(const ushort4*)(keT + c * 2304 + i * 48 + j0);
            qv[c][0] = b2f(uq.x); qv[c][1] = b2f(uq.y); qv[c][2] = b2f(uq.z); qv[c][3] = b2f(uq.w);
            kv[c][0] = b2f(uk.x); kv[c][1] = b2f(uk.y); kv[c][2] = b2f(uk.z); kv[c][3] = b2f(uk.w);
        }
#pragma unroll
        for (int g = 0; g < 8; g++) {
            float zq[4] = {0,0,0,0}, zr[4] = {0,0,0,0}, zk[4] = {0,0,0,0};
#pragma unroll
            for (int c = 0; c < 8; c++) {
                float qi = qsh[(g * 8 + c) * 48 + i];
                float4 kk = *(const float4*)(ksh + (g * 8 + c) * 48 + j0);
                zq[0] += qi * kk.x; zq[1] += qi * kk.y; zq[2] += qi * kk.z; zq[3] += qi * kk.w;
                zr[0] += qi * qv[c][0]; zr[1] += qi * qv[c][1]; zr[2] += qi * qv[c][2]; zr[3] += qi * qv[c][3];
                zk[0] += kk.x * kv[c][0]; zk[1] += kk.y * kv[c][1]; zk[2] += kk.z * kv[c][2]; zk[3] += kk.w * kv[c][3];
            }
#pragma unroll
            for (int u = 0; u < 4; u++) {
                float a = zq[u];        sum[g] += a;       sq[g] += a * a;
                float r1 = zr[u] * fqr; sum[8 + g] += r1;  sq[8 + g] += r1 * r1;
                float r2 = zk[u] * fkr; sum[16 + g] += r2; sq[16 + g] += r2 * r2;
            }
        }
    }
#pragma unroll
    for (int k = 0; k < 24; k++) {
        float s = sum[k], q = sq[k];
        for (int off = 32; off >= 1; off >>= 1) { s += __shfl_xor(s, off); q += __shfl_xor(q, off); }
        if ((tid & 63) == 0) { atomicAdd(&red[k], s); atomicAdd(&red[24 + k], q); }
    }
    __syncthreads();
    if (tid < 48) atomicAdd(&sstatR[(b & 255) * 48 + tid], red[tid]);
}

__global__ __launch_bounds__(256) void k_attn(const void* Xv, const float* weff, const float* beff,
        const u16* qe, const u16* keT, const u16* ve,
        const float* scoef, const float* ocoef,
        const void* fqrp, const void* fkrp, const void* fsvp, const void* fsvep,
        const int* flag, float* ostatR, void* outp, int mode) {
    __shared__ __align__(16) float zx[3072];
    __shared__ __align__(16) float qsh[3072];
    __shared__ __align__(16) float ksh[3072];
    __shared__ __align__(16) float vsh[6144];
    __shared__ float osl[512];
    int f32 = flag[0];
    int b = blockIdx.x, tid = threadIdx.x;
    for (int idx = tid; idx < 3072; idx += 256) {
        int c = idx / 48, h = idx % 48;
        zx[idx] = ldf(Xv, c * N_S + h * 2304 + b, f32);
    }
    __syncthreads();
    {
        int o; float* dst;
        if (tid < 64)       { o = 192 + tid; dst = qsh + tid * 48; }
        else if (tid < 128) { int rk = tid - 64; o = (rk >> 3) * 24 + (rk & 7); dst = ksh + rk * 48; }
        else                { int rv = tid - 128; o = (rv >> 4) * 24 + 8 + (rv & 15); dst = vsh + rv * 48; }
        float wr[64];
        const float4* wrow = (const float4*)(weff + o * 64);
#pragma unroll
        for (int c4 = 0; c4 < 16; c4++) {
            float4 t4 = wrow[c4];
            wr[c4 * 4 + 0] = t4.x; wr[c4 * 4 + 1] = t4.y; wr[c4 * 4 + 2] = t4.z; wr[c4 * 4 + 3] = t4.w;
        }
        float bias = beff[o];
#pragma unroll
        for (int hb = 0; hb < 6; hb++) {
            float acc[8];
#pragma unroll
            for (int u = 0; u < 8; u++) acc[u] = bias;
#pragma unroll
            for (int c = 0; c < 64; c++) {
                float wv = wr[c];
                const float4* xp = (const float4*)(zx + c * 48 + hb * 8);
                float4 x0 = xp[0], x1 = xp[1];
                acc[0] += wv * x0.x; acc[1] += wv * x0.y; acc[2] += wv * x0.z; acc[3] += wv * x0.w;
                acc[4] += wv * x1.x; acc[5] += wv * x1.y; acc[6] += wv * x1.z; acc[7] += wv * x1.w;
            }
            *(float4*)(dst + hb * 8)     = make_float4(acc[0], acc[1], acc[2], acc[3]);
            *(float4*)(dst + hb * 8 + 4) = make_float4(acc[4], acc[5], acc[6], acc[7]);
        }
    }
    __syncthreads();
    float fqr = ldf(fqrp, 0, f32), fkr = ldf(fkrp, 0, f32);
    float fsv = ldf(fsvp, 0, f32), fsve = ldf(fsvep, 0, f32);
    float* z = zx;
    for (int g = 0; g < 8; g++) {
        float c0 = scoef[g], c1 = scoef[8 + g], c2 = scoef[16 + g];
        for (int r = 0; r < 3; r++) {
            int chunk = tid + 256 * r;
            if (chunk >= 576) break;
            int i = chunk / 12, j0 = (chunk % 12) * 4;
            float zq[4] = {0,0,0,0}, zr[4] = {0,0,0,0}, zk[4] = {0,0,0,0};
#pragma unroll
            for (int c = 0; c < 8; c++) {
                ushort4 uq = *(const ushort4*)(qe + c * 2304 + i * 48 + j0);
                ushort4 uk = *(const ushort4*)(keT + c * 2304 + i * 48 + j0);
                float qi = qsh[(g * 8 + c) * 48 + i];
                float4 kk = *(const float4*)(ksh + (g * 8 + c) * 48 + j0);
                zq[0] += qi * kk.x; zq[1] += qi * kk.y; zq[2] += qi * kk.z; zq[3] += qi * kk.w;
                zr[0] += qi * b2f(uq.x); zr[1] += qi * b2f(uq.y); zr[2] += qi * b2f(uq.z); zr[3] += qi * b2f(uq.w);
                zk[0] += kk.x * b2f(uk.x); zk[1] += kk.y * b2f(uk.y); zk[2] += kk.z * b2f(uk.z); zk[3] += kk.w * b2f(uk.w);
            }
            float4 o4;
            o4.x = c0 * zq[0] + c1 * (fqr * zr[0]) + c2 * (fkr * zk[0]);
            o4.y = c0 * zq[1] + c1 * (fqr * zr[1]) + c2 * (fkr * zk[1]);
            o4.z = c0 * zq[2] + c1 * (fqr * zr[2]) + c2 * (fkr * zk[2]);
            o4.w = c0 * zq[3] + c1 * (fqr * zr[3]) + c2 * (fkr * zk[3]);
            *(float4*)(z + i * 52 + j0) = o4;
        }
        __syncthreads();
        {
            int wv = tid >> 6, lane = tid & 63;
            for (int rr = 0; rr < 12; rr++) {
                int i = wv * 12 + rr;
                float val = (lane < 48) ? z[i * 52 + lane] : -1e30f;
                float m = val;
                for (int off = 32; off >= 1; off >>= 1) m = fmaxf(m, __shfl_xor(m, off));
                float e = (lane < 48) ? __expf(val - m) : 0.0f;
                float s = e;
                for (int off = 32; off >= 1; off >>= 1) s += __shfl_xor(s, off);
                if (lane < 48) z[i * 52 + lane] = e / s;
            }
        }
        __syncthreads();
        {
            int c = tid >> 4, u = tid & 15;
            int ch2 = g * 32 + c * 2;
            float oc0 = 0, oc1 = 0, osh = 0;
            if (mode != 0) {
                oc0 = ocoef[ch2 * 2]; oc1 = ocoef[(ch2 + 1) * 2];
                osh = ocoef[ch2 * 2 + 1] + ocoef[(ch2 + 1) * 2 + 1];
            }
            float sumA = 0, sqA = 0, sumB = 0, sqB = 0;
#pragma unroll
            for (int r = 0; r < 3; r++) {
                int i = u + 16 * r;
                float sv = 0.0f, se = 0.0f;
#pragma unroll
                for (int j4 = 0; j4 < 12; j4++) {
                    float4 sm = *(const float4*)(z + i * 52 + j4 * 4);
                    float4 vv = *(const float4*)(vsh + (g * 16 + c) * 48 + j4 * 4);
                    ushort4 veu = *(const ushort4*)(ve + c * 2304 + i * 48 + j4 * 4);
                    sv += sm.x * vv.x + sm.y * vv.y + sm.z * vv.z + sm.w * vv.w;
                    se += sm.x * b2f(veu.x) + sm.y * b2f(veu.y) + sm.z * b2f(veu.z) + sm.w * b2f(veu.w);
                }
                float a = sv * fsv, bb = se * fsve;
                if (mode == 0) {
                    sumA += a; sqA += a * a; sumB += bb; sqB += bb * bb;
                } else {
                    float outv = a * oc0 + bb * oc1 + osh;
                    int oidx = (g * 16 + c) * N_S + i * 2304 + b;
                    if (f32) ((float*)outp)[oidx] = outv;
                    else     ((u16*)outp)[oidx] = f2b(outv);
                }
            }
            if (mode == 0) {
                for (int off = 1; off <= 8; off <<= 1) {
                    sumA += __shfl_xor(sumA, off); sqA += __shfl_xor(sqA, off);
                    sumB += __shfl_xor(sumB, off); sqB += __shfl_xor(sqB, off);
                }
                if (u == 0) {
                    int base = ch2 * 2;
                    osl[base + 0] = sumA; osl[base + 1] = sqA;
                    osl[base + 2] = sumB; osl[base + 3] = sqB;
                }
            }
        }
        __syncthreads();
    }
    if (mode == 0) {
        float* od = ostatR + (b & 255) * 512;
        atomicAdd(&od[tid], osl[tid]);
        atomicAdd(&od[tid + 256], osl[tid + 256]);
    }
}

extern "C" void kernel_launch(void* const* d_in, const int* in_sizes, int n_in,
                              void* d_out, int out_size, void* d_ws, size_t ws_size,
                              hipStream_t stream) {
    const void* X    = d_in[0];
    const void* Wkv  = d_in[1];
    const void* Wq   = d_in[2];
    const void* gkv  = d_in[3];
    const void* bkv  = d_in[4];
    const void* gq   = d_in[5];
    const void* bq   = d_in[6];
    const void* gsim = d_in[7];
    const void* gout = d_in[9];
    const void* bout = d_in[10];
    const void* rel  = d_in[11];
    const void* fqrp = d_in[12];
    const void* fkrp = d_in[13];
    const void* fsvp = d_in[14];
    const void* fsvep= d_in[15];
    const int* fidx  = (const int*)d_in[16];

    float* W      = (float*)d_ws;
    float* musum  = W;             // 64 -> 64
    float* gram   = W + 64;        // 4096 -> 4160
    float* musumR = W + 4160;      // 8*64 -> 4672
    float* gramR  = W + 4672;      // 8*4096 -> 37440
    float* sstatR = W + 37440;     // 256*48 -> 49728
    float* ostatR = W + 49728;     // 256*512 -> 180800  (zero region = [0,180800))
    float* weff   = W + 180800;    // 16384 -> 197184
    float* beff   = W + 197184;    // 256 -> 197440
    float* scoef  = W + 197440;    // 24 -> 197464
    float* ocoef  = W + 197464;    // 512 -> 197976
    int*   flag   = (int*)(W + 197976);   // 1 (+3 pad) -> 197980
    float* mq     = W + 197980;    // 1920 -> 199900
    float* mk     = W + 199900;    // 1920 -> 201820
    float* e1q    = W + 201820;    // 384 -> 202204
    float* e1k    = W + 202204;    // 384 -> 202588
    u16*   qe     = (u16*)(W + 202588);   // 18432 u16 = 9216 fl -> 211804
    u16*   keT    = (u16*)(W + 211804);   // 18432 u16 = 9216 fl -> 221020
    u16*   ve     = (u16*)(W + 221020);   // 36864 u16 = 18432 fl -> 239452
    u16*   weffh  = (u16*)(W + 239452);   // 16384 u16 = 8192 fl -> 247644
    u16*   rq2    = (u16*)(W + 247644);   // 768 u16 = 384 fl -> 248028
    u16*   rk2    = (u16*)(W + 248028);   // 768 u16 = 384 fl -> 248412
    u16*   rv2    = (u16*)(W + 248412);   // 1536 u16 = 768 fl -> 249180
    u16*   qkv    = (u16*)(W + 249180);   // 28,311,552 u16 = 14,155,776 fl -> 14,404,956
    u16*   pre2   = qkv + 28311552;       // 28,311,552 u16 -> 28,560,732
    u16*   Xt     = (u16*)(W + 28560732); // 7,962,624 u16 = 3,981,312 fl -> 32,542,044

    const size_t need1 = (size_t)28560732 * 4;   // ~114.3 MB (tier 1)
    const size_t need2 = (size_t)32542044 * 4;   // ~130.2 MB (tier 2, +Xt)
    const int tier = (ws_size >= need2) ? 2 : ((ws_size >= need1) ? 1 : 0);

    k_detect<<<1, 256, 0, stream>>>((const u16*)X, flag);
    k_zero<<<180, 256, 0, stream>>>(W);
    k_emb<<<9, 256, 0, stream>>>(rel, fidx, flag, qe, keT, ve, rq2, rk2, rv2);
    if (tier == 2) {
        k_xpose<<<dim3(48, 36), 256, 0, stream>>>(X, flag, Xt);
        k_gramm<<<256, 256, 0, stream>>>(Xt, musumR, gramR);
    } else {
        k_gram<<<256, 256, 0, stream>>>(X, flag, musumR, gramR);
    }
    k_gsum<<<17, 256, 0, stream>>>(musumR, gramR, musum, gram);
    k_fold<<<1, 256, 0, stream>>>(Wkv, Wq, gkv, bkv, gq, bq, flag, musum, gram, weff, weffh, beff);
    if (tier > 0) {
        k_mtab<<<1, 128, 0, stream>>>(rel, flag, mq, mk, e1q, e1k);
        if (tier == 2) {
            k_stage1m<<<2304, 256, 0, stream>>>(Xt, weffh, beff, mq, mk, e1q, e1k, sstatR, qkv);
        } else {
            k_stage1<<<2304, 256, 0, stream>>>(X, weff, beff, mq, mk, e1q, e1k, flag, sstatR, qkv);
        }
        k_simcoef<<<1, 32, 0, stream>>>(sstatR, gsim, fqrp, fkrp, flag, 0, scoef);
        k_attn3<<<dim3(2304, 8), 64, 0, stream>>>(qkv, rq2, rk2, rv2, scoef,
                                                  fqrp, fkrp, fsvp, fsvep, flag, ostatR, pre2);
        k_outcoef<<<1, 256, 0, stream>>>(ostatR, gout, bout, flag, ocoef);
        k_final<<<dim3(128, 48), 256, 0, stream>>>(pre2, ocoef, flag, d_out);
    } else {
        k_qkstat<<<2304, 256, 0, stream>>>(X, weff, beff, qe, keT, fqrp, fkrp, flag, sstatR);
        k_simcoef<<<1, 32, 0, stream>>>(sstatR, gsim, fqrp, fkrp, flag, 1, scoef);
        k_attn<<<2304, 256, 0, stream>>>(X, weff, beff, qe, keT, ve, scoef, ocoef,
                                         fqrp, fkrp, fsvp, fsvep, flag, ostatR, d_out, 0);
        k_outcoef<<<1, 256, 0, stream>>>(ostatR, gout, bout, flag, ocoef);
        k_attn<<<2304, 256, 0, stream>>>(X, weff, beff, qe, keT, ve, scoef, ocoef,
                                         fqrp, fkrp, fsvp, fsvep, flag, ostatR, d_out, 2);
    }
}